// Round 9
// baseline (409.576 us; speedup 1.0000x reference)
//
#include <hip/hip_runtime.h>

static constexpr int F = 128;
static constexpr int N_RBF = 20;
static constexpr int N_ATOMS = 8000;
static constexpr int NP = 8064;          // padded to 128
static constexpr int N_EDGES = 160000;
static constexpr int N_MOLS = 100;
static constexpr float CUTOFF = 5.0f;
static constexpr size_t NFC = (size_t)NP * F;
static constexpr int REC = 28;           // j, ev, ux,uy,uz, rbf[20], pad[3]
#define PIF 3.14159265358979323846f

typedef __attribute__((ext_vector_type(8))) short bf16x8;
typedef __attribute__((ext_vector_type(4))) float f32x4;
typedef unsigned short ushort_t;
typedef unsigned int uint_t;

__device__ __forceinline__ float silu_f(float x) { return x / (1.f + __expf(-x)); }

__device__ __forceinline__ ushort_t f2bf(float x) {   // round-to-nearest-even
    union { float f; uint_t u; } v; v.f = x;
    uint_t r = v.u + 0x7fffu + ((v.u >> 16) & 1u);
    return (ushort_t)(r >> 16);
}
__device__ __forceinline__ float bf2f(ushort_t h) {
    union { uint_t u; float f; } v; v.u = ((uint_t)h) << 16; return v.f;
}

// Lessons:
//  - r6: phi/v/s inter-layer activations MUST stay f32 (bf16 phi -> 49% output error).
//  - r7: 2-deep B prefetch REGRESSED; compiler schedules 1-deep fine.
//  - r5: edge-gather must stay its own high-occupancy dispatch.
//  - r8: updphi is BARRIER-bound (MfmaUtil 9.6%, VALU 11.7%, HBM 11%): 41 barriers around
//    LDS round-trips. THIS ROUND: B operands load DIRECT from global (L2-resident, same
//    total bytes, perfectly coalesced 16 rows x 64B per wave-fragment) -> phases 1/2/3
//    are barrier-free; norms/sS precomputed once into the LDS freed from B staging.

// ---------------- pass 1: distance + envelope + live-edge histogram ----------------
__global__ __launch_bounds__(256) void count_kernel(
    const float* __restrict__ xyz, const int* __restrict__ nbrs,
    float* __restrict__ envb, int* __restrict__ cnt)
{
    int e = blockIdx.x * 256 + threadIdx.x;
    if (e >= N_EDGES) return;
    int i0 = nbrs[2*e+0], i1 = nbrs[2*e+1];
    float dx = xyz[3*i1+0] - xyz[3*i0+0];
    float dy = xyz[3*i1+1] - xyz[3*i0+1];
    float dz = xyz[3*i1+2] - xyz[3*i0+2];
    float d  = sqrtf(dx*dx + dy*dy + dz*dz);
    float ev = (d <= CUTOFF) ? 0.5f*(cosf(PIF*d/CUTOFF) + 1.f) : 0.f;
    envb[e] = ev;
    if (ev > 0.f) atomicAdd(&cnt[i0], 1);
}

// ---------------- exclusive scan of 8000 counters (single block) + zero out ----------------
__global__ __launch_bounds__(1024) void scan_kernel(
    const int* __restrict__ cnt, int* __restrict__ offsets, float* __restrict__ out)
{
    __shared__ int sums[1024];
    int tid = threadIdx.x;
    if (tid < N_MOLS) out[tid] = 0.f;
    int base = tid * 8;
    int local[8]; int s = 0;
    #pragma unroll
    for (int i = 0; i < 8; ++i) {
        int idx = base + i;
        local[i] = (idx < N_ATOMS) ? cnt[idx] : 0;
        s += local[i];
    }
    sums[tid] = s;
    __syncthreads();
    for (int d = 1; d < 1024; d <<= 1) {
        int v = (tid >= d) ? sums[tid - d] : 0;
        __syncthreads();
        sums[tid] += v;
        __syncthreads();
    }
    int ex = (tid == 0) ? 0 : sums[tid - 1];
    #pragma unroll
    for (int i = 0; i < 8; ++i) {
        int idx = base + i;
        if (idx < N_ATOMS) { offsets[idx] = ex; ex += local[i]; }
    }
}

// ---------------- pass 2: build packed records for LIVE edges only ----------------
__global__ __launch_bounds__(256) void build_kernel(
    const float* __restrict__ xyz, const int* __restrict__ nbrs,
    const float* __restrict__ envb, const int* __restrict__ offsets,
    int* __restrict__ cursor, float* __restrict__ rec)
{
    int e = blockIdx.x * 256 + threadIdx.x;
    if (e >= N_EDGES) return;
    float ev = envb[e];
    if (ev <= 0.f) return;
    int i0 = nbrs[2*e+0], i1 = nbrs[2*e+1];
    float dx = xyz[3*i1+0] - xyz[3*i0+0];
    float dy = xyz[3*i1+1] - xyz[3*i0+1];
    float dz = xyz[3*i1+2] - xyz[3*i0+2];
    float d  = sqrtf(dx*dx + dy*dy + dz*dz);
    float inv = 1.f / d;
    int pos = offsets[i0] + atomicAdd(&cursor[i0], 1);
    float* r = rec + (size_t)pos * REC;
    r[0] = __int_as_float(i1);
    r[1] = ev;
    r[2] = dx*inv; r[3] = dy*inv; r[4] = dz*inv;
    float base = PIF*d/CUTOFF;
    float sc = inv * ev;   // fold env into rbf
    #pragma unroll
    for (int k = 0; k < N_RBF; ++k)
        r[5 + k] = sinf((float)(k+1)*base) * sc;
}

// ---------------- fused prep: embed + weight transpose/split + zero cnt/cursor ----------------
static constexpr int WPREP_W = 557056;
static constexpr int WPREP_TOTAL = 557184;
static constexpr int NATF = N_ATOMS * F;
static constexpr int PREP_TOTAL = NATF + WPREP_TOTAL + 2 * N_ATOMS;
__global__ __launch_bounds__(256) void prep_kernel(
    const float* __restrict__ emb, const int* __restrict__ z, float* __restrict__ s,
    const float* __restrict__ msg_w1, const float* __restrict__ msg_w2,
    const float* __restrict__ upd_u,  const float* __restrict__ upd_v,
    const float* __restrict__ upd_w1, const float* __restrict__ upd_w2,
    const float* __restrict__ ro_w1,  const float* __restrict__ ro_b1,
    ushort_t* __restrict__ dhi, ushort_t* __restrict__ dlo,
    float* __restrict__ robias, int* __restrict__ cntz)
{
    int gidx = blockIdx.x * 256 + threadIdx.x;
    if (gidx < NATF) {                          // s = emb_table[z]
        int n = gidx >> 7, f = gidx & 127;
        s[gidx] = emb[z[n]*F + f];
        return;
    }
    int idx = gidx - NATF;
    if (idx >= WPREP_TOTAL) {                   // zero cnt + cursor (adjacent)
        cntz[idx - WPREP_TOTAL] = 0;
        return;
    }
    if (idx >= WPREP_W) {
        int l = idx - WPREP_W;
        robias[l] = (l < 64) ? ro_b1[l] : 0.f;
        return;
    }
    float val;
    if (idx < 540672) {
        const float* src; int K, N, rem;
        if (idx < 49152)       { int l = idx;          int c = l / 16384; rem = l % 16384; K = 128; N = 128; src = msg_w1 + c * 16384; }
        else if (idx < 196608) { int l = idx - 49152;  int c = l / 49152; rem = l % 49152; K = 128; N = 384; src = msg_w2 + c * 49152; }
        else if (idx < 294912) { int l = idx - 196608; int c = l / 32768; rem = l % 32768; K = 128; N = 128;
                                 if (rem < 16384) src = upd_u + c * 16384;
                                 else { src = upd_v + c * 16384; rem -= 16384; } }
        else if (idx < 393216) { int l = idx - 294912; int c = l / 32768; rem = l % 32768; K = 256; N = 128; src = upd_w1 + c * 32768; }
        else                   { int l = idx - 393216; int c = l / 49152; rem = l % 49152; K = 128; N = 384; src = upd_w2 + c * 49152; }
        int n = rem / K, k = rem % K;
        val = src[k * N + n];
    } else {
        int l = idx - 540672;             // ro_w1 pad: [n][k], n>=64 -> 0
        int n = l >> 7, k = l & 127;
        val = (n < 64) ? ro_w1[k * 64 + n] : 0.f;
    }
    ushort_t h = f2bf(val);
    dhi[idx] = h;
    dlo[idx] = f2bf(val - bf2f(h));
}

// helper: f32x8 (two float4) -> bf16 hi/lo fragments
__device__ __forceinline__ void split8(const float* __restrict__ p, bf16x8& hi, bf16x8& lo) {
    float4 a = *(const float4*)p;
    float4 b = *(const float4*)(p + 4);
    float e[8] = {a.x, a.y, a.z, a.w, b.x, b.y, b.z, b.w};
    ushort_t ph[8], pl[8];
    #pragma unroll
    for (int t = 0; t < 8; ++t) {
        ushort_t h = f2bf(e[t]);
        ph[t] = h; pl[t] = f2bf(e[t] - bf2f(h));
    }
    hi = *(bf16x8*)ph; lo = *(bf16x8*)pl;
}

// ---------------- phi0: phi = silu(s@W1+b1)@W2+b2 (all operands direct; H via LDS) ----------------
__global__ __launch_bounds__(256) void phi0_kernel(
    const float* __restrict__ sbuf,
    const ushort_t* __restrict__ W1h, const ushort_t* __restrict__ W1l,
    const float* __restrict__ b1,
    const ushort_t* __restrict__ W2h, const ushort_t* __restrict__ W2l,
    const float* __restrict__ b2,
    float* __restrict__ C)
{
    __shared__ __align__(16) ushort_t Hh[32 * 136], Hl[32 * 136];
    const int tid = threadIdx.x;
    const int wave = tid >> 6, lane = tid & 63;
    const int row_l = lane & 15, quad = lane >> 4;
    const int wn = wave * 32;
    const int m0 = blockIdx.x * 32;

    f32x4 acc[2][2];
    #pragma unroll
    for (int i = 0; i < 2; ++i)
        #pragma unroll
        for (int j = 0; j < 2; ++j)
            #pragma unroll
            for (int r = 0; r < 4; ++r) acc[i][j][r] = 0.f;

    #pragma unroll
    for (int it = 0; it < 4; ++it) {
        const int k0 = it * 32;
        bf16x8 ahf[2], alf[2], bhf[2], blf[2];
        #pragma unroll
        for (int i = 0; i < 2; ++i)
            split8(&sbuf[(size_t)(m0 + i*16 + row_l) * 128 + k0 + quad*8], ahf[i], alf[i]);
        #pragma unroll
        for (int j = 0; j < 2; ++j) {
            size_t br = (size_t)(wn + j*16 + row_l) * 128 + k0 + quad*8;
            bhf[j] = *(const bf16x8*)&W1h[br];
            blf[j] = *(const bf16x8*)&W1l[br];
        }
        #pragma unroll
        for (int i = 0; i < 2; ++i)
            #pragma unroll
            for (int j = 0; j < 2; ++j) {
                acc[i][j] = __builtin_amdgcn_mfma_f32_16x16x32_bf16(ahf[i], bhf[j], acc[i][j], 0, 0, 0);
                acc[i][j] = __builtin_amdgcn_mfma_f32_16x16x32_bf16(ahf[i], blf[j], acc[i][j], 0, 0, 0);
                acc[i][j] = __builtin_amdgcn_mfma_f32_16x16x32_bf16(alf[i], bhf[j], acc[i][j], 0, 0, 0);
            }
    }
    #pragma unroll
    for (int j = 0; j < 2; ++j) {
        int col = wn + j * 16 + row_l;
        float bval = b1[col];
        #pragma unroll
        for (int i = 0; i < 2; ++i)
            #pragma unroll
            for (int r = 0; r < 4; ++r) {
                int row = i * 16 + quad * 4 + r;
                float v = silu_f(acc[i][j][r] + bval);
                ushort_t h = f2bf(v);
                Hh[row * 136 + col] = h;
                Hl[row * 136 + col] = f2bf(v - bf2f(h));
            }
    }
    __syncthreads();

    #pragma unroll
    for (int i = 0; i < 2; ++i)
        #pragma unroll
        for (int j = 0; j < 2; ++j)
            #pragma unroll
            for (int r = 0; r < 4; ++r) acc[i][j][r] = 0.f;
    #pragma unroll
    for (int it = 0; it < 12; ++it) {
        const int k0 = (it & 3) * 32;
        const int ct = it >> 2;
        bf16x8 ahf[2], alf[2], bhf[2], blf[2];
        #pragma unroll
        for (int i = 0; i < 2; ++i) {
            int ar = (i * 16 + row_l) * 136 + k0 + quad * 8;
            ahf[i] = *(const bf16x8*)&Hh[ar];
            alf[i] = *(const bf16x8*)&Hl[ar];
        }
        #pragma unroll
        for (int j = 0; j < 2; ++j) {
            size_t br = (size_t)(ct * 128 + wn + j*16 + row_l) * 128 + k0 + quad*8;
            bhf[j] = *(const bf16x8*)&W2h[br];
            blf[j] = *(const bf16x8*)&W2l[br];
        }
        #pragma unroll
        for (int i = 0; i < 2; ++i)
            #pragma unroll
            for (int j = 0; j < 2; ++j) {
                acc[i][j] = __builtin_amdgcn_mfma_f32_16x16x32_bf16(ahf[i], bhf[j], acc[i][j], 0, 0, 0);
                acc[i][j] = __builtin_amdgcn_mfma_f32_16x16x32_bf16(ahf[i], blf[j], acc[i][j], 0, 0, 0);
                acc[i][j] = __builtin_amdgcn_mfma_f32_16x16x32_bf16(alf[i], bhf[j], acc[i][j], 0, 0, 0);
            }
        if ((it & 3) == 3) {
            #pragma unroll
            for (int j = 0; j < 2; ++j) {
                int col = ct * 128 + wn + j * 16 + row_l;
                float bval = b2[col];
                #pragma unroll
                for (int i = 0; i < 2; ++i)
                    #pragma unroll
                    for (int r = 0; r < 4; ++r) {
                        int row = i * 16 + quad * 4 + r;
                        C[(size_t)(m0 + row) * 384 + col] = acc[i][j][r] + bval;
                    }
            }
            #pragma unroll
            for (int i = 0; i < 2; ++i)
                #pragma unroll
                for (int j = 0; j < 2; ++j)
                    #pragma unroll
                    for (int r = 0; r < 4; ++r) acc[i][j][r] = 0.f;
        }
    }
}

// ---------------- fused update (+ next phi / readout tail), direct-B, barrier-light ----------------
// Phase 0 (staged, as before): [uv|vv] = v @ UVt -> uvv LDS.
// Norm precompute: norm(vv) -> bf16 hi/lo in LDS (freed B-staging area).
// Phase 1: h = silu([s|norm]@W1+b1) — A: s direct-global / norm LDS; B direct-global. No barriers.
// Phase 2: a = h@W2+b2 — A: H LDS; B direct. finupd in ct epilogues; sS -> bf16 LDS. No barriers.
// Phase 3: next-phi (TAIL=0) or readout (TAIL=1) — A: sS LDS; B direct. No barriers inside.
template<int TAIL>
__global__ __launch_bounds__(256) void updphi_kernel(
    float* __restrict__ s_io, float* __restrict__ v_io,
    const ushort_t* __restrict__ UVh, const ushort_t* __restrict__ UVl,
    const ushort_t* __restrict__ W1h, const ushort_t* __restrict__ W1l,
    const float* __restrict__ b1,
    const ushort_t* __restrict__ W2h, const ushort_t* __restrict__ W2l,
    const float* __restrict__ b2,
    const ushort_t* __restrict__ XW1h, const ushort_t* __restrict__ XW1l,
    const float* __restrict__ xb1,
    const ushort_t* __restrict__ XW2h, const ushort_t* __restrict__ XW2l,
    const float* __restrict__ xb2,
    float* __restrict__ phi_out,
    const float* __restrict__ w2ro, const float* __restrict__ b2ro,
    const int* __restrict__ mol, float* __restrict__ outp)
{
    __shared__ float uvv[96][261];                     // [ln*3+d][0:128 uv | 128:256 vv]
    __shared__ __align__(16) ushort_t NBh[256 * 40];   // phase0 B hi | then normH+normL (2x 32*136)
    __shared__ __align__(16) ushort_t NBl[256 * 40];   // phase0 B lo | then sSh+sSl   (2x 32*136)
    __shared__ __align__(16) unsigned char AH[17408];  // phase0 A staging | then H (hi+lo)
    __shared__ float molacc[128];                      // TAIL=1 only
    __shared__ float redl[32][4];                      // TAIL=1 only
    const int tid = threadIdx.x;
    const int wave = tid >> 6, lane = tid & 63;
    const int row_l = lane & 15, quad = lane >> 4;
    const int wn = wave * 32;
    const int m0 = blockIdx.x * 32;
    const int lrA = tid >> 3;          // 0..31
    const int ksA = (tid & 7) * 4;     // 0,4,..28

    ushort_t* normH = NBh;             // [32][136]
    ushort_t* normL = NBh + 32 * 136;
    ushort_t* sSh   = NBl;             // [32][136]
    ushort_t* sSl   = NBl + 32 * 136;
    ushort_t* Hh    = (ushort_t*)AH;   // [32][136]
    ushort_t* Hl    = Hh + 32 * 136;

    // ================= phase 0 (staged): [uv|vv] = v @ UVt (M=96, N=256, K=128) =================
    {
        ushort_t* A0h = (ushort_t*)AH;                 // [96][40]
        ushort_t* A0l = A0h + 96 * 40;
        f32x4 acc0[6][4];
        #pragma unroll
        for (int i = 0; i < 6; ++i)
            #pragma unroll
            for (int j = 0; j < 4; ++j)
                #pragma unroll
                for (int r = 0; r < 4; ++r) acc0[i][j][r] = 0.f;
        for (int k0 = 0; k0 < 128; k0 += 32) {
            #pragma unroll
            for (int g = 0; g < 3; ++g) {
                int row = g * 32 + lrA;
                float4 v = *(const float4*)&v_io[(size_t)(m0 * 3 + row) * 128 + k0 + ksA];
                float e[4] = {v.x, v.y, v.z, v.w};
                ushort_t ph[4], pl[4];
                #pragma unroll
                for (int t = 0; t < 4; ++t) {
                    ushort_t h = f2bf(e[t]);
                    ph[t] = h; pl[t] = f2bf(e[t] - bf2f(h));
                }
                *(uint2*)&A0h[row * 40 + ksA] = *(uint2*)ph;
                *(uint2*)&A0l[row * 40 + ksA] = *(uint2*)pl;
            }
            {
                const ushort_t* bh = &UVh[(size_t)tid * 128 + k0];
                const ushort_t* bl = &UVl[(size_t)tid * 128 + k0];
                *(uint4*)&NBh[tid * 40 + 0]  = *(const uint4*)(bh + 0);
                *(uint4*)&NBh[tid * 40 + 8]  = *(const uint4*)(bh + 8);
                *(uint4*)&NBh[tid * 40 + 16] = *(const uint4*)(bh + 16);
                *(uint4*)&NBh[tid * 40 + 24] = *(const uint4*)(bh + 24);
                *(uint4*)&NBl[tid * 40 + 0]  = *(const uint4*)(bl + 0);
                *(uint4*)&NBl[tid * 40 + 8]  = *(const uint4*)(bl + 8);
                *(uint4*)&NBl[tid * 40 + 16] = *(const uint4*)(bl + 16);
                *(uint4*)&NBl[tid * 40 + 24] = *(const uint4*)(bl + 24);
            }
            __syncthreads();
            bf16x8 a0h[6], a0l[6], b0h[4], b0l[4];
            #pragma unroll
            for (int i = 0; i < 6; ++i) {
                int ar = (i * 16 + row_l) * 40 + quad * 8;
                a0h[i] = *(const bf16x8*)&A0h[ar];
                a0l[i] = *(const bf16x8*)&A0l[ar];
            }
            #pragma unroll
            for (int j = 0; j < 4; ++j) {
                int br = (wave * 64 + j * 16 + row_l) * 40 + quad * 8;
                b0h[j] = *(const bf16x8*)&NBh[br];
                b0l[j] = *(const bf16x8*)&NBl[br];
            }
            #pragma unroll
            for (int i = 0; i < 6; ++i)
                #pragma unroll
                for (int j = 0; j < 4; ++j) {
                    acc0[i][j] = __builtin_amdgcn_mfma_f32_16x16x32_bf16(a0h[i], b0h[j], acc0[i][j], 0, 0, 0);
                    acc0[i][j] = __builtin_amdgcn_mfma_f32_16x16x32_bf16(a0h[i], b0l[j], acc0[i][j], 0, 0, 0);
                    acc0[i][j] = __builtin_amdgcn_mfma_f32_16x16x32_bf16(a0l[i], b0h[j], acc0[i][j], 0, 0, 0);
                }
            __syncthreads();
        }
        #pragma unroll
        for (int i = 0; i < 6; ++i)
            #pragma unroll
            for (int j = 0; j < 4; ++j)
                #pragma unroll
                for (int r = 0; r < 4; ++r)
                    uvv[i * 16 + quad * 4 + r][wave * 64 + j * 16 + row_l] = acc0[i][j][r];
        __syncthreads();
    }

    // ================= norm precompute: norm(vv) -> bf16 hi/lo (overwrites phase0 B area) =================
    {
        #pragma unroll
        for (int t = 0; t < 16; ++t) {
            int idx = t * 256 + tid;           // 0..4095
            int ln = idx >> 7, f = idx & 127;
            float x = uvv[ln * 3 + 0][128 + f];
            float y = uvv[ln * 3 + 1][128 + f];
            float z = uvv[ln * 3 + 2][128 + f];
            float nv = sqrtf(x * x + y * y + z * z + 1e-15f);
            ushort_t h = f2bf(nv);
            normH[ln * 136 + f] = h;
            normL[ln * 136 + f] = f2bf(nv - bf2f(h));
        }
        __syncthreads();
    }

    // ================= phase 1: h = silu([s | norm] @ W1 + b1) — NO barriers =================
    f32x4 acc[2][2];
    #pragma unroll
    for (int i = 0; i < 2; ++i)
        #pragma unroll
        for (int j = 0; j < 2; ++j)
            #pragma unroll
            for (int r = 0; r < 4; ++r) acc[i][j][r] = 0.f;

    #pragma unroll
    for (int it = 0; it < 8; ++it) {
        const int k0 = it * 32;
        bf16x8 ahf[2], alf[2], bhf[2], blf[2];
        if (k0 < 128) {
            #pragma unroll
            for (int i = 0; i < 2; ++i)
                split8(&s_io[(size_t)(m0 + i*16 + row_l) * 128 + k0 + quad*8], ahf[i], alf[i]);
        } else {
            #pragma unroll
            for (int i = 0; i < 2; ++i) {
                int off = (i * 16 + row_l) * 136 + (k0 - 128) + quad * 8;
                ahf[i] = *(const bf16x8*)&normH[off];
                alf[i] = *(const bf16x8*)&normL[off];
            }
        }
        #pragma unroll
        for (int j = 0; j < 2; ++j) {
            size_t br = (size_t)(wn + j*16 + row_l) * 256 + k0 + quad*8;
            bhf[j] = *(const bf16x8*)&W1h[br];
            blf[j] = *(const bf16x8*)&W1l[br];
        }
        #pragma unroll
        for (int i = 0; i < 2; ++i)
            #pragma unroll
            for (int j = 0; j < 2; ++j) {
                acc[i][j] = __builtin_amdgcn_mfma_f32_16x16x32_bf16(ahf[i], bhf[j], acc[i][j], 0, 0, 0);
                acc[i][j] = __builtin_amdgcn_mfma_f32_16x16x32_bf16(ahf[i], blf[j], acc[i][j], 0, 0, 0);
                acc[i][j] = __builtin_amdgcn_mfma_f32_16x16x32_bf16(alf[i], bhf[j], acc[i][j], 0, 0, 0);
            }
    }
    // epilogue -> H (AH area; phase-0 A staging dead, nothing reads AH concurrently)
    #pragma unroll
    for (int j = 0; j < 2; ++j) {
        int col = wn + j * 16 + row_l;
        float bval = b1[col];
        #pragma unroll
        for (int i = 0; i < 2; ++i)
            #pragma unroll
            for (int r = 0; r < 4; ++r) {
                int row = i * 16 + quad * 4 + r;
                float v = silu_f(acc[i][j][r] + bval);
                ushort_t h = f2bf(v);
                Hh[row * 136 + col] = h;
                Hl[row * 136 + col] = f2bf(v - bf2f(h));
            }
    }
    __syncthreads();

    // ================= phase 2: a = h @ W2 + b2, finupd in ct epilogues — NO barriers =================
    constexpr int CT0 = TAIL ? 1 : 0;          // TAIL=1: a_vv unused (v dead) -> skip ct0
    constexpr int NIT2 = (3 - CT0) * 4;
    #pragma unroll
    for (int i = 0; i < 2; ++i)
        #pragma unroll
        for (int j = 0; j < 2; ++j)
            #pragma unroll
            for (int r = 0; r < 4; ++r) acc[i][j][r] = 0.f;
    f32x4 ssum[2][2];

    #pragma unroll
    for (int it = 0; it < NIT2; ++it) {
        const int k0 = (it & 3) * 32;
        const int ct = CT0 + (it >> 2);
        bf16x8 ahf[2], alf[2], bhf[2], blf[2];
        #pragma unroll
        for (int i = 0; i < 2; ++i) {
            int ar = (i * 16 + row_l) * 136 + k0 + quad * 8;
            ahf[i] = *(const bf16x8*)&Hh[ar];
            alf[i] = *(const bf16x8*)&Hl[ar];
        }
        #pragma unroll
        for (int j = 0; j < 2; ++j) {
            size_t br = (size_t)(ct * 128 + wn + j*16 + row_l) * 128 + k0 + quad*8;
            bhf[j] = *(const bf16x8*)&W2h[br];
            blf[j] = *(const bf16x8*)&W2l[br];
        }
        #pragma unroll
        for (int i = 0; i < 2; ++i)
            #pragma unroll
            for (int j = 0; j < 2; ++j) {
                acc[i][j] = __builtin_amdgcn_mfma_f32_16x16x32_bf16(ahf[i], bhf[j], acc[i][j], 0, 0, 0);
                acc[i][j] = __builtin_amdgcn_mfma_f32_16x16x32_bf16(ahf[i], blf[j], acc[i][j], 0, 0, 0);
                acc[i][j] = __builtin_amdgcn_mfma_f32_16x16x32_bf16(alf[i], bhf[j], acc[i][j], 0, 0, 0);
            }
        if ((it & 3) == 3) {                     // column-tile epilogue + finupd slice
            #pragma unroll
            for (int j = 0; j < 2; ++j) {
                int f = wn + j * 16 + row_l;
                float bval = b2[ct * 128 + f];
                #pragma unroll
                for (int i = 0; i < 2; ++i)
                    #pragma unroll
                    for (int r = 0; r < 4; ++r) {
                        int ln = i * 16 + quad * 4 + r;
                        float a = acc[i][j][r] + bval;
                        if (ct == 0) {                      // a_vv: v += uv * a
                            size_t vb = (size_t)(m0 + ln) * 3 * F + f;
                            v_io[vb]         += uvv[ln * 3 + 0][f] * a;
                            v_io[vb + F]     += uvv[ln * 3 + 1][f] * a;
                            v_io[vb + 2 * F] += uvv[ln * 3 + 2][f] * a;
                        } else if (ct == 1) {               // a_sv: ssum = <uv,vv> * a
                            float dot = uvv[ln * 3 + 0][f] * uvv[ln * 3 + 0][128 + f]
                                      + uvv[ln * 3 + 1][f] * uvv[ln * 3 + 1][128 + f]
                                      + uvv[ln * 3 + 2][f] * uvv[ln * 3 + 2][128 + f];
                            ssum[i][j][r] = dot * a;
                        } else {                            // a_ss: s_new = s + ssum + a
                            float sv = s_io[(size_t)(m0 + ln) * F + f] + ssum[i][j][r] + a;
                            if constexpr (TAIL == 0) s_io[(size_t)(m0 + ln) * F + f] = sv;
                            ushort_t h = f2bf(sv);
                            sSh[ln * 136 + f] = h;          // own LDS area (no uvv overlay hazard)
                            sSl[ln * 136 + f] = f2bf(sv - bf2f(h));
                        }
                    }
            }
            #pragma unroll
            for (int i = 0; i < 2; ++i)
                #pragma unroll
                for (int j = 0; j < 2; ++j)
                    #pragma unroll
                    for (int r = 0; r < 4; ++r) acc[i][j][r] = 0.f;
        }
    }
    __syncthreads();                             // sS visible to all waves

    // ================= phase 3: next-phi (TAIL=0) or readout (TAIL=1), A = sS =================
    if constexpr (TAIL == 1) { if (tid < 128) molacc[tid] = 0.f; }

    #pragma unroll
    for (int i = 0; i < 2; ++i)
        #pragma unroll
        for (int j = 0; j < 2; ++j)
            #pragma unroll
            for (int r = 0; r < 4; ++r) acc[i][j][r] = 0.f;

    #pragma unroll
    for (int it = 0; it < 4; ++it) {
        const int k0 = it * 32;
        bf16x8 ahf[2], alf[2], bhf[2], blf[2];
        #pragma unroll
        for (int i = 0; i < 2; ++i) {
            int off = (i * 16 + row_l) * 136 + k0 + quad * 8;
            ahf[i] = *(const bf16x8*)&sSh[off];
            alf[i] = *(const bf16x8*)&sSl[off];
        }
        #pragma unroll
        for (int j = 0; j < 2; ++j) {
            size_t br = (size_t)(wn + j*16 + row_l) * 128 + k0 + quad*8;
            bhf[j] = *(const bf16x8*)&XW1h[br];
            blf[j] = *(const bf16x8*)&XW1l[br];
        }
        #pragma unroll
        for (int i = 0; i < 2; ++i)
            #pragma unroll
            for (int j = 0; j < 2; ++j) {
                acc[i][j] = __builtin_amdgcn_mfma_f32_16x16x32_bf16(ahf[i], bhf[j], acc[i][j], 0, 0, 0);
                acc[i][j] = __builtin_amdgcn_mfma_f32_16x16x32_bf16(ahf[i], blf[j], acc[i][j], 0, 0, 0);
                acc[i][j] = __builtin_amdgcn_mfma_f32_16x16x32_bf16(alf[i], bhf[j], acc[i][j], 0, 0, 0);
            }
    }

    if constexpr (TAIL == 0) {
        // -> H (phase-2 H reads all done at the post-phase-2 barrier), barrier, stage 2
        #pragma unroll
        for (int j = 0; j < 2; ++j) {
            int col = wn + j * 16 + row_l;
            float bval = xb1[col];
            #pragma unroll
            for (int i = 0; i < 2; ++i)
                #pragma unroll
                for (int r = 0; r < 4; ++r) {
                    int row = i * 16 + quad * 4 + r;
                    float v = silu_f(acc[i][j][r] + bval);
                    ushort_t h = f2bf(v);
                    Hh[row * 136 + col] = h;
                    Hl[row * 136 + col] = f2bf(v - bf2f(h));
                }
        }
        __syncthreads();
        #pragma unroll
        for (int i = 0; i < 2; ++i)
            #pragma unroll
            for (int j = 0; j < 2; ++j)
                #pragma unroll
                for (int r = 0; r < 4; ++r) acc[i][j][r] = 0.f;
        #pragma unroll
        for (int it = 0; it < 12; ++it) {
            const int k0 = (it & 3) * 32;
            const int ct = it >> 2;
            bf16x8 ahf[2], alf[2], bhf[2], blf[2];
            #pragma unroll
            for (int i = 0; i < 2; ++i) {
                int ar = (i * 16 + row_l) * 136 + k0 + quad * 8;
                ahf[i] = *(const bf16x8*)&Hh[ar];
                alf[i] = *(const bf16x8*)&Hl[ar];
            }
            #pragma unroll
            for (int j = 0; j < 2; ++j) {
                size_t br = (size_t)(ct * 128 + wn + j*16 + row_l) * 128 + k0 + quad*8;
                bhf[j] = *(const bf16x8*)&XW2h[br];
                blf[j] = *(const bf16x8*)&XW2l[br];
            }
            #pragma unroll
            for (int i = 0; i < 2; ++i)
                #pragma unroll
                for (int j = 0; j < 2; ++j) {
                    acc[i][j] = __builtin_amdgcn_mfma_f32_16x16x32_bf16(ahf[i], bhf[j], acc[i][j], 0, 0, 0);
                    acc[i][j] = __builtin_amdgcn_mfma_f32_16x16x32_bf16(ahf[i], blf[j], acc[i][j], 0, 0, 0);
                    acc[i][j] = __builtin_amdgcn_mfma_f32_16x16x32_bf16(alf[i], bhf[j], acc[i][j], 0, 0, 0);
                }
            if ((it & 3) == 3) {
                #pragma unroll
                for (int j = 0; j < 2; ++j) {
                    int col = ct * 128 + wn + j * 16 + row_l;
                    float bval = xb2[col];
                    #pragma unroll
                    for (int i = 0; i < 2; ++i)
                        #pragma unroll
                        for (int r = 0; r < 4; ++r) {
                            int row = i * 16 + quad * 4 + r;
                            phi_out[(size_t)(m0 + row) * 384 + col] = acc[i][j][r] + bval;
                        }
                }
                #pragma unroll
                for (int i = 0; i < 2; ++i)
                    #pragma unroll
                    for (int j = 0; j < 2; ++j)
                        #pragma unroll
                        for (int r = 0; r < 4; ++r) acc[i][j][r] = 0.f;
            }
        }
    } else {
        // readout: atom_e = sum_{col<64} silu(acc+robias)·w2 ; block mol table -> out
        float part[2][4];
        #pragma unroll
        for (int i = 0; i < 2; ++i)
            #pragma unroll
            for (int r = 0; r < 4; ++r) part[i][r] = 0.f;
        #pragma unroll
        for (int j = 0; j < 2; ++j) {
            int col = wn + j * 16 + row_l;
            float bv = xb1[col];                       // robias (zero-padded)
            float wv = (col < 64) ? w2ro[col] : 0.f;
            #pragma unroll
            for (int i = 0; i < 2; ++i)
                #pragma unroll
                for (int r = 0; r < 4; ++r)
                    part[i][r] += silu_f(acc[i][j][r] + bv) * wv;
        }
        #pragma unroll
        for (int o = 1; o < 16; o <<= 1)
            #pragma unroll
            for (int i = 0; i < 2; ++i)
                #pragma unroll
                for (int r = 0; r < 4; ++r)
                    part[i][r] += __shfl_xor(part[i][r], o);
        if (row_l == 0)
            #pragma unroll
            for (int i = 0; i < 2; ++i)
                #pragma unroll
                for (int r = 0; r < 4; ++r)
                    redl[i * 16 + quad * 4 + r][wave] = part[i][r];
        __syncthreads();
        if (tid < 32) {
            int n = m0 + tid;
            if (n < N_ATOMS) {
                float e = redl[tid][0] + redl[tid][1] + redl[tid][2] + redl[tid][3] + b2ro[0];
                atomicAdd(&molacc[mol[n]], e);
            }
        }
        __syncthreads();
        if (tid < 100 && molacc[tid] != 0.f) atomicAdd(&outp[tid], molacc[tid]);
    }
}

// ---------------- atom-centric message gather (atomic-free, packed records; phi f32) ----------------
template<int ZVIN>
__global__ __launch_bounds__(128) void msg_gather(
    const float* __restrict__ phi, const float* __restrict__ rec,
    const float* __restrict__ rbf_w, const float* __restrict__ rbf_b,
    const float* __restrict__ v_in, float* __restrict__ s,
    float* __restrict__ v_out, const int* __restrict__ offsets,
    const int* __restrict__ cnt)
{
    const int n = blockIdx.x, tid = threadIdx.x;
    float W0[N_RBF], W1[N_RBF], W2[N_RBF];
    #pragma unroll
    for (int k = 0; k < N_RBF; ++k) {
        W0[k] = rbf_w[k*3*F + tid];
        W1[k] = rbf_w[k*3*F + F + tid];
        W2[k] = rbf_w[k*3*F + 2*F + tid];
    }
    const float b0 = rbf_b[tid], b1 = rbf_b[F + tid], b2 = rbf_b[2*F + tid];
    float ds = 0.f, dvx = 0.f, dvy = 0.f, dvz = 0.f;
    const int off = offsets[n], c = cnt[n];
    const float* r = rec + (size_t)off * REC;
    #pragma unroll 4
    for (int t = 0; t < c; ++t, r += REC) {
        int j = __float_as_int(r[0]);
        float ev = r[1];
        float ux = r[2], uy = r[3], uz = r[4];
        float w0 = b0 * ev, w1 = b1 * ev, w2 = b2 * ev;
        #pragma unroll
        for (int k = 0; k < N_RBF; ++k) {
            float rk = r[5 + k];
            w0 += rk * W0[k]; w1 += rk * W1[k]; w2 += rk * W2[k];
        }
        const float* prow = phi + (size_t)j * 3 * F;
        float s0 = prow[tid] * w0;
        float s1 = prow[F + tid] * w1;
        float s2 = prow[2*F + tid] * w2;
        ds  += s1;
        if constexpr (ZVIN) {
            dvx += s2*ux; dvy += s2*uy; dvz += s2*uz;
        } else {
            const float* vrow = v_in + (size_t)j * 3 * F;
            dvx += s2*ux + s0 * vrow[tid];
            dvy += s2*uy + s0 * vrow[F + tid];
            dvz += s2*uz + s0 * vrow[2*F + tid];
        }
    }
    s[(size_t)n * F + tid] += ds;
    size_t vb = (size_t)n * 3 * F + tid;
    if constexpr (ZVIN) {
        v_out[vb]       = dvx;
        v_out[vb + F]   = dvy;
        v_out[vb + 2*F] = dvz;
    } else {
        v_out[vb]       = v_in[vb]       + dvx;
        v_out[vb + F]   = v_in[vb + F]   + dvy;
        v_out[vb + 2*F] = v_in[vb + 2*F] + dvz;
    }
}

extern "C" void kernel_launch(void* const* d_in, const int* in_sizes, int n_in,
                              void* d_out, int out_size, void* d_ws, size_t ws_size,
                              hipStream_t stream)
{
    const float* xyz    = (const float*)d_in[0];
    const float* emb    = (const float*)d_in[1];
    const float* msg_w1 = (const float*)d_in[2];
    const float* msg_b1 = (const float*)d_in[3];
    const float* msg_w2 = (const float*)d_in[4];
    const float* msg_b2 = (const float*)d_in[5];
    const float* rbf_w  = (const float*)d_in[6];
    const float* rbf_b  = (const float*)d_in[7];
    const float* upd_u  = (const float*)d_in[8];
    const float* upd_v  = (const float*)d_in[9];
    const float* upd_w1 = (const float*)d_in[10];
    const float* upd_b1 = (const float*)d_in[11];
    const float* upd_w2 = (const float*)d_in[12];
    const float* upd_b2 = (const float*)d_in[13];
    const float* ro_w1  = (const float*)d_in[14];
    const float* ro_b1  = (const float*)d_in[15];
    const float* ro_w2  = (const float*)d_in[16];
    const float* ro_b2  = (const float*)d_in[17];
    const int*   z      = (const int*)d_in[18];
    const int*   nbrs   = (const int*)d_in[19];
    const int*   molidx = (const int*)d_in[20];
    float* out = (float*)d_out;

    float* ws = (float*)d_ws;
    size_t off = 0;
    auto alloc = [&](size_t n) { float* p = ws + off; off += n; return p; };
    float* s_buf   = alloc(NFC);
    float* v1_buf  = alloc(3 * NFC);       // [n][3][f]
    float* v2_buf  = alloc(3 * NFC);
    float* phi_buf = alloc(3 * NFC);       // f32 [n][384]
    float* envb    = alloc(N_EDGES);
    float* edgerec = alloc((size_t)N_EDGES * REC);
    ushort_t* wbf_hi = (ushort_t*)alloc(WPREP_W / 2 + 64);
    ushort_t* wbf_lo = (ushort_t*)alloc(WPREP_W / 2 + 64);
    float* robias   = alloc(128);
    int* cnt        = (int*)alloc(N_ATOMS);
    int* cursor     = (int*)alloc(N_ATOMS);   // adjacent to cnt (zeroed together)
    int* offsets    = (int*)alloc(N_ATOMS);

    // bf16 weight sub-offsets (elements, see prep_kernel)
    const size_t oW1 = 0, oW2 = 49152, oUV = 196608, oU1 = 294912, oU2 = 393216, oRO = 540672;

    prep_kernel<<<dim3((PREP_TOTAL + 255) / 256), dim3(256), 0, stream>>>(
        emb, z, s_buf,
        msg_w1, msg_w2, upd_u, upd_v, upd_w1, upd_w2, ro_w1, ro_b1,
        wbf_hi, wbf_lo, robias, cnt);
    count_kernel<<<dim3((N_EDGES + 255) / 256), dim3(256), 0, stream>>>(
        xyz, nbrs, envb, cnt);
    scan_kernel<<<dim3(1), dim3(1024), 0, stream>>>(cnt, offsets, out);
    build_kernel<<<dim3((N_EDGES + 255) / 256), dim3(256), 0, stream>>>(
        xyz, nbrs, envb, offsets, cursor, edgerec);

    // phi_0 = silu(s@W1+b1)@W2+b2 (f32 out)
    phi0_kernel<<<dim3(NP/32), dim3(256), 0, stream>>>(
        s_buf,
        wbf_hi + oW1, wbf_lo + oW1, msg_b1,
        wbf_hi + oW2, wbf_lo + oW2, msg_b2,
        phi_buf);

    float* vin = v1_buf;
    float* vout = v2_buf;
    for (int i = 0; i < 3; ++i) {
        if (i == 0)
            msg_gather<1><<<dim3(N_ATOMS), dim3(128), 0, stream>>>(
                phi_buf, edgerec, rbf_w + (size_t)i*N_RBF*3*F, rbf_b + (size_t)i*3*F,
                vin, s_buf, vout, offsets, cnt);
        else
            msg_gather<0><<<dim3(N_ATOMS), dim3(128), 0, stream>>>(
                phi_buf, edgerec, rbf_w + (size_t)i*N_RBF*3*F, rbf_b + (size_t)i*3*F,
                vin, s_buf, vout, offsets, cnt);
        if (i < 2) {
            // upd(i) + phi(i+1) fused
            updphi_kernel<0><<<dim3(NP/32), dim3(256), 0, stream>>>(
                s_buf, vout,
                wbf_hi + oUV + (size_t)i*32768, wbf_lo + oUV + (size_t)i*32768,
                wbf_hi + oU1 + (size_t)i*32768, wbf_lo + oU1 + (size_t)i*32768,
                upd_b1 + (size_t)i*F,
                wbf_hi + oU2 + (size_t)i*49152, wbf_lo + oU2 + (size_t)i*49152,
                upd_b2 + (size_t)i*3*F,
                wbf_hi + oW1 + (size_t)(i+1)*16384, wbf_lo + oW1 + (size_t)(i+1)*16384,
                msg_b1 + (size_t)(i+1)*F,
                wbf_hi + oW2 + (size_t)(i+1)*49152, wbf_lo + oW2 + (size_t)(i+1)*49152,
                msg_b2 + (size_t)(i+1)*3*F,
                phi_buf,
                nullptr, nullptr, nullptr, nullptr);
        } else {
            // upd(2) + readout + mol reduce fused
            updphi_kernel<1><<<dim3(NP/32), dim3(256), 0, stream>>>(
                s_buf, vout,
                wbf_hi + oUV + (size_t)i*32768, wbf_lo + oUV + (size_t)i*32768,
                wbf_hi + oU1 + (size_t)i*32768, wbf_lo + oU1 + (size_t)i*32768,
                upd_b1 + (size_t)i*F,
                wbf_hi + oU2 + (size_t)i*49152, wbf_lo + oU2 + (size_t)i*49152,
                upd_b2 + (size_t)i*3*F,
                wbf_hi + oRO, wbf_lo + oRO, robias,
                nullptr, nullptr, nullptr,
                nullptr,
                ro_w2, ro_b2, molidx, out);
        }
        float* tmp = vin; vin = vout; vout = tmp;
    }
}

// Round 10
// 405.138 us; speedup vs baseline: 1.0110x; 1.0110x over previous
//
#include <hip/hip_runtime.h>

static constexpr int F = 128;
static constexpr int N_RBF = 20;
static constexpr int N_ATOMS = 8000;
static constexpr int NP = 8064;          // padded to 128
static constexpr int N_EDGES = 160000;
static constexpr int N_MOLS = 100;
static constexpr float CUTOFF = 5.0f;
static constexpr size_t NFC = (size_t)NP * F;
static constexpr int REC = 28;           // j, ev, ux,uy,uz, rbf[20], pad[3]
#define PIF 3.14159265358979323846f

typedef __attribute__((ext_vector_type(8))) short bf16x8;
typedef __attribute__((ext_vector_type(4))) float f32x4;
typedef unsigned short ushort_t;
typedef unsigned int uint_t;

__device__ __forceinline__ float silu_f(float x) { return x / (1.f + __expf(-x)); }

__device__ __forceinline__ ushort_t f2bf(float x) {   // round-to-nearest-even
    union { float f; uint_t u; } v; v.f = x;
    uint_t r = v.u + 0x7fffu + ((v.u >> 16) & 1u);
    return (ushort_t)(r >> 16);
}
__device__ __forceinline__ float bf2f(ushort_t h) {
    union { uint_t u; float f; } v; v.u = ((uint_t)h) << 16; return v.f;
}

// Lessons:
//  - r6: phi/v/s inter-layer activations MUST stay f32 (bf16 phi -> 49% output error).
//  - r7/r9: ILP tricks (2-deep prefetch, direct-B at 1 block/CU) REGRESS — kernel is
//    LATENCY-bound with zero TLP (MfmaUtil 6-10%, VALU 8-12%, HBM 7-12%).
//  - r5: edge-gather must stay its own high-occupancy dispatch.
//  - THIS ROUND: TLP, not ILP. 16 atoms/block -> 504 blocks -> 2 blocks/CU.
//    LDS cut to ~68KB by dropping ALL A/B staging (direct global loads; per-block
//    A tiles fit L1, weights fit L2); only uvv/H/sS live in LDS; ~4 barriers total.

// ---------------- pass 1: distance + envelope + live-edge histogram ----------------
__global__ __launch_bounds__(256) void count_kernel(
    const float* __restrict__ xyz, const int* __restrict__ nbrs,
    float* __restrict__ envb, int* __restrict__ cnt)
{
    int e = blockIdx.x * 256 + threadIdx.x;
    if (e >= N_EDGES) return;
    int i0 = nbrs[2*e+0], i1 = nbrs[2*e+1];
    float dx = xyz[3*i1+0] - xyz[3*i0+0];
    float dy = xyz[3*i1+1] - xyz[3*i0+1];
    float dz = xyz[3*i1+2] - xyz[3*i0+2];
    float d  = sqrtf(dx*dx + dy*dy + dz*dz);
    float ev = (d <= CUTOFF) ? 0.5f*(cosf(PIF*d/CUTOFF) + 1.f) : 0.f;
    envb[e] = ev;
    if (ev > 0.f) atomicAdd(&cnt[i0], 1);
}

// ---------------- exclusive scan of 8000 counters (single block) + zero out ----------------
__global__ __launch_bounds__(1024) void scan_kernel(
    const int* __restrict__ cnt, int* __restrict__ offsets, float* __restrict__ out)
{
    __shared__ int sums[1024];
    int tid = threadIdx.x;
    if (tid < N_MOLS) out[tid] = 0.f;
    int base = tid * 8;
    int local[8]; int s = 0;
    #pragma unroll
    for (int i = 0; i < 8; ++i) {
        int idx = base + i;
        local[i] = (idx < N_ATOMS) ? cnt[idx] : 0;
        s += local[i];
    }
    sums[tid] = s;
    __syncthreads();
    for (int d = 1; d < 1024; d <<= 1) {
        int v = (tid >= d) ? sums[tid - d] : 0;
        __syncthreads();
        sums[tid] += v;
        __syncthreads();
    }
    int ex = (tid == 0) ? 0 : sums[tid - 1];
    #pragma unroll
    for (int i = 0; i < 8; ++i) {
        int idx = base + i;
        if (idx < N_ATOMS) { offsets[idx] = ex; ex += local[i]; }
    }
}

// ---------------- pass 2: build packed records for LIVE edges only ----------------
__global__ __launch_bounds__(256) void build_kernel(
    const float* __restrict__ xyz, const int* __restrict__ nbrs,
    const float* __restrict__ envb, const int* __restrict__ offsets,
    int* __restrict__ cursor, float* __restrict__ rec)
{
    int e = blockIdx.x * 256 + threadIdx.x;
    if (e >= N_EDGES) return;
    float ev = envb[e];
    if (ev <= 0.f) return;
    int i0 = nbrs[2*e+0], i1 = nbrs[2*e+1];
    float dx = xyz[3*i1+0] - xyz[3*i0+0];
    float dy = xyz[3*i1+1] - xyz[3*i0+1];
    float dz = xyz[3*i1+2] - xyz[3*i0+2];
    float d  = sqrtf(dx*dx + dy*dy + dz*dz);
    float inv = 1.f / d;
    int pos = offsets[i0] + atomicAdd(&cursor[i0], 1);
    float* r = rec + (size_t)pos * REC;
    r[0] = __int_as_float(i1);
    r[1] = ev;
    r[2] = dx*inv; r[3] = dy*inv; r[4] = dz*inv;
    float base = PIF*d/CUTOFF;
    float sc = inv * ev;   // fold env into rbf
    #pragma unroll
    for (int k = 0; k < N_RBF; ++k)
        r[5 + k] = sinf((float)(k+1)*base) * sc;
}

// ---------------- fused prep: embed + weight transpose/split + zero cnt/cursor ----------------
static constexpr int WPREP_W = 557056;
static constexpr int WPREP_TOTAL = 557184;
static constexpr int NATF = N_ATOMS * F;
static constexpr int PREP_TOTAL = NATF + WPREP_TOTAL + 2 * N_ATOMS;
__global__ __launch_bounds__(256) void prep_kernel(
    const float* __restrict__ emb, const int* __restrict__ z, float* __restrict__ s,
    const float* __restrict__ msg_w1, const float* __restrict__ msg_w2,
    const float* __restrict__ upd_u,  const float* __restrict__ upd_v,
    const float* __restrict__ upd_w1, const float* __restrict__ upd_w2,
    const float* __restrict__ ro_w1,  const float* __restrict__ ro_b1,
    ushort_t* __restrict__ dhi, ushort_t* __restrict__ dlo,
    float* __restrict__ robias, int* __restrict__ cntz)
{
    int gidx = blockIdx.x * 256 + threadIdx.x;
    if (gidx < NATF) {                          // s = emb_table[z]
        int n = gidx >> 7, f = gidx & 127;
        s[gidx] = emb[z[n]*F + f];
        return;
    }
    int idx = gidx - NATF;
    if (idx >= WPREP_TOTAL) {                   // zero cnt + cursor (adjacent)
        cntz[idx - WPREP_TOTAL] = 0;
        return;
    }
    if (idx >= WPREP_W) {
        int l = idx - WPREP_W;
        robias[l] = (l < 64) ? ro_b1[l] : 0.f;
        return;
    }
    float val;
    if (idx < 540672) {
        const float* src; int K, N, rem;
        if (idx < 49152)       { int l = idx;          int c = l / 16384; rem = l % 16384; K = 128; N = 128; src = msg_w1 + c * 16384; }
        else if (idx < 196608) { int l = idx - 49152;  int c = l / 49152; rem = l % 49152; K = 128; N = 384; src = msg_w2 + c * 49152; }
        else if (idx < 294912) { int l = idx - 196608; int c = l / 32768; rem = l % 32768; K = 128; N = 128;
                                 if (rem < 16384) src = upd_u + c * 16384;
                                 else { src = upd_v + c * 16384; rem -= 16384; } }
        else if (idx < 393216) { int l = idx - 294912; int c = l / 32768; rem = l % 32768; K = 256; N = 128; src = upd_w1 + c * 32768; }
        else                   { int l = idx - 393216; int c = l / 49152; rem = l % 49152; K = 128; N = 384; src = upd_w2 + c * 49152; }
        int n = rem / K, k = rem % K;
        val = src[k * N + n];
    } else {
        int l = idx - 540672;             // ro_w1 pad: [n][k], n>=64 -> 0
        int n = l >> 7, k = l & 127;
        val = (n < 64) ? ro_w1[k * 64 + n] : 0.f;
    }
    ushort_t h = f2bf(val);
    dhi[idx] = h;
    dlo[idx] = f2bf(val - bf2f(h));
}

// helpers: f32 -> bf16 hi/lo fragments
__device__ __forceinline__ void split8(const float* __restrict__ p, bf16x8& hi, bf16x8& lo) {
    float4 a = *(const float4*)p;
    float4 b = *(const float4*)(p + 4);
    float e[8] = {a.x, a.y, a.z, a.w, b.x, b.y, b.z, b.w};
    ushort_t ph[8], pl[8];
    #pragma unroll
    for (int t = 0; t < 8; ++t) {
        ushort_t h = f2bf(e[t]);
        ph[t] = h; pl[t] = f2bf(e[t] - bf2f(h));
    }
    hi = *(bf16x8*)ph; lo = *(bf16x8*)pl;
}
__device__ __forceinline__ void split8v(const float* __restrict__ e, bf16x8& hi, bf16x8& lo) {
    ushort_t ph[8], pl[8];
    #pragma unroll
    for (int t = 0; t < 8; ++t) {
        ushort_t h = f2bf(e[t]);
        ph[t] = h; pl[t] = f2bf(e[t] - bf2f(h));
    }
    hi = *(bf16x8*)ph; lo = *(bf16x8*)pl;
}

// ---------------- phi0 (16 rows/block, direct operands, 1 barrier) ----------------
__global__ __launch_bounds__(256) void phi0_kernel(
    const float* __restrict__ sbuf,
    const ushort_t* __restrict__ W1h, const ushort_t* __restrict__ W1l,
    const float* __restrict__ b1,
    const ushort_t* __restrict__ W2h, const ushort_t* __restrict__ W2l,
    const float* __restrict__ b2,
    float* __restrict__ C)
{
    __shared__ __align__(16) ushort_t Hh[16 * 136], Hl[16 * 136];
    const int tid = threadIdx.x;
    const int wave = tid >> 6, lane = tid & 63;
    const int row_l = lane & 15, quad = lane >> 4;
    const int wn = wave * 32;
    const int m0 = blockIdx.x * 16;

    f32x4 acc[2];
    #pragma unroll
    for (int j = 0; j < 2; ++j)
        #pragma unroll
        for (int r = 0; r < 4; ++r) acc[j][r] = 0.f;

    #pragma unroll
    for (int it = 0; it < 4; ++it) {
        const int k0 = it * 32;
        bf16x8 ahf, alf, bhf[2], blf[2];
        split8(&sbuf[(size_t)(m0 + row_l) * 128 + k0 + quad*8], ahf, alf);
        #pragma unroll
        for (int j = 0; j < 2; ++j) {
            size_t br = (size_t)(wn + j*16 + row_l) * 128 + k0 + quad*8;
            bhf[j] = *(const bf16x8*)&W1h[br];
            blf[j] = *(const bf16x8*)&W1l[br];
        }
        #pragma unroll
        for (int j = 0; j < 2; ++j) {
            acc[j] = __builtin_amdgcn_mfma_f32_16x16x32_bf16(ahf, bhf[j], acc[j], 0, 0, 0);
            acc[j] = __builtin_amdgcn_mfma_f32_16x16x32_bf16(ahf, blf[j], acc[j], 0, 0, 0);
            acc[j] = __builtin_amdgcn_mfma_f32_16x16x32_bf16(alf, bhf[j], acc[j], 0, 0, 0);
        }
    }
    #pragma unroll
    for (int j = 0; j < 2; ++j) {
        int col = wn + j * 16 + row_l;
        float bval = b1[col];
        #pragma unroll
        for (int r = 0; r < 4; ++r) {
            int row = quad * 4 + r;
            float v = silu_f(acc[j][r] + bval);
            ushort_t h = f2bf(v);
            Hh[row * 136 + col] = h;
            Hl[row * 136 + col] = f2bf(v - bf2f(h));
        }
    }
    __syncthreads();

    #pragma unroll
    for (int j = 0; j < 2; ++j)
        #pragma unroll
        for (int r = 0; r < 4; ++r) acc[j][r] = 0.f;
    #pragma unroll
    for (int it = 0; it < 12; ++it) {
        const int k0 = (it & 3) * 32;
        const int ct = it >> 2;
        bf16x8 ahf, alf, bhf[2], blf[2];
        {
            int ar = row_l * 136 + k0 + quad * 8;
            ahf = *(const bf16x8*)&Hh[ar];
            alf = *(const bf16x8*)&Hl[ar];
        }
        #pragma unroll
        for (int j = 0; j < 2; ++j) {
            size_t br = (size_t)(ct * 128 + wn + j*16 + row_l) * 128 + k0 + quad*8;
            bhf[j] = *(const bf16x8*)&W2h[br];
            blf[j] = *(const bf16x8*)&W2l[br];
        }
        #pragma unroll
        for (int j = 0; j < 2; ++j) {
            acc[j] = __builtin_amdgcn_mfma_f32_16x16x32_bf16(ahf, bhf[j], acc[j], 0, 0, 0);
            acc[j] = __builtin_amdgcn_mfma_f32_16x16x32_bf16(ahf, blf[j], acc[j], 0, 0, 0);
            acc[j] = __builtin_amdgcn_mfma_f32_16x16x32_bf16(alf, bhf[j], acc[j], 0, 0, 0);
        }
        if ((it & 3) == 3) {
            #pragma unroll
            for (int j = 0; j < 2; ++j) {
                int col = ct * 128 + wn + j * 16 + row_l;
                float bval = b2[col];
                #pragma unroll
                for (int r = 0; r < 4; ++r) {
                    int row = quad * 4 + r;
                    C[(size_t)(m0 + row) * 384 + col] = acc[j][r] + bval;
                }
            }
            #pragma unroll
            for (int j = 0; j < 2; ++j)
                #pragma unroll
                for (int r = 0; r < 4; ++r) acc[j][r] = 0.f;
        }
    }
}

// ---------------- fused update (+ next phi / readout), 16 atoms/block, 2 blocks/CU ----------------
// Phase 0: [uv|vv] = v @ UVt (M=48) — all operands direct; epilogue -> uvv LDS. [barrier]
// Phase 1: h = silu([s|norm(vv)]@W1+b1) — s direct, norms on-the-fly from uvv, W direct
//          -> H LDS (wave-exclusive cols). [barrier]
// Phase 2: a = h@W2+b2 — H LDS, W direct; finupd in ct epilogues; s_new -> sS LDS (f32,
//          own region: no uvv overlay, avoids cross-wave race in barrier-free phases). [barrier]
// Phase 3: next-phi (TAIL=0, +1 barrier for H) or readout (TAIL=1).
template<int TAIL>
__global__ __launch_bounds__(256) void updphi_kernel(
    float* __restrict__ s_io, float* __restrict__ v_io,
    const ushort_t* __restrict__ UVh, const ushort_t* __restrict__ UVl,
    const ushort_t* __restrict__ W1h, const ushort_t* __restrict__ W1l,
    const float* __restrict__ b1,
    const ushort_t* __restrict__ W2h, const ushort_t* __restrict__ W2l,
    const float* __restrict__ b2,
    const ushort_t* __restrict__ XW1h, const ushort_t* __restrict__ XW1l,
    const float* __restrict__ xb1,
    const ushort_t* __restrict__ XW2h, const ushort_t* __restrict__ XW2l,
    const float* __restrict__ xb2,
    float* __restrict__ phi_out,
    const float* __restrict__ w2ro, const float* __restrict__ b2ro,
    const int* __restrict__ mol, float* __restrict__ outp)
{
    __shared__ float uvv[48][260];                    // [ln*3+d][0:128 uv | 128:256 vv]
    __shared__ float sS[16 * 132];                    // s_new (f32)
    __shared__ __align__(16) ushort_t Hh[16 * 136], Hl[16 * 136];
    __shared__ float molacc[128];                     // TAIL=1 only
    __shared__ float redl[16][4];                     // TAIL=1 only
    const int tid = threadIdx.x;
    const int wave = tid >> 6, lane = tid & 63;
    const int row_l = lane & 15, quad = lane >> 4;
    const int wn = wave * 32;
    const int m0 = blockIdx.x * 16;

    // ================= phase 0: [uv|vv] = v @ UVt (M=48, N=256, K=128), direct =================
    {
        f32x4 acc0[3][4];
        #pragma unroll
        for (int i = 0; i < 3; ++i)
            #pragma unroll
            for (int j = 0; j < 4; ++j)
                #pragma unroll
                for (int r = 0; r < 4; ++r) acc0[i][j][r] = 0.f;
        #pragma unroll
        for (int it = 0; it < 4; ++it) {
            const int k0 = it * 32;
            bf16x8 a0h[3], a0l[3], b0h[4], b0l[4];
            #pragma unroll
            for (int i = 0; i < 3; ++i)
                split8(&v_io[(size_t)(m0*3 + i*16 + row_l) * 128 + k0 + quad*8], a0h[i], a0l[i]);
            #pragma unroll
            for (int j = 0; j < 4; ++j) {
                size_t br = (size_t)(wave*64 + j*16 + row_l) * 128 + k0 + quad*8;
                b0h[j] = *(const bf16x8*)&UVh[br];
                b0l[j] = *(const bf16x8*)&UVl[br];
            }
            #pragma unroll
            for (int i = 0; i < 3; ++i)
                #pragma unroll
                for (int j = 0; j < 4; ++j) {
                    acc0[i][j] = __builtin_amdgcn_mfma_f32_16x16x32_bf16(a0h[i], b0h[j], acc0[i][j], 0, 0, 0);
                    acc0[i][j] = __builtin_amdgcn_mfma_f32_16x16x32_bf16(a0h[i], b0l[j], acc0[i][j], 0, 0, 0);
                    acc0[i][j] = __builtin_amdgcn_mfma_f32_16x16x32_bf16(a0l[i], b0h[j], acc0[i][j], 0, 0, 0);
                }
        }
        #pragma unroll
        for (int i = 0; i < 3; ++i)
            #pragma unroll
            for (int j = 0; j < 4; ++j)
                #pragma unroll
                for (int r = 0; r < 4; ++r)
                    uvv[i * 16 + quad * 4 + r][wave * 64 + j * 16 + row_l] = acc0[i][j][r];
        __syncthreads();
    }

    // ================= phase 1: h = silu([s | norm(vv)] @ W1 + b1), barrier-free =================
    f32x4 acc[2];
    #pragma unroll
    for (int j = 0; j < 2; ++j)
        #pragma unroll
        for (int r = 0; r < 4; ++r) acc[j][r] = 0.f;

    #pragma unroll
    for (int it = 0; it < 8; ++it) {
        const int k0 = it * 32;
        bf16x8 ahf, alf, bhf[2], blf[2];
        if (k0 < 128) {
            split8(&s_io[(size_t)(m0 + row_l) * 128 + k0 + quad*8], ahf, alf);
        } else {
            const int cb = k0 + quad * 8;            // uvv col (128..255)
            const float* p0 = &uvv[row_l * 3 + 0][cb];
            const float* p1 = &uvv[row_l * 3 + 1][cb];
            const float* p2 = &uvv[row_l * 3 + 2][cb];
            float4 x0 = *(const float4*)p0, x1 = *(const float4*)(p0 + 4);
            float4 y0 = *(const float4*)p1, y1 = *(const float4*)(p1 + 4);
            float4 z0 = *(const float4*)p2, z1 = *(const float4*)(p2 + 4);
            float e[8];
            e[0] = sqrtf(x0.x*x0.x + y0.x*y0.x + z0.x*z0.x + 1e-15f);
            e[1] = sqrtf(x0.y*x0.y + y0.y*y0.y + z0.y*z0.y + 1e-15f);
            e[2] = sqrtf(x0.z*x0.z + y0.z*y0.z + z0.z*z0.z + 1e-15f);
            e[3] = sqrtf(x0.w*x0.w + y0.w*y0.w + z0.w*z0.w + 1e-15f);
            e[4] = sqrtf(x1.x*x1.x + y1.x*y1.x + z1.x*z1.x + 1e-15f);
            e[5] = sqrtf(x1.y*x1.y + y1.y*y1.y + z1.y*z1.y + 1e-15f);
            e[6] = sqrtf(x1.z*x1.z + y1.z*y1.z + z1.z*z1.z + 1e-15f);
            e[7] = sqrtf(x1.w*x1.w + y1.w*y1.w + z1.w*z1.w + 1e-15f);
            split8v(e, ahf, alf);
        }
        #pragma unroll
        for (int j = 0; j < 2; ++j) {
            size_t br = (size_t)(wn + j*16 + row_l) * 256 + k0 + quad*8;
            bhf[j] = *(const bf16x8*)&W1h[br];
            blf[j] = *(const bf16x8*)&W1l[br];
        }
        #pragma unroll
        for (int j = 0; j < 2; ++j) {
            acc[j] = __builtin_amdgcn_mfma_f32_16x16x32_bf16(ahf, bhf[j], acc[j], 0, 0, 0);
            acc[j] = __builtin_amdgcn_mfma_f32_16x16x32_bf16(ahf, blf[j], acc[j], 0, 0, 0);
            acc[j] = __builtin_amdgcn_mfma_f32_16x16x32_bf16(alf, bhf[j], acc[j], 0, 0, 0);
        }
    }
    #pragma unroll
    for (int j = 0; j < 2; ++j) {
        int col = wn + j * 16 + row_l;
        float bval = b1[col];
        #pragma unroll
        for (int r = 0; r < 4; ++r) {
            int row = quad * 4 + r;
            float v = silu_f(acc[j][r] + bval);
            ushort_t h = f2bf(v);
            Hh[row * 136 + col] = h;
            Hl[row * 136 + col] = f2bf(v - bf2f(h));
        }
    }
    __syncthreads();     // H ready; also all phase-1 s_io reads done before phase-2 s writes

    // ================= phase 2: a = h @ W2 + b2, finupd in ct epilogues, barrier-free =================
    constexpr int CT0 = TAIL ? 1 : 0;          // TAIL=1: a_vv unused (v dead) -> skip ct0
    constexpr int NIT2 = (3 - CT0) * 4;
    #pragma unroll
    for (int j = 0; j < 2; ++j)
        #pragma unroll
        for (int r = 0; r < 4; ++r) acc[j][r] = 0.f;
    f32x4 ssum[2];

    #pragma unroll
    for (int it = 0; it < NIT2; ++it) {
        const int k0 = (it & 3) * 32;
        const int ct = CT0 + (it >> 2);
        bf16x8 ahf, alf, bhf[2], blf[2];
        {
            int ar = row_l * 136 + k0 + quad * 8;
            ahf = *(const bf16x8*)&Hh[ar];
            alf = *(const bf16x8*)&Hl[ar];
        }
        #pragma unroll
        for (int j = 0; j < 2; ++j) {
            size_t br = (size_t)(ct * 128 + wn + j*16 + row_l) * 128 + k0 + quad*8;
            bhf[j] = *(const bf16x8*)&W2h[br];
            blf[j] = *(const bf16x8*)&W2l[br];
        }
        #pragma unroll
        for (int j = 0; j < 2; ++j) {
            acc[j] = __builtin_amdgcn_mfma_f32_16x16x32_bf16(ahf, bhf[j], acc[j], 0, 0, 0);
            acc[j] = __builtin_amdgcn_mfma_f32_16x16x32_bf16(ahf, blf[j], acc[j], 0, 0, 0);
            acc[j] = __builtin_amdgcn_mfma_f32_16x16x32_bf16(alf, bhf[j], acc[j], 0, 0, 0);
        }
        if ((it & 3) == 3) {                     // column-tile epilogue + finupd slice
            #pragma unroll
            for (int j = 0; j < 2; ++j) {
                int f = wn + j * 16 + row_l;
                float bval = b2[ct * 128 + f];
                #pragma unroll
                for (int r = 0; r < 4; ++r) {
                    int ln = quad * 4 + r;
                    float a = acc[j][r] + bval;
                    if (ct == 0) {                      // a_vv: v += uv * a
                        size_t vb = (size_t)(m0 + ln) * 3 * F + f;
                        v_io[vb]         += uvv[ln * 3 + 0][f] * a;
                        v_io[vb + F]     += uvv[ln * 3 + 1][f] * a;
                        v_io[vb + 2 * F] += uvv[ln * 3 + 2][f] * a;
                    } else if (ct == 1) {               // a_sv: ssum = <uv,vv> * a
                        float dot = uvv[ln * 3 + 0][f] * uvv[ln * 3 + 0][128 + f]
                                  + uvv[ln * 3 + 1][f] * uvv[ln * 3 + 1][128 + f]
                                  + uvv[ln * 3 + 2][f] * uvv[ln * 3 + 2][128 + f];
                        ssum[j][r] = dot * a;
                    } else {                            // a_ss: s_new = s + ssum + a
                        float sv = s_io[(size_t)(m0 + ln) * F + f] + ssum[j][r] + a;
                        if constexpr (TAIL == 0) s_io[(size_t)(m0 + ln) * F + f] = sv;
                        sS[ln * 132 + f] = sv;
                    }
                }
            }
            #pragma unroll
            for (int j = 0; j < 2; ++j)
                #pragma unroll
                for (int r = 0; r < 4; ++r) acc[j][r] = 0.f;
        }
    }
    __syncthreads();                             // sS visible to all waves

    // ================= phase 3: next-phi (TAIL=0) or readout (TAIL=1), A = sS =================
    if constexpr (TAIL == 1) { if (tid < 128) molacc[tid] = 0.f; }

    #pragma unroll
    for (int j = 0; j < 2; ++j)
        #pragma unroll
        for (int r = 0; r < 4; ++r) acc[j][r] = 0.f;

    #pragma unroll
    for (int it = 0; it < 4; ++it) {
        const int k0 = it * 32;
        bf16x8 ahf, alf, bhf[2], blf[2];
        split8(&sS[row_l * 132 + k0 + quad * 8], ahf, alf);
        #pragma unroll
        for (int j = 0; j < 2; ++j) {
            size_t br = (size_t)(wn + j*16 + row_l) * 128 + k0 + quad*8;
            bhf[j] = *(const bf16x8*)&XW1h[br];
            blf[j] = *(const bf16x8*)&XW1l[br];
        }
        #pragma unroll
        for (int j = 0; j < 2; ++j) {
            acc[j] = __builtin_amdgcn_mfma_f32_16x16x32_bf16(ahf, bhf[j], acc[j], 0, 0, 0);
            acc[j] = __builtin_amdgcn_mfma_f32_16x16x32_bf16(ahf, blf[j], acc[j], 0, 0, 0);
            acc[j] = __builtin_amdgcn_mfma_f32_16x16x32_bf16(alf, bhf[j], acc[j], 0, 0, 0);
        }
    }

    if constexpr (TAIL == 0) {
        #pragma unroll
        for (int j = 0; j < 2; ++j) {
            int col = wn + j * 16 + row_l;
            float bval = xb1[col];
            #pragma unroll
            for (int r = 0; r < 4; ++r) {
                int row = quad * 4 + r;
                float v = silu_f(acc[j][r] + bval);
                ushort_t h = f2bf(v);
                Hh[row * 136 + col] = h;
                Hl[row * 136 + col] = f2bf(v - bf2f(h));
            }
        }
        __syncthreads();
        #pragma unroll
        for (int j = 0; j < 2; ++j)
            #pragma unroll
            for (int r = 0; r < 4; ++r) acc[j][r] = 0.f;
        #pragma unroll
        for (int it = 0; it < 12; ++it) {
            const int k0 = (it & 3) * 32;
            const int ct = it >> 2;
            bf16x8 ahf, alf, bhf[2], blf[2];
            {
                int ar = row_l * 136 + k0 + quad * 8;
                ahf = *(const bf16x8*)&Hh[ar];
                alf = *(const bf16x8*)&Hl[ar];
            }
            #pragma unroll
            for (int j = 0; j < 2; ++j) {
                size_t br = (size_t)(ct * 128 + wn + j*16 + row_l) * 128 + k0 + quad*8;
                bhf[j] = *(const bf16x8*)&XW2h[br];
                blf[j] = *(const bf16x8*)&XW2l[br];
            }
            #pragma unroll
            for (int j = 0; j < 2; ++j) {
                acc[j] = __builtin_amdgcn_mfma_f32_16x16x32_bf16(ahf, bhf[j], acc[j], 0, 0, 0);
                acc[j] = __builtin_amdgcn_mfma_f32_16x16x32_bf16(ahf, blf[j], acc[j], 0, 0, 0);
                acc[j] = __builtin_amdgcn_mfma_f32_16x16x32_bf16(alf, bhf[j], acc[j], 0, 0, 0);
            }
            if ((it & 3) == 3) {
                #pragma unroll
                for (int j = 0; j < 2; ++j) {
                    int col = ct * 128 + wn + j * 16 + row_l;
                    float bval = xb2[col];
                    #pragma unroll
                    for (int r = 0; r < 4; ++r) {
                        int row = quad * 4 + r;
                        phi_out[(size_t)(m0 + row) * 384 + col] = acc[j][r] + bval;
                    }
                }
                #pragma unroll
                for (int j = 0; j < 2; ++j)
                    #pragma unroll
                    for (int r = 0; r < 4; ++r) acc[j][r] = 0.f;
            }
        }
    } else {
        // readout: atom_e = sum_{col<64} silu(acc+robias)·w2 ; block mol table -> out
        float part[4];
        #pragma unroll
        for (int r = 0; r < 4; ++r) part[r] = 0.f;
        #pragma unroll
        for (int j = 0; j < 2; ++j) {
            int col = wn + j * 16 + row_l;
            float bv = xb1[col];                       // robias (zero-padded)
            float wv = (col < 64) ? w2ro[col] : 0.f;
            #pragma unroll
            for (int r = 0; r < 4; ++r)
                part[r] += silu_f(acc[j][r] + bv) * wv;
        }
        #pragma unroll
        for (int o = 1; o < 16; o <<= 1)
            #pragma unroll
            for (int r = 0; r < 4; ++r)
                part[r] += __shfl_xor(part[r], o);
        if (row_l == 0)
            #pragma unroll
            for (int r = 0; r < 4; ++r)
                redl[quad * 4 + r][wave] = part[r];
        __syncthreads();
        if (tid < 16) {
            int n = m0 + tid;
            if (n < N_ATOMS) {
                float e = redl[tid][0] + redl[tid][1] + redl[tid][2] + redl[tid][3] + b2ro[0];
                atomicAdd(&molacc[mol[n]], e);
            }
        }
        __syncthreads();
        if (tid < 100 && molacc[tid] != 0.f) atomicAdd(&outp[tid], molacc[tid]);
    }
}

// ---------------- atom-centric message gather (atomic-free, packed records; phi f32) ----------------
template<int ZVIN>
__global__ __launch_bounds__(128) void msg_gather(
    const float* __restrict__ phi, const float* __restrict__ rec,
    const float* __restrict__ rbf_w, const float* __restrict__ rbf_b,
    const float* __restrict__ v_in, float* __restrict__ s,
    float* __restrict__ v_out, const int* __restrict__ offsets,
    const int* __restrict__ cnt)
{
    const int n = blockIdx.x, tid = threadIdx.x;
    float W0[N_RBF], W1[N_RBF], W2[N_RBF];
    #pragma unroll
    for (int k = 0; k < N_RBF; ++k) {
        W0[k] = rbf_w[k*3*F + tid];
        W1[k] = rbf_w[k*3*F + F + tid];
        W2[k] = rbf_w[k*3*F + 2*F + tid];
    }
    const float b0 = rbf_b[tid], b1 = rbf_b[F + tid], b2 = rbf_b[2*F + tid];
    float ds = 0.f, dvx = 0.f, dvy = 0.f, dvz = 0.f;
    const int off = offsets[n], c = cnt[n];
    const float* r = rec + (size_t)off * REC;
    #pragma unroll 4
    for (int t = 0; t < c; ++t, r += REC) {
        int j = __float_as_int(r[0]);
        float ev = r[1];
        float ux = r[2], uy = r[3], uz = r[4];
        float w0 = b0 * ev, w1 = b1 * ev, w2 = b2 * ev;
        #pragma unroll
        for (int k = 0; k < N_RBF; ++k) {
            float rk = r[5 + k];
            w0 += rk * W0[k]; w1 += rk * W1[k]; w2 += rk * W2[k];
        }
        const float* prow = phi + (size_t)j * 3 * F;
        float s0 = prow[tid] * w0;
        float s1 = prow[F + tid] * w1;
        float s2 = prow[2*F + tid] * w2;
        ds  += s1;
        if constexpr (ZVIN) {
            dvx += s2*ux; dvy += s2*uy; dvz += s2*uz;
        } else {
            const float* vrow = v_in + (size_t)j * 3 * F;
            dvx += s2*ux + s0 * vrow[tid];
            dvy += s2*uy + s0 * vrow[F + tid];
            dvz += s2*uz + s0 * vrow[2*F + tid];
        }
    }
    s[(size_t)n * F + tid] += ds;
    size_t vb = (size_t)n * 3 * F + tid;
    if constexpr (ZVIN) {
        v_out[vb]       = dvx;
        v_out[vb + F]   = dvy;
        v_out[vb + 2*F] = dvz;
    } else {
        v_out[vb]       = v_in[vb]       + dvx;
        v_out[vb + F]   = v_in[vb + F]   + dvy;
        v_out[vb + 2*F] = v_in[vb + 2*F] + dvz;
    }
}

extern "C" void kernel_launch(void* const* d_in, const int* in_sizes, int n_in,
                              void* d_out, int out_size, void* d_ws, size_t ws_size,
                              hipStream_t stream)
{
    const float* xyz    = (const float*)d_in[0];
    const float* emb    = (const float*)d_in[1];
    const float* msg_w1 = (const float*)d_in[2];
    const float* msg_b1 = (const float*)d_in[3];
    const float* msg_w2 = (const float*)d_in[4];
    const float* msg_b2 = (const float*)d_in[5];
    const float* rbf_w  = (const float*)d_in[6];
    const float* rbf_b  = (const float*)d_in[7];
    const float* upd_u  = (const float*)d_in[8];
    const float* upd_v  = (const float*)d_in[9];
    const float* upd_w1 = (const float*)d_in[10];
    const float* upd_b1 = (const float*)d_in[11];
    const float* upd_w2 = (const float*)d_in[12];
    const float* upd_b2 = (const float*)d_in[13];
    const float* ro_w1  = (const float*)d_in[14];
    const float* ro_b1  = (const float*)d_in[15];
    const float* ro_w2  = (const float*)d_in[16];
    const float* ro_b2  = (const float*)d_in[17];
    const int*   z      = (const int*)d_in[18];
    const int*   nbrs   = (const int*)d_in[19];
    const int*   molidx = (const int*)d_in[20];
    float* out = (float*)d_out;

    float* ws = (float*)d_ws;
    size_t off = 0;
    auto alloc = [&](size_t n) { float* p = ws + off; off += n; return p; };
    float* s_buf   = alloc(NFC);
    float* v1_buf  = alloc(3 * NFC);       // [n][3][f]
    float* v2_buf  = alloc(3 * NFC);
    float* phi_buf = alloc(3 * NFC);       // f32 [n][384]
    float* envb    = alloc(N_EDGES);
    float* edgerec = alloc((size_t)N_EDGES * REC);
    ushort_t* wbf_hi = (ushort_t*)alloc(WPREP_W / 2 + 64);
    ushort_t* wbf_lo = (ushort_t*)alloc(WPREP_W / 2 + 64);
    float* robias   = alloc(128);
    int* cnt        = (int*)alloc(N_ATOMS);
    int* cursor     = (int*)alloc(N_ATOMS);   // adjacent to cnt (zeroed together)
    int* offsets    = (int*)alloc(N_ATOMS);

    // bf16 weight sub-offsets (elements, see prep_kernel)
    const size_t oW1 = 0, oW2 = 49152, oUV = 196608, oU1 = 294912, oU2 = 393216, oRO = 540672;

    prep_kernel<<<dim3((PREP_TOTAL + 255) / 256), dim3(256), 0, stream>>>(
        emb, z, s_buf,
        msg_w1, msg_w2, upd_u, upd_v, upd_w1, upd_w2, ro_w1, ro_b1,
        wbf_hi, wbf_lo, robias, cnt);
    count_kernel<<<dim3((N_EDGES + 255) / 256), dim3(256), 0, stream>>>(
        xyz, nbrs, envb, cnt);
    scan_kernel<<<dim3(1), dim3(1024), 0, stream>>>(cnt, offsets, out);
    build_kernel<<<dim3((N_EDGES + 255) / 256), dim3(256), 0, stream>>>(
        xyz, nbrs, envb, offsets, cursor, edgerec);

    // phi_0 = silu(s@W1+b1)@W2+b2 (f32 out)
    phi0_kernel<<<dim3(NP/16), dim3(256), 0, stream>>>(
        s_buf,
        wbf_hi + oW1, wbf_lo + oW1, msg_b1,
        wbf_hi + oW2, wbf_lo + oW2, msg_b2,
        phi_buf);

    float* vin = v1_buf;
    float* vout = v2_buf;
    for (int i = 0; i < 3; ++i) {
        if (i == 0)
            msg_gather<1><<<dim3(N_ATOMS), dim3(128), 0, stream>>>(
                phi_buf, edgerec, rbf_w + (size_t)i*N_RBF*3*F, rbf_b + (size_t)i*3*F,
                vin, s_buf, vout, offsets, cnt);
        else
            msg_gather<0><<<dim3(N_ATOMS), dim3(128), 0, stream>>>(
                phi_buf, edgerec, rbf_w + (size_t)i*N_RBF*3*F, rbf_b + (size_t)i*3*F,
                vin, s_buf, vout, offsets, cnt);
        if (i < 2) {
            // upd(i) + phi(i+1) fused
            updphi_kernel<0><<<dim3(NP/16), dim3(256), 0, stream>>>(
                s_buf, vout,
                wbf_hi + oUV + (size_t)i*32768, wbf_lo + oUV + (size_t)i*32768,
                wbf_hi + oU1 + (size_t)i*32768, wbf_lo + oU1 + (size_t)i*32768,
                upd_b1 + (size_t)i*F,
                wbf_hi + oU2 + (size_t)i*49152, wbf_lo + oU2 + (size_t)i*49152,
                upd_b2 + (size_t)i*3*F,
                wbf_hi + oW1 + (size_t)(i+1)*16384, wbf_lo + oW1 + (size_t)(i+1)*16384,
                msg_b1 + (size_t)(i+1)*F,
                wbf_hi + oW2 + (size_t)(i+1)*49152, wbf_lo + oW2 + (size_t)(i+1)*49152,
                msg_b2 + (size_t)(i+1)*3*F,
                phi_buf,
                nullptr, nullptr, nullptr, nullptr);
        } else {
            // upd(2) + readout + mol reduce fused
            updphi_kernel<1><<<dim3(NP/16), dim3(256), 0, stream>>>(
                s_buf, vout,
                wbf_hi + oUV + (size_t)i*32768, wbf_lo + oUV + (size_t)i*32768,
                wbf_hi + oU1 + (size_t)i*32768, wbf_lo + oU1 + (size_t)i*32768,
                upd_b1 + (size_t)i*F,
                wbf_hi + oU2 + (size_t)i*49152, wbf_lo + oU2 + (size_t)i*49152,
                upd_b2 + (size_t)i*3*F,
                wbf_hi + oRO, wbf_lo + oRO, robias,
                nullptr, nullptr, nullptr,
                nullptr,
                ro_w2, ro_b2, molidx, out);
        }
        float* tmp = vin; vin = vout; vout = tmp;
    }
}

// Round 11
// 325.110 us; speedup vs baseline: 1.2598x; 1.2462x over previous
//
#include <hip/hip_runtime.h>

static constexpr int F = 128;
static constexpr int N_RBF = 20;
static constexpr int N_ATOMS = 8000;
static constexpr int NP = 8064;          // padded to 128
static constexpr int N_EDGES = 160000;
static constexpr int N_MOLS = 100;
static constexpr float CUTOFF = 5.0f;
static constexpr size_t NFC = (size_t)NP * F;
static constexpr int REC = 28;           // j, ev, ux,uy,uz, rbf[20], pad[3]
#define PIF 3.14159265358979323846f

typedef __attribute__((ext_vector_type(8))) short bf16x8;
typedef __attribute__((ext_vector_type(4))) float f32x4;
typedef unsigned short ushort_t;
typedef unsigned int uint_t;

__device__ __forceinline__ float silu_f(float x) { return x / (1.f + __expf(-x)); }

__device__ __forceinline__ ushort_t f2bf(float x) {   // round-to-nearest-even
    union { float f; uint_t u; } v; v.f = x;
    uint_t r = v.u + 0x7fffu + ((v.u >> 16) & 1u);
    return (ushort_t)(r >> 16);
}
__device__ __forceinline__ float bf2f(ushort_t h) {
    union { uint_t u; float f; } v; v.u = ((uint_t)h) << 16; return v.f;
}

// Session lessons (r4-r10 all regressed vs this structure):
//  - r4: cooperative launch silently fails under graph capture -> zeros.
//  - r5: fusing edge-gather into the 1-block/CU MFMA kernel: 3x slower (latency, no TLP).
//  - r6: phi/v/s inter-layer activations MUST stay f32 (bf16 phi -> 49% output error).
//  - r7: 2-deep B prefetch regressed 40->64us (compiler schedules 1-deep fine).
//  - r8: uvv +pad increased conflicts & time; r9 direct-B 45->69us; r10 16-atom 2blk/CU
//    no better (latency from short acc chains + VMEM issue, not occupancy/barriers).
//  This file == round-3 verified optimum (327.8us).

// ---------------- pass 1: distance + envelope + live-edge histogram ----------------
__global__ __launch_bounds__(256) void count_kernel(
    const float* __restrict__ xyz, const int* __restrict__ nbrs,
    float* __restrict__ envb, int* __restrict__ cnt)
{
    int e = blockIdx.x * 256 + threadIdx.x;
    if (e >= N_EDGES) return;
    int i0 = nbrs[2*e+0], i1 = nbrs[2*e+1];
    float dx = xyz[3*i1+0] - xyz[3*i0+0];
    float dy = xyz[3*i1+1] - xyz[3*i0+1];
    float dz = xyz[3*i1+2] - xyz[3*i0+2];
    float d  = sqrtf(dx*dx + dy*dy + dz*dz);
    float ev = (d <= CUTOFF) ? 0.5f*(cosf(PIF*d/CUTOFF) + 1.f) : 0.f;
    envb[e] = ev;
    if (ev > 0.f) atomicAdd(&cnt[i0], 1);
}

// ---------------- exclusive scan of 8000 counters (single block) + zero out ----------------
__global__ __launch_bounds__(1024) void scan_kernel(
    const int* __restrict__ cnt, int* __restrict__ offsets, float* __restrict__ out)
{
    __shared__ int sums[1024];
    int tid = threadIdx.x;
    if (tid < N_MOLS) out[tid] = 0.f;
    int base = tid * 8;
    int local[8]; int s = 0;
    #pragma unroll
    for (int i = 0; i < 8; ++i) {
        int idx = base + i;
        local[i] = (idx < N_ATOMS) ? cnt[idx] : 0;
        s += local[i];
    }
    sums[tid] = s;
    __syncthreads();
    for (int d = 1; d < 1024; d <<= 1) {
        int v = (tid >= d) ? sums[tid - d] : 0;
        __syncthreads();
        sums[tid] += v;
        __syncthreads();
    }
    int ex = (tid == 0) ? 0 : sums[tid - 1];
    #pragma unroll
    for (int i = 0; i < 8; ++i) {
        int idx = base + i;
        if (idx < N_ATOMS) { offsets[idx] = ex; ex += local[i]; }
    }
}

// ---------------- pass 2: build packed records for LIVE edges only ----------------
__global__ __launch_bounds__(256) void build_kernel(
    const float* __restrict__ xyz, const int* __restrict__ nbrs,
    const float* __restrict__ envb, const int* __restrict__ offsets,
    int* __restrict__ cursor, float* __restrict__ rec)
{
    int e = blockIdx.x * 256 + threadIdx.x;
    if (e >= N_EDGES) return;
    float ev = envb[e];
    if (ev <= 0.f) return;
    int i0 = nbrs[2*e+0], i1 = nbrs[2*e+1];
    float dx = xyz[3*i1+0] - xyz[3*i0+0];
    float dy = xyz[3*i1+1] - xyz[3*i0+1];
    float dz = xyz[3*i1+2] - xyz[3*i0+2];
    float d  = sqrtf(dx*dx + dy*dy + dz*dz);
    float inv = 1.f / d;
    int pos = offsets[i0] + atomicAdd(&cursor[i0], 1);
    float* r = rec + (size_t)pos * REC;
    r[0] = __int_as_float(i1);
    r[1] = ev;
    r[2] = dx*inv; r[3] = dy*inv; r[4] = dz*inv;
    float base = PIF*d/CUTOFF;
    float sc = inv * ev;   // fold env into rbf (w_s = (rbf*env)@W + b*env)
    #pragma unroll
    for (int k = 0; k < N_RBF; ++k)
        r[5 + k] = sinf((float)(k+1)*base) * sc;
}

// ---------------- fused prep: embed + weight transpose/split + zero cnt/cursor ----------------
// dst layout (bf16, [n][k] row-major K-contig), same offsets for hi and lo buffers:
//   W1t  3x(128n x 128k) @ 0        src msg_w1 (128k x 128n)
//   W2t  3x(384n x 128k) @ 49152    src msg_w2
//   UVt  3x(256n x 128k) @ 196608   src upd_u (n 0..127) | upd_v (n 128..255)
//   U1t  3x(128n x 256k) @ 294912   src upd_w1 (256k x 128n)
//   U2t  3x(384n x 128k) @ 393216   src upd_w2
//   ROt  128n x 128k    @ 540672    src ro_w1 (128k x 64n), cols 64..127 zero
//   robias[128] (f32)   idx 557056..557183: ro_b1 padded with zeros
static constexpr int WPREP_W = 557056;
static constexpr int WPREP_TOTAL = 557184;
static constexpr int NATF = N_ATOMS * F;
static constexpr int PREP_TOTAL = NATF + WPREP_TOTAL + 2 * N_ATOMS;
__global__ __launch_bounds__(256) void prep_kernel(
    const float* __restrict__ emb, const int* __restrict__ z, float* __restrict__ s,
    const float* __restrict__ msg_w1, const float* __restrict__ msg_w2,
    const float* __restrict__ upd_u,  const float* __restrict__ upd_v,
    const float* __restrict__ upd_w1, const float* __restrict__ upd_w2,
    const float* __restrict__ ro_w1,  const float* __restrict__ ro_b1,
    ushort_t* __restrict__ dhi, ushort_t* __restrict__ dlo,
    float* __restrict__ robias, int* __restrict__ cntz)
{
    int gidx = blockIdx.x * 256 + threadIdx.x;
    if (gidx < NATF) {                          // s = emb_table[z]
        int n = gidx >> 7, f = gidx & 127;
        s[gidx] = emb[z[n]*F + f];
        return;
    }
    int idx = gidx - NATF;
    if (idx >= WPREP_TOTAL) {                   // zero cnt + cursor (adjacent)
        cntz[idx - WPREP_TOTAL] = 0;
        return;
    }
    if (idx >= WPREP_W) {
        int l = idx - WPREP_W;
        robias[l] = (l < 64) ? ro_b1[l] : 0.f;
        return;
    }
    float val;
    if (idx < 540672) {
        const float* src; int K, N, rem;
        if (idx < 49152)       { int l = idx;          int c = l / 16384; rem = l % 16384; K = 128; N = 128; src = msg_w1 + c * 16384; }
        else if (idx < 196608) { int l = idx - 49152;  int c = l / 49152; rem = l % 49152; K = 128; N = 384; src = msg_w2 + c * 49152; }
        else if (idx < 294912) { int l = idx - 196608; int c = l / 32768; rem = l % 32768; K = 128; N = 128;
                                 if (rem < 16384) src = upd_u + c * 16384;
                                 else { src = upd_v + c * 16384; rem -= 16384; } }
        else if (idx < 393216) { int l = idx - 294912; int c = l / 32768; rem = l % 32768; K = 256; N = 128; src = upd_w1 + c * 32768; }
        else                   { int l = idx - 393216; int c = l / 49152; rem = l % 49152; K = 128; N = 384; src = upd_w2 + c * 49152; }
        int n = rem / K, k = rem % K;
        val = src[k * N + n];
    } else {
        int l = idx - 540672;             // ro_w1 pad: [n][k], n>=64 -> 0
        int n = l >> 7, k = l & 127;
        val = (n < 64) ? ro_w1[k * 64 + n] : 0.f;
    }
    ushort_t h = f2bf(val);
    dhi[idx] = h;
    dlo[idx] = f2bf(val - bf2f(h));
}

// ---------------- phi0: phi = silu(s@W1+b1)@W2+b2 (A from global s) ----------------
__global__ __launch_bounds__(256) void phi0_kernel(
    const float* __restrict__ sbuf,
    const ushort_t* __restrict__ W1h, const ushort_t* __restrict__ W1l,
    const float* __restrict__ b1,
    const ushort_t* __restrict__ W2h, const ushort_t* __restrict__ W2l,
    const float* __restrict__ b2,
    float* __restrict__ C)
{
    __shared__ __align__(16) ushort_t Ah[2][32 * 40], Al[2][32 * 40];
    __shared__ __align__(16) ushort_t Bh[2][128 * 40], Bl[2][128 * 40];
    __shared__ __align__(16) ushort_t Hh[32 * 136], Hl[32 * 136];
    const int tid = threadIdx.x;
    const int wave = tid >> 6, lane = tid & 63;
    const int row_l = lane & 15, quad = lane >> 4;
    const int wn = wave * 32;
    const int m0 = blockIdx.x * 32;
    const int lrA = tid >> 3, ksA = (tid & 7) * 4;
    const int lrB = tid >> 1, ksB = (tid & 1) * 16;

    float4 rx;
    uint4 b_h0, b_h1, b_l0, b_l1;

    auto loadB1 = [&](int k0) {
        const ushort_t* bh = &W1h[(size_t)lrB * 128 + k0 + ksB];
        const ushort_t* bl = &W1l[(size_t)lrB * 128 + k0 + ksB];
        b_h0 = *(const uint4*)bh; b_h1 = *(const uint4*)(bh + 8);
        b_l0 = *(const uint4*)bl; b_l1 = *(const uint4*)(bl + 8);
    };
    auto loadB2 = [&](int it2) {
        int ct = it2 >> 2, k0 = (it2 & 3) * 32;
        const ushort_t* bh = &W2h[(size_t)(ct * 128 + lrB) * 128 + k0 + ksB];
        const ushort_t* bl = &W2l[(size_t)(ct * 128 + lrB) * 128 + k0 + ksB];
        b_h0 = *(const uint4*)bh; b_h1 = *(const uint4*)(bh + 8);
        b_l0 = *(const uint4*)bl; b_l1 = *(const uint4*)(bl + 8);
    };
    auto writeA = [&](int buf) {
        float e[4] = {rx.x, rx.y, rx.z, rx.w};
        ushort_t ph[4], pl[4];
        #pragma unroll
        for (int t = 0; t < 4; ++t) {
            ushort_t h = f2bf(e[t]);
            ph[t] = h; pl[t] = f2bf(e[t] - bf2f(h));
        }
        *(uint2*)&Ah[buf][lrA * 40 + ksA] = *(uint2*)ph;
        *(uint2*)&Al[buf][lrA * 40 + ksA] = *(uint2*)pl;
    };
    auto writeB = [&](int buf) {
        *(uint4*)&Bh[buf][lrB * 40 + ksB]     = b_h0;
        *(uint4*)&Bh[buf][lrB * 40 + ksB + 8] = b_h1;
        *(uint4*)&Bl[buf][lrB * 40 + ksB]     = b_l0;
        *(uint4*)&Bl[buf][lrB * 40 + ksB + 8] = b_l1;
    };

    f32x4 acc[2][2];
    #pragma unroll
    for (int i = 0; i < 2; ++i)
        #pragma unroll
        for (int j = 0; j < 2; ++j)
            #pragma unroll
            for (int r = 0; r < 4; ++r) acc[i][j][r] = 0.f;

    rx = *(const float4*)&sbuf[(size_t)(m0 + lrA) * 128 + ksA];
    loadB1(0);
    writeA(0); writeB(0);
    __syncthreads();
    #pragma unroll
    for (int it = 0; it < 4; ++it) {
        const int k0n = (it + 1) * 32;
        if (it + 1 < 4) {
            rx = *(const float4*)&sbuf[(size_t)(m0 + lrA) * 128 + k0n + ksA];
            loadB1(k0n);
        }
        bf16x8 ahf[2], alf[2], bhf[2], blf[2];
        #pragma unroll
        for (int i = 0; i < 2; ++i) {
            int ar = (i * 16 + row_l) * 40 + quad * 8;
            ahf[i] = *(const bf16x8*)&Ah[it & 1][ar];
            alf[i] = *(const bf16x8*)&Al[it & 1][ar];
        }
        #pragma unroll
        for (int j = 0; j < 2; ++j) {
            int br = (wn + j * 16 + row_l) * 40 + quad * 8;
            bhf[j] = *(const bf16x8*)&Bh[it & 1][br];
            blf[j] = *(const bf16x8*)&Bl[it & 1][br];
        }
        #pragma unroll
        for (int i = 0; i < 2; ++i)
            #pragma unroll
            for (int j = 0; j < 2; ++j) {
                acc[i][j] = __builtin_amdgcn_mfma_f32_16x16x32_bf16(ahf[i], bhf[j], acc[i][j], 0, 0, 0);
                acc[i][j] = __builtin_amdgcn_mfma_f32_16x16x32_bf16(ahf[i], blf[j], acc[i][j], 0, 0, 0);
                acc[i][j] = __builtin_amdgcn_mfma_f32_16x16x32_bf16(alf[i], bhf[j], acc[i][j], 0, 0, 0);
            }
        if (it + 1 < 4) { writeA((it + 1) & 1); writeB((it + 1) & 1); }
        __syncthreads();
    }
    #pragma unroll
    for (int j = 0; j < 2; ++j) {
        int col = wn + j * 16 + row_l;
        float bval = b1[col];
        #pragma unroll
        for (int i = 0; i < 2; ++i)
            #pragma unroll
            for (int r = 0; r < 4; ++r) {
                int row = i * 16 + quad * 4 + r;
                float v = silu_f(acc[i][j][r] + bval);
                ushort_t h = f2bf(v);
                Hh[row * 136 + col] = h;
                Hl[row * 136 + col] = f2bf(v - bf2f(h));
            }
    }

    #pragma unroll
    for (int i = 0; i < 2; ++i)
        #pragma unroll
        for (int j = 0; j < 2; ++j)
            #pragma unroll
            for (int r = 0; r < 4; ++r) acc[i][j][r] = 0.f;
    loadB2(0); writeB(0);
    __syncthreads();
    #pragma unroll
    for (int it = 0; it < 12; ++it) {
        const int k0 = (it & 3) * 32;
        if (it + 1 < 12) loadB2(it + 1);
        bf16x8 ahf[2], alf[2], bhf[2], blf[2];
        #pragma unroll
        for (int i = 0; i < 2; ++i) {
            int ar = (i * 16 + row_l) * 136 + k0 + quad * 8;
            ahf[i] = *(const bf16x8*)&Hh[ar];
            alf[i] = *(const bf16x8*)&Hl[ar];
        }
        #pragma unroll
        for (int j = 0; j < 2; ++j) {
            int br = (wn + j * 16 + row_l) * 40 + quad * 8;
            bhf[j] = *(const bf16x8*)&Bh[it & 1][br];
            blf[j] = *(const bf16x8*)&Bl[it & 1][br];
        }
        #pragma unroll
        for (int i = 0; i < 2; ++i)
            #pragma unroll
            for (int j = 0; j < 2; ++j) {
                acc[i][j] = __builtin_amdgcn_mfma_f32_16x16x32_bf16(ahf[i], bhf[j], acc[i][j], 0, 0, 0);
                acc[i][j] = __builtin_amdgcn_mfma_f32_16x16x32_bf16(ahf[i], blf[j], acc[i][j], 0, 0, 0);
                acc[i][j] = __builtin_amdgcn_mfma_f32_16x16x32_bf16(alf[i], bhf[j], acc[i][j], 0, 0, 0);
            }
        if ((it & 3) == 3) {
            const int ct = it >> 2;
            #pragma unroll
            for (int j = 0; j < 2; ++j) {
                int col = ct * 128 + wn + j * 16 + row_l;
                float bval = b2[col];
                #pragma unroll
                for (int i = 0; i < 2; ++i)
                    #pragma unroll
                    for (int r = 0; r < 4; ++r) {
                        int row = i * 16 + quad * 4 + r;
                        C[(size_t)(m0 + row) * 384 + col] = acc[i][j][r] + bval;
                    }
            }
            #pragma unroll
            for (int i = 0; i < 2; ++i)
                #pragma unroll
                for (int j = 0; j < 2; ++j)
                    #pragma unroll
                    for (int r = 0; r < 4; ++r) acc[i][j][r] = 0.f;
        }
        if (it + 1 < 12) writeB((it + 1) & 1);
        __syncthreads();
    }
}

// ---------------- fused update (+ next phi / readout tail) ----------------
// Phase 0: [uv|vv] = v @ UVt in LDS.  Phase 1: h = silu([s|norm(vv)]@W1+b1).
// Phase 2: a = h@W2+b2; finupd folded into column-tile epilogues; s_new kept in LDS (sS).
// Phase 3 (TAIL=0): phi_{i+1} = silu(sS@XW1+xb1)@XW2+xb2 -> phi_out.
// Phase 3 (TAIL=1): h2 = silu(sS@ROt+robias); atom_e = h2[0:64]·w2ro + b2ro;
//                   per-block mol table -> atomicAdd(out).  (ct0/a_vv skipped: v dead.)
template<int TAIL>
__global__ __launch_bounds__(256) void updphi_kernel(
    float* __restrict__ s_io, float* __restrict__ v_io,
    const ushort_t* __restrict__ UVh, const ushort_t* __restrict__ UVl,
    const ushort_t* __restrict__ W1h, const ushort_t* __restrict__ W1l,
    const float* __restrict__ b1,
    const ushort_t* __restrict__ W2h, const ushort_t* __restrict__ W2l,
    const float* __restrict__ b2,
    const ushort_t* __restrict__ XW1h, const ushort_t* __restrict__ XW1l,
    const float* __restrict__ xb1,
    const ushort_t* __restrict__ XW2h, const ushort_t* __restrict__ XW2l,
    const float* __restrict__ xb2,
    float* __restrict__ phi_out,
    const float* __restrict__ w2ro, const float* __restrict__ b2ro,
    const int* __restrict__ mol, float* __restrict__ outp)
{
    __shared__ float uvv[96][260];                     // [ln*3+d][0:128 uv | 128:256 vv]
    __shared__ __align__(16) ushort_t Bh[2][128 * 40];
    __shared__ __align__(16) ushort_t Bl[2][128 * 40];
    __shared__ __align__(16) unsigned char AH[17408];  // union: A-stage dbuf / H
    __shared__ float molacc[128];                      // TAIL=1 only
    __shared__ float redl[32][4];                      // TAIL=1 only
    const int tid = threadIdx.x;
    const int wave = tid >> 6, lane = tid & 63;
    const int row_l = lane & 15, quad = lane >> 4;
    const int wn = wave * 32;
    const int m0 = blockIdx.x * 32;
    const int lrA = tid >> 3;          // 0..31
    const int ksA = (tid & 7) * 4;     // 0,4,..28
    const int lrB = tid >> 1, ksB = (tid & 1) * 16;

    float* sS = &uvv[0][0];            // 32 x 132 f32 (overlays dead uvv rows in phase 2 tail)
    constexpr int SSTR = 132;

    // ================= phase 0: [uv|vv] = v @ UVt (M=96, N=256, K=128) =================
    {
        ushort_t* A0h = (ushort_t*)AH;                 // [96][40]
        ushort_t* A0l = A0h + 96 * 40;
        ushort_t* B0h = &Bh[0][0];                     // [256][40] spans both buffers
        ushort_t* B0l = &Bl[0][0];
        f32x4 acc0[6][4];
        #pragma unroll
        for (int i = 0; i < 6; ++i)
            #pragma unroll
            for (int j = 0; j < 4; ++j)
                #pragma unroll
                for (int r = 0; r < 4; ++r) acc0[i][j][r] = 0.f;
        for (int k0 = 0; k0 < 128; k0 += 32) {
            #pragma unroll
            for (int g = 0; g < 3; ++g) {
                int row = g * 32 + lrA;
                float4 v = *(const float4*)&v_io[(size_t)(m0 * 3 + row) * 128 + k0 + ksA];
                float e[4] = {v.x, v.y, v.z, v.w};
                ushort_t ph[4], pl[4];
                #pragma unroll
                for (int t = 0; t < 4; ++t) {
                    ushort_t h = f2bf(e[t]);
                    ph[t] = h; pl[t] = f2bf(e[t] - bf2f(h));
                }
                *(uint2*)&A0h[row * 40 + ksA] = *(uint2*)ph;
                *(uint2*)&A0l[row * 40 + ksA] = *(uint2*)pl;
            }
            {
                const ushort_t* bh = &UVh[(size_t)tid * 128 + k0];
                const ushort_t* bl = &UVl[(size_t)tid * 128 + k0];
                *(uint4*)&B0h[tid * 40 + 0]  = *(const uint4*)(bh + 0);
                *(uint4*)&B0h[tid * 40 + 8]  = *(const uint4*)(bh + 8);
                *(uint4*)&B0h[tid * 40 + 16] = *(const uint4*)(bh + 16);
                *(uint4*)&B0h[tid * 40 + 24] = *(const uint4*)(bh + 24);
                *(uint4*)&B0l[tid * 40 + 0]  = *(const uint4*)(bl + 0);
                *(uint4*)&B0l[tid * 40 + 8]  = *(const uint4*)(bl + 8);
                *(uint4*)&B0l[tid * 40 + 16] = *(const uint4*)(bl + 16);
                *(uint4*)&B0l[tid * 40 + 24] = *(const uint4*)(bl + 24);
            }
            __syncthreads();
            bf16x8 a0h[6], a0l[6], b0h[4], b0l[4];
            #pragma unroll
            for (int i = 0; i < 6; ++i) {
                int ar = (i * 16 + row_l) * 40 + quad * 8;
                a0h[i] = *(const bf16x8*)&A0h[ar];
                a0l[i] = *(const bf16x8*)&A0l[ar];
            }
            #pragma unroll
            for (int j = 0; j < 4; ++j) {
                int br = (wave * 64 + j * 16 + row_l) * 40 + quad * 8;
                b0h[j] = *(const bf16x8*)&B0h[br];
                b0l[j] = *(const bf16x8*)&B0l[br];
            }
            #pragma unroll
            for (int i = 0; i < 6; ++i)
                #pragma unroll
                for (int j = 0; j < 4; ++j) {
                    acc0[i][j] = __builtin_amdgcn_mfma_f32_16x16x32_bf16(a0h[i], b0h[j], acc0[i][j], 0, 0, 0);
                    acc0[i][j] = __builtin_amdgcn_mfma_f32_16x16x32_bf16(a0h[i], b0l[j], acc0[i][j], 0, 0, 0);
                    acc0[i][j] = __builtin_amdgcn_mfma_f32_16x16x32_bf16(a0l[i], b0h[j], acc0[i][j], 0, 0, 0);
                }
            __syncthreads();
        }
        #pragma unroll
        for (int i = 0; i < 6; ++i)
            #pragma unroll
            for (int j = 0; j < 4; ++j)
                #pragma unroll
                for (int r = 0; r < 4; ++r)
                    uvv[i * 16 + quad * 4 + r][wave * 64 + j * 16 + row_l] = acc0[i][j][r];
        __syncthreads();
    }

    // ================= phase 1: h = silu([s | norm(vv)] @ W1 + b1) =================
    ushort_t* Ah1 = (ushort_t*)AH;                     // [2][32*40]
    ushort_t* Al1 = Ah1 + 2 * 32 * 40;
    ushort_t* Hh  = (ushort_t*)AH;                     // [32][136]
    ushort_t* Hl  = Hh + 32 * 136;

    float4 rx;
    uint4 b_h0, b_h1, b_l0, b_l1;

    auto loadB1 = [&](int k0) {
        const ushort_t* bh = &W1h[(size_t)lrB * 256 + k0 + ksB];
        const ushort_t* bl = &W1l[(size_t)lrB * 256 + k0 + ksB];
        b_h0 = *(const uint4*)bh; b_h1 = *(const uint4*)(bh + 8);
        b_l0 = *(const uint4*)bl; b_l1 = *(const uint4*)(bl + 8);
    };
    auto writeB = [&](int buf) {
        *(uint4*)&Bh[buf][lrB * 40 + ksB]     = b_h0;
        *(uint4*)&Bh[buf][lrB * 40 + ksB + 8] = b_h1;
        *(uint4*)&Bl[buf][lrB * 40 + ksB]     = b_l0;
        *(uint4*)&Bl[buf][lrB * 40 + ksB + 8] = b_l1;
    };
    auto writeA1 = [&](int buf, int k0) {
        float e[4];
        if (k0 < 128) {
            e[0] = rx.x; e[1] = rx.y; e[2] = rx.z; e[3] = rx.w;
        } else {
            int f = k0 + ksA;          // uvv col 128..255 (vv)
            #pragma unroll
            for (int t = 0; t < 4; ++t) {
                float x = uvv[lrA * 3 + 0][f + t];
                float y = uvv[lrA * 3 + 1][f + t];
                float z = uvv[lrA * 3 + 2][f + t];
                e[t] = sqrtf(x * x + y * y + z * z + 1e-15f);
            }
        }
        ushort_t ph[4], pl[4];
        #pragma unroll
        for (int t = 0; t < 4; ++t) {
            ushort_t h = f2bf(e[t]);
            ph[t] = h; pl[t] = f2bf(e[t] - bf2f(h));
        }
        *(uint2*)&Ah1[buf * 1280 + lrA * 40 + ksA] = *(uint2*)ph;
        *(uint2*)&Al1[buf * 1280 + lrA * 40 + ksA] = *(uint2*)pl;
    };

    f32x4 acc[2][2];
    #pragma unroll
    for (int i = 0; i < 2; ++i)
        #pragma unroll
        for (int j = 0; j < 2; ++j)
            #pragma unroll
            for (int r = 0; r < 4; ++r) acc[i][j][r] = 0.f;

    rx = *(const float4*)&s_io[(size_t)(m0 + lrA) * 128 + ksA];
    loadB1(0);
    writeA1(0, 0); writeB(0);
    __syncthreads();
    #pragma unroll
    for (int it = 0; it < 8; ++it) {
        const int k0n = (it + 1) * 32;
        if (it + 1 < 8) {
            if (k0n < 128) rx = *(const float4*)&s_io[(size_t)(m0 + lrA) * 128 + k0n + ksA];
            loadB1(k0n);
        }
        bf16x8 ahf[2], alf[2], bhf[2], blf[2];
        #pragma unroll
        for (int i = 0; i < 2; ++i) {
            int ar = (it & 1) * 1280 + (i * 16 + row_l) * 40 + quad * 8;
            ahf[i] = *(const bf16x8*)&Ah1[ar];
            alf[i] = *(const bf16x8*)&Al1[ar];
        }
        #pragma unroll
        for (int j = 0; j < 2; ++j) {
            int br = (wn + j * 16 + row_l) * 40 + quad * 8;
            bhf[j] = *(const bf16x8*)&Bh[it & 1][br];
            blf[j] = *(const bf16x8*)&Bl[it & 1][br];
        }
        #pragma unroll
        for (int i = 0; i < 2; ++i)
            #pragma unroll
            for (int j = 0; j < 2; ++j) {
                acc[i][j] = __builtin_amdgcn_mfma_f32_16x16x32_bf16(ahf[i], bhf[j], acc[i][j], 0, 0, 0);
                acc[i][j] = __builtin_amdgcn_mfma_f32_16x16x32_bf16(ahf[i], blf[j], acc[i][j], 0, 0, 0);
                acc[i][j] = __builtin_amdgcn_mfma_f32_16x16x32_bf16(alf[i], bhf[j], acc[i][j], 0, 0, 0);
            }
        if (it + 1 < 8) { writeA1((it + 1) & 1, k0n); writeB((it + 1) & 1); }
        __syncthreads();
    }
    // epilogue 1 -> H (overwrites phase-1 A region; loop-end barrier makes it safe)
    #pragma unroll
    for (int j = 0; j < 2; ++j) {
        int col = wn + j * 16 + row_l;
        float bval = b1[col];
        #pragma unroll
        for (int i = 0; i < 2; ++i)
            #pragma unroll
            for (int r = 0; r < 4; ++r) {
                int row = i * 16 + quad * 4 + r;
                float v = silu_f(acc[i][j][r] + bval);
                ushort_t h = f2bf(v);
                Hh[row * 136 + col] = h;
                Hl[row * 136 + col] = f2bf(v - bf2f(h));
            }
    }

    // ================= phase 2: a = h @ W2 + b2, finupd folded into ct epilogues =================
    constexpr int CT0 = TAIL ? 1 : 0;          // TAIL=1: a_vv unused (v dead) -> skip ct0
    constexpr int NIT2 = (3 - CT0) * 4;
    auto loadB2 = [&](int it2) {
        int ct = CT0 + (it2 >> 2), k0 = (it2 & 3) * 32;
        const ushort_t* bh = &W2h[(size_t)(ct * 128 + lrB) * 128 + k0 + ksB];
        const ushort_t* bl = &W2l[(size_t)(ct * 128 + lrB) * 128 + k0 + ksB];
        b_h0 = *(const uint4*)bh; b_h1 = *(const uint4*)(bh + 8);
        b_l0 = *(const uint4*)bl; b_l1 = *(const uint4*)(bl + 8);
    };

    #pragma unroll
    for (int i = 0; i < 2; ++i)
        #pragma unroll
        for (int j = 0; j < 2; ++j)
            #pragma unroll
            for (int r = 0; r < 4; ++r) acc[i][j][r] = 0.f;
    f32x4 ssum[2][2];

    loadB2(0); writeB(0);
    __syncthreads();
    #pragma unroll
    for (int it = 0; it < NIT2; ++it) {
        const int k0 = (it & 3) * 32;
        if (it + 1 < NIT2) loadB2(it + 1);
        bf16x8 ahf[2], alf[2], bhf[2], blf[2];
        #pragma unroll
        for (int i = 0; i < 2; ++i) {
            int ar = (i * 16 + row_l) * 136 + k0 + quad * 8;
            ahf[i] = *(const bf16x8*)&Hh[ar];
            alf[i] = *(const bf16x8*)&Hl[ar];
        }
        #pragma unroll
        for (int j = 0; j < 2; ++j) {
            int br = (wn + j * 16 + row_l) * 40 + quad * 8;
            bhf[j] = *(const bf16x8*)&Bh[it & 1][br];
            blf[j] = *(const bf16x8*)&Bl[it & 1][br];
        }
        #pragma unroll
        for (int i = 0; i < 2; ++i)
            #pragma unroll
            for (int j = 0; j < 2; ++j) {
                acc[i][j] = __builtin_amdgcn_mfma_f32_16x16x32_bf16(ahf[i], bhf[j], acc[i][j], 0, 0, 0);
                acc[i][j] = __builtin_amdgcn_mfma_f32_16x16x32_bf16(ahf[i], blf[j], acc[i][j], 0, 0, 0);
                acc[i][j] = __builtin_amdgcn_mfma_f32_16x16x32_bf16(alf[i], bhf[j], acc[i][j], 0, 0, 0);
            }
        if ((it & 3) == 3) {                     // column-tile epilogue + finupd slice
            const int ct = CT0 + (it >> 2);
            #pragma unroll
            for (int j = 0; j < 2; ++j) {
                int f = wn + j * 16 + row_l;
                float bval = b2[ct * 128 + f];
                #pragma unroll
                for (int i = 0; i < 2; ++i)
                    #pragma unroll
                    for (int r = 0; r < 4; ++r) {
                        int ln = i * 16 + quad * 4 + r;
                        float a = acc[i][j][r] + bval;
                        if (ct == 0) {                      // a_vv: v += uv * a
                            size_t vb = (size_t)(m0 + ln) * 3 * F + f;
                            v_io[vb]         += uvv[ln * 3 + 0][f] * a;
                            v_io[vb + F]     += uvv[ln * 3 + 1][f] * a;
                            v_io[vb + 2 * F] += uvv[ln * 3 + 2][f] * a;
                        } else if (ct == 1) {               // a_sv: ssum = <uv,vv> * a
                            float dot = uvv[ln * 3 + 0][f] * uvv[ln * 3 + 0][128 + f]
                                      + uvv[ln * 3 + 1][f] * uvv[ln * 3 + 1][128 + f]
                                      + uvv[ln * 3 + 2][f] * uvv[ln * 3 + 2][128 + f];
                            ssum[i][j][r] = dot * a;
                        } else {                            // a_ss: s_new = s + ssum + a
                            float sv = s_io[(size_t)(m0 + ln) * F + f] + ssum[i][j][r] + a;
                            if constexpr (TAIL == 0) s_io[(size_t)(m0 + ln) * F + f] = sv;
                            sS[ln * SSTR + f] = sv;         // sS overlays uvv rows (dead by now)
                        }
                    }
            }
            #pragma unroll
            for (int i = 0; i < 2; ++i)
                #pragma unroll
                for (int j = 0; j < 2; ++j)
                    #pragma unroll
                    for (int r = 0; r < 4; ++r) acc[i][j][r] = 0.f;
        }
        if (it + 1 < NIT2) writeB((it + 1) & 1);
        __syncthreads();
    }

    // ================= phase 3: next-phi MLP (TAIL=0) or readout (TAIL=1), A = sS =================
    if constexpr (TAIL == 1) { if (tid < 128) molacc[tid] = 0.f; }
    ushort_t* Ah3 = (ushort_t*)AH;
    ushort_t* Al3 = Ah3 + 2 * 1280;

    auto loadB31 = [&](int k0) {
        const ushort_t* bh = &XW1h[(size_t)lrB * 128 + k0 + ksB];
        const ushort_t* bl = &XW1l[(size_t)lrB * 128 + k0 + ksB];
        b_h0 = *(const uint4*)bh; b_h1 = *(const uint4*)(bh + 8);
        b_l0 = *(const uint4*)bl; b_l1 = *(const uint4*)(bl + 8);
    };
    auto writeA3 = [&](int buf, int k0) {
        float e[4];
        #pragma unroll
        for (int t = 0; t < 4; ++t) e[t] = sS[lrA * SSTR + k0 + ksA + t];
        ushort_t ph[4], pl[4];
        #pragma unroll
        for (int t = 0; t < 4; ++t) {
            ushort_t h = f2bf(e[t]);
            ph[t] = h; pl[t] = f2bf(e[t] - bf2f(h));
        }
        *(uint2*)&Ah3[buf * 1280 + lrA * 40 + ksA] = *(uint2*)ph;
        *(uint2*)&Al3[buf * 1280 + lrA * 40 + ksA] = *(uint2*)pl;
    };

    #pragma unroll
    for (int i = 0; i < 2; ++i)
        #pragma unroll
        for (int j = 0; j < 2; ++j)
            #pragma unroll
            for (int r = 0; r < 4; ++r) acc[i][j][r] = 0.f;

    loadB31(0);
    writeA3(0, 0); writeB(0);
    __syncthreads();
    #pragma unroll
    for (int it = 0; it < 4; ++it) {
        const int k0n = (it + 1) * 32;
        if (it + 1 < 4) loadB31(k0n);
        bf16x8 ahf[2], alf[2], bhf[2], blf[2];
        #pragma unroll
        for (int i = 0; i < 2; ++i) {
            int ar = (it & 1) * 1280 + (i * 16 + row_l) * 40 + quad * 8;
            ahf[i] = *(const bf16x8*)&Ah3[ar];
            alf[i] = *(const bf16x8*)&Al3[ar];
        }
        #pragma unroll
        for (int j = 0; j < 2; ++j) {
            int br = (wn + j * 16 + row_l) * 40 + quad * 8;
            bhf[j] = *(const bf16x8*)&Bh[it & 1][br];
            blf[j] = *(const bf16x8*)&Bl[it & 1][br];
        }
        #pragma unroll
        for (int i = 0; i < 2; ++i)
            #pragma unroll
            for (int j = 0; j < 2; ++j) {
                acc[i][j] = __builtin_amdgcn_mfma_f32_16x16x32_bf16(ahf[i], bhf[j], acc[i][j], 0, 0, 0);
                acc[i][j] = __builtin_amdgcn_mfma_f32_16x16x32_bf16(ahf[i], blf[j], acc[i][j], 0, 0, 0);
                acc[i][j] = __builtin_amdgcn_mfma_f32_16x16x32_bf16(alf[i], bhf[j], acc[i][j], 0, 0, 0);
            }
        if (it + 1 < 4) { writeA3((it + 1) & 1, k0n); writeB((it + 1) & 1); }
        __syncthreads();
    }

    if constexpr (TAIL == 0) {
        // -> H, then stage 2 with XW2 -> phi_out
        #pragma unroll
        for (int j = 0; j < 2; ++j) {
            int col = wn + j * 16 + row_l;
            float bval = xb1[col];
            #pragma unroll
            for (int i = 0; i < 2; ++i)
                #pragma unroll
                for (int r = 0; r < 4; ++r) {
                    int row = i * 16 + quad * 4 + r;
                    float v = silu_f(acc[i][j][r] + bval);
                    ushort_t h = f2bf(v);
                    Hh[row * 136 + col] = h;
                    Hl[row * 136 + col] = f2bf(v - bf2f(h));
                }
        }
        auto loadB32 = [&](int it2) {
            int ct = it2 >> 2, k0 = (it2 & 3) * 32;
            const ushort_t* bh = &XW2h[(size_t)(ct * 128 + lrB) * 128 + k0 + ksB];
            const ushort_t* bl = &XW2l[(size_t)(ct * 128 + lrB) * 128 + k0 + ksB];
            b_h0 = *(const uint4*)bh; b_h1 = *(const uint4*)(bh + 8);
            b_l0 = *(const uint4*)bl; b_l1 = *(const uint4*)(bl + 8);
        };
        #pragma unroll
        for (int i = 0; i < 2; ++i)
            #pragma unroll
            for (int j = 0; j < 2; ++j)
                #pragma unroll
                for (int r = 0; r < 4; ++r) acc[i][j][r] = 0.f;
        loadB32(0); writeB(0);
        __syncthreads();
        #pragma unroll
        for (int it = 0; it < 12; ++it) {
            const int k0 = (it & 3) * 32;
            if (it + 1 < 12) loadB32(it + 1);
            bf16x8 ahf[2], alf[2], bhf[2], blf[2];
            #pragma unroll
            for (int i = 0; i < 2; ++i) {
                int ar = (i * 16 + row_l) * 136 + k0 + quad * 8;
                ahf[i] = *(const bf16x8*)&Hh[ar];
                alf[i] = *(const bf16x8*)&Hl[ar];
            }
            #pragma unroll
            for (int j = 0; j < 2; ++j) {
                int br = (wn + j * 16 + row_l) * 40 + quad * 8;
                bhf[j] = *(const bf16x8*)&Bh[it & 1][br];
                blf[j] = *(const bf16x8*)&Bl[it & 1][br];
            }
            #pragma unroll
            for (int i = 0; i < 2; ++i)
                #pragma unroll
                for (int j = 0; j < 2; ++j) {
                    acc[i][j] = __builtin_amdgcn_mfma_f32_16x16x32_bf16(ahf[i], bhf[j], acc[i][j], 0, 0, 0);
                    acc[i][j] = __builtin_amdgcn_mfma_f32_16x16x32_bf16(ahf[i], blf[j], acc[i][j], 0, 0, 0);
                    acc[i][j] = __builtin_amdgcn_mfma_f32_16x16x32_bf16(alf[i], bhf[j], acc[i][j], 0, 0, 0);
                }
            if ((it & 3) == 3) {
                const int ct = it >> 2;
                #pragma unroll
                for (int j = 0; j < 2; ++j) {
                    int col = ct * 128 + wn + j * 16 + row_l;
                    float bval = xb2[col];
                    #pragma unroll
                    for (int i = 0; i < 2; ++i)
                        #pragma unroll
                        for (int r = 0; r < 4; ++r) {
                            int row = i * 16 + quad * 4 + r;
                            phi_out[(size_t)(m0 + row) * 384 + col] = acc[i][j][r] + bval;
                        }
                }
                #pragma unroll
                for (int i = 0; i < 2; ++i)
                    #pragma unroll
                    for (int j = 0; j < 2; ++j)
                        #pragma unroll
                        for (int r = 0; r < 4; ++r) acc[i][j][r] = 0.f;
            }
            if (it + 1 < 12) writeB((it + 1) & 1);
            __syncthreads();
        }
    } else {
        // readout: atom_e = sum_{col<64} silu(acc+robias)·w2 ; block mol table -> out
        float part[2][4];
        #pragma unroll
        for (int i = 0; i < 2; ++i)
            #pragma unroll
            for (int r = 0; r < 4; ++r) part[i][r] = 0.f;
        #pragma unroll
        for (int j = 0; j < 2; ++j) {
            int col = wn + j * 16 + row_l;
            float bv = xb1[col];                       // robias (zero-padded)
            float wv = (col < 64) ? w2ro[col] : 0.f;
            #pragma unroll
            for (int i = 0; i < 2; ++i)
                #pragma unroll
                for (int r = 0; r < 4; ++r)
                    part[i][r] += silu_f(acc[i][j][r] + bv) * wv;
        }
        #pragma unroll
        for (int o = 1; o < 16; o <<= 1)
            #pragma unroll
            for (int i = 0; i < 2; ++i)
                #pragma unroll
                for (int r = 0; r < 4; ++r)
                    part[i][r] += __shfl_xor(part[i][r], o);
        if (row_l == 0)
            #pragma unroll
            for (int i = 0; i < 2; ++i)
                #pragma unroll
                for (int r = 0; r < 4; ++r)
                    redl[i * 16 + quad * 4 + r][wave] = part[i][r];
        __syncthreads();
        if (tid < 32) {
            int n = m0 + tid;
            if (n < N_ATOMS) {
                float e = redl[tid][0] + redl[tid][1] + redl[tid][2] + redl[tid][3] + b2ro[0];
                atomicAdd(&molacc[mol[n]], e);
            }
        }
        __syncthreads();
        if (tid < 100 && molacc[tid] != 0.f) atomicAdd(&outp[tid], molacc[tid]);
    }
}

// ---------------- atom-centric message gather (atomic-free, packed records) ----------------
template<int ZVIN>
__global__ __launch_bounds__(128) void msg_gather(
    const float* __restrict__ phi, const float* __restrict__ rec,
    const float* __restrict__ rbf_w, const float* __restrict__ rbf_b,
    const float* __restrict__ v_in, float* __restrict__ s,
    float* __restrict__ v_out, const int* __restrict__ offsets,
    const int* __restrict__ cnt)
{
    const int n = blockIdx.x, tid = threadIdx.x;
    float W0[N_RBF], W1[N_RBF], W2[N_RBF];
    #pragma unroll
    for (int k = 0; k < N_RBF; ++k) {
        W0[k] = rbf_w[k*3*F + tid];
        W1[k] = rbf_w[k*3*F + F + tid];
        W2[k] = rbf_w[k*3*F + 2*F + tid];
    }
    const float b0 = rbf_b[tid], b1 = rbf_b[F + tid], b2 = rbf_b[2*F + tid];
    float ds = 0.f, dvx = 0.f, dvy = 0.f, dvz = 0.f;
    const int off = offsets[n], c = cnt[n];
    const float* r = rec + (size_t)off * REC;
    #pragma unroll 2
    for (int t = 0; t < c; ++t, r += REC) {
        int j = __float_as_int(r[0]);
        float ev = r[1];
        float ux = r[2], uy = r[3], uz = r[4];
        float w0 = b0 * ev, w1 = b1 * ev, w2 = b2 * ev;
        #pragma unroll
        for (int k = 0; k < N_RBF; ++k) {
            float rk = r[5 + k];
            w0 += rk * W0[k]; w1 += rk * W1[k]; w2 += rk * W2[k];
        }
        const float* prow = phi + (size_t)j * 3 * F;
        float s0 = prow[tid] * w0;
        float s1 = prow[F + tid] * w1;
        float s2 = prow[2*F + tid] * w2;
        ds  += s1;
        if constexpr (ZVIN) {
            dvx += s2*ux; dvy += s2*uy; dvz += s2*uz;
        } else {
            const float* vrow = v_in + (size_t)j * 3 * F;
            dvx += s2*ux + s0 * vrow[tid];
            dvy += s2*uy + s0 * vrow[F + tid];
            dvz += s2*uz + s0 * vrow[2*F + tid];
        }
    }
    s[(size_t)n * F + tid] += ds;
    size_t vb = (size_t)n * 3 * F + tid;
    if constexpr (ZVIN) {
        v_out[vb]       = dvx;
        v_out[vb + F]   = dvy;
        v_out[vb + 2*F] = dvz;
    } else {
        v_out[vb]       = v_in[vb]       + dvx;
        v_out[vb + F]   = v_in[vb + F]   + dvy;
        v_out[vb + 2*F] = v_in[vb + 2*F] + dvz;
    }
}

extern "C" void kernel_launch(void* const* d_in, const int* in_sizes, int n_in,
                              void* d_out, int out_size, void* d_ws, size_t ws_size,
                              hipStream_t stream)
{
    const float* xyz    = (const float*)d_in[0];
    const float* emb    = (const float*)d_in[1];
    const float* msg_w1 = (const float*)d_in[2];
    const float* msg_b1 = (const float*)d_in[3];
    const float* msg_w2 = (const float*)d_in[4];
    const float* msg_b2 = (const float*)d_in[5];
    const float* rbf_w  = (const float*)d_in[6];
    const float* rbf_b  = (const float*)d_in[7];
    const float* upd_u  = (const float*)d_in[8];
    const float* upd_v  = (const float*)d_in[9];
    const float* upd_w1 = (const float*)d_in[10];
    const float* upd_b1 = (const float*)d_in[11];
    const float* upd_w2 = (const float*)d_in[12];
    const float* upd_b2 = (const float*)d_in[13];
    const float* ro_w1  = (const float*)d_in[14];
    const float* ro_b1  = (const float*)d_in[15];
    const float* ro_w2  = (const float*)d_in[16];
    const float* ro_b2  = (const float*)d_in[17];
    const int*   z      = (const int*)d_in[18];
    const int*   nbrs   = (const int*)d_in[19];
    const int*   molidx = (const int*)d_in[20];
    float* out = (float*)d_out;

    float* ws = (float*)d_ws;
    size_t off = 0;
    auto alloc = [&](size_t n) { float* p = ws + off; off += n; return p; };
    float* s_buf   = alloc(NFC);
    float* v1_buf  = alloc(3 * NFC);       // [n][3][f]
    float* v2_buf  = alloc(3 * NFC);
    float* phi_buf = alloc(3 * NFC);
    float* envb    = alloc(N_EDGES);
    float* edgerec = alloc((size_t)N_EDGES * REC);
    ushort_t* wbf_hi = (ushort_t*)alloc(WPREP_W / 2 + 64);
    ushort_t* wbf_lo = (ushort_t*)alloc(WPREP_W / 2 + 64);
    float* robias   = alloc(128);
    int* cnt        = (int*)alloc(N_ATOMS);
    int* cursor     = (int*)alloc(N_ATOMS);   // adjacent to cnt (zeroed together)
    int* offsets    = (int*)alloc(N_ATOMS);

    // bf16 weight sub-offsets (elements, see prep_kernel)
    const size_t oW1 = 0, oW2 = 49152, oUV = 196608, oU1 = 294912, oU2 = 393216, oRO = 540672;

    prep_kernel<<<dim3(PREP_TOTAL / 256), dim3(256), 0, stream>>>(
        emb, z, s_buf,
        msg_w1, msg_w2, upd_u, upd_v, upd_w1, upd_w2, ro_w1, ro_b1,
        wbf_hi, wbf_lo, robias, cnt);
    count_kernel<<<dim3((N_EDGES + 255) / 256), dim3(256), 0, stream>>>(
        xyz, nbrs, envb, cnt);
    scan_kernel<<<dim3(1), dim3(1024), 0, stream>>>(cnt, offsets, out);
    build_kernel<<<dim3((N_EDGES + 255) / 256), dim3(256), 0, stream>>>(
        xyz, nbrs, envb, offsets, cursor, edgerec);

    // phi_0 = silu(s@W1+b1)@W2+b2
    phi0_kernel<<<dim3(NP/32), dim3(256), 0, stream>>>(
        s_buf,
        wbf_hi + oW1, wbf_lo + oW1, msg_b1,
        wbf_hi + oW2, wbf_lo + oW2, msg_b2,
        phi_buf);

    float* vin = v1_buf;
    float* vout = v2_buf;
    for (int i = 0; i < 3; ++i) {
        if (i == 0)
            msg_gather<1><<<dim3(N_ATOMS), dim3(128), 0, stream>>>(
                phi_buf, edgerec, rbf_w + (size_t)i*N_RBF*3*F, rbf_b + (size_t)i*3*F,
                vin, s_buf, vout, offsets, cnt);
        else
            msg_gather<0><<<dim3(N_ATOMS), dim3(128), 0, stream>>>(
                phi_buf, edgerec, rbf_w + (size_t)i*N_RBF*3*F, rbf_b + (size_t)i*3*F,
                vin, s_buf, vout, offsets, cnt);
        if (i < 2) {
            // upd(i) + phi(i+1) fused
            updphi_kernel<0><<<dim3(NP/32), dim3(256), 0, stream>>>(
                s_buf, vout,
                wbf_hi + oUV + (size_t)i*32768, wbf_lo + oUV + (size_t)i*32768,
                wbf_hi + oU1 + (size_t)i*32768, wbf_lo + oU1 + (size_t)i*32768,
                upd_b1 + (size_t)i*F,
                wbf_hi + oU2 + (size_t)i*49152, wbf_lo + oU2 + (size_t)i*49152,
                upd_b2 + (size_t)i*3*F,
                wbf_hi + oW1 + (size_t)(i+1)*16384, wbf_lo + oW1 + (size_t)(i+1)*16384,
                msg_b1 + (size_t)(i+1)*F,
                wbf_hi + oW2 + (size_t)(i+1)*49152, wbf_lo + oW2 + (size_t)(i+1)*49152,
                msg_b2 + (size_t)(i+1)*3*F,
                phi_buf,
                nullptr, nullptr, nullptr, nullptr);
        } else {
            // upd(2) + readout + mol reduce fused
            updphi_kernel<1><<<dim3(NP/32), dim3(256), 0, stream>>>(
                s_buf, vout,
                wbf_hi + oUV + (size_t)i*32768, wbf_lo + oUV + (size_t)i*32768,
                wbf_hi + oU1 + (size_t)i*32768, wbf_lo + oU1 + (size_t)i*32768,
                upd_b1 + (size_t)i*F,
                wbf_hi + oU2 + (size_t)i*49152, wbf_lo + oU2 + (size_t)i*49152,
                upd_b2 + (size_t)i*3*F,
                wbf_hi + oRO, wbf_lo + oRO, robias,
                nullptr, nullptr, nullptr,
                nullptr,
                ro_w2, ro_b2, molidx, out);
        }
        float* tmp = vin; vin = vout; vout = tmp;
    }
}

// Round 12
// 318.303 us; speedup vs baseline: 1.2867x; 1.0214x over previous
//
#include <hip/hip_runtime.h>

static constexpr int F = 128;
static constexpr int N_RBF = 20;
static constexpr int N_ATOMS = 8000;
static constexpr int NP = 8064;          // padded to 128
static constexpr int N_EDGES = 160000;
static constexpr int N_MOLS = 100;
static constexpr float CUTOFF = 5.0f;
static constexpr size_t NFC = (size_t)NP * F;
static constexpr int REC = 28;           // j, ev, ux,uy,uz, rbf[20], pad[3]
static constexpr int NPHI_BLK = NP / 32;                 // 252
static constexpr int NBUILD_BLK = (N_EDGES + 255) / 256; // 625
#define PIF 3.14159265358979323846f

typedef __attribute__((ext_vector_type(8))) short bf16x8;
typedef __attribute__((ext_vector_type(4))) float f32x4;
typedef unsigned short ushort_t;
typedef unsigned int uint_t;

__device__ __forceinline__ float silu_f(float x) { return x / (1.f + __expf(-x)); }

__device__ __forceinline__ ushort_t f2bf(float x) {   // round-to-nearest-even
    union { float f; uint_t u; } v; v.f = x;
    uint_t r = v.u + 0x7fffu + ((v.u >> 16) & 1u);
    return (ushort_t)(r >> 16);
}
__device__ __forceinline__ float bf2f(ushort_t h) {
    union { uint_t u; float f; } v; v.u = ((uint_t)h) << 16; return v.f;
}

// Session lessons (r4-r10 all regressed vs the r3 structure; r11 reproduced 325us):
//  - r4: cooperative launch silently fails under graph capture -> zeros.
//  - r5: fusing edge-gather into the 1-block/CU MFMA kernel: 3x slower (latency, no TLP).
//  - r6: phi/v/s inter-layer activations MUST stay f32 (bf16 phi -> 49% output error).
//  - r7: 2-deep B prefetch regressed 40->64us BUT its build+phi0 merge saved ~16us
//    (verified-correct). This file = r3 structure + that merge ONLY.
//  - r8: uvv pad increased conflicts; r9 direct-B 45->69us; r10 16-atom 2blk/CU no better.

// ---------------- pass 1: distance + envelope + live-edge histogram ----------------
__global__ __launch_bounds__(256) void count_kernel(
    const float* __restrict__ xyz, const int* __restrict__ nbrs,
    float* __restrict__ envb, int* __restrict__ cnt)
{
    int e = blockIdx.x * 256 + threadIdx.x;
    if (e >= N_EDGES) return;
    int i0 = nbrs[2*e+0], i1 = nbrs[2*e+1];
    float dx = xyz[3*i1+0] - xyz[3*i0+0];
    float dy = xyz[3*i1+1] - xyz[3*i0+1];
    float dz = xyz[3*i1+2] - xyz[3*i0+2];
    float d  = sqrtf(dx*dx + dy*dy + dz*dz);
    float ev = (d <= CUTOFF) ? 0.5f*(cosf(PIF*d/CUTOFF) + 1.f) : 0.f;
    envb[e] = ev;
    if (ev > 0.f) atomicAdd(&cnt[i0], 1);
}

// ---------------- exclusive scan of 8000 counters (single block) + zero out ----------------
__global__ __launch_bounds__(1024) void scan_kernel(
    const int* __restrict__ cnt, int* __restrict__ offsets, float* __restrict__ out)
{
    __shared__ int sums[1024];
    int tid = threadIdx.x;
    if (tid < N_MOLS) out[tid] = 0.f;
    int base = tid * 8;
    int local[8]; int s = 0;
    #pragma unroll
    for (int i = 0; i < 8; ++i) {
        int idx = base + i;
        local[i] = (idx < N_ATOMS) ? cnt[idx] : 0;
        s += local[i];
    }
    sums[tid] = s;
    __syncthreads();
    for (int d = 1; d < 1024; d <<= 1) {
        int v = (tid >= d) ? sums[tid - d] : 0;
        __syncthreads();
        sums[tid] += v;
        __syncthreads();
    }
    int ex = (tid == 0) ? 0 : sums[tid - 1];
    #pragma unroll
    for (int i = 0; i < 8; ++i) {
        int idx = base + i;
        if (idx < N_ATOMS) { offsets[idx] = ex; ex += local[i]; }
    }
}

// ---------------- fused prep: embed + weight transpose/split + zero cnt/cursor ----------------
// dst layout (bf16, [n][k] row-major K-contig), same offsets for hi and lo buffers:
//   W1t  3x(128n x 128k) @ 0        src msg_w1 (128k x 128n)
//   W2t  3x(384n x 128k) @ 49152    src msg_w2
//   UVt  3x(256n x 128k) @ 196608   src upd_u (n 0..127) | upd_v (n 128..255)
//   U1t  3x(128n x 256k) @ 294912   src upd_w1 (256k x 128n)
//   U2t  3x(384n x 128k) @ 393216   src upd_w2
//   ROt  128n x 128k    @ 540672    src ro_w1 (128k x 64n), cols 64..127 zero
//   robias[128] (f32)   idx 557056..557183: ro_b1 padded with zeros
static constexpr int WPREP_W = 557056;
static constexpr int WPREP_TOTAL = 557184;
static constexpr int NATF = N_ATOMS * F;
static constexpr int PREP_TOTAL = NATF + WPREP_TOTAL + 2 * N_ATOMS;
__global__ __launch_bounds__(256) void prep_kernel(
    const float* __restrict__ emb, const int* __restrict__ z, float* __restrict__ s,
    const float* __restrict__ msg_w1, const float* __restrict__ msg_w2,
    const float* __restrict__ upd_u,  const float* __restrict__ upd_v,
    const float* __restrict__ upd_w1, const float* __restrict__ upd_w2,
    const float* __restrict__ ro_w1,  const float* __restrict__ ro_b1,
    ushort_t* __restrict__ dhi, ushort_t* __restrict__ dlo,
    float* __restrict__ robias, int* __restrict__ cntz)
{
    int gidx = blockIdx.x * 256 + threadIdx.x;
    if (gidx < NATF) {                          // s = emb_table[z]
        int n = gidx >> 7, f = gidx & 127;
        s[gidx] = emb[z[n]*F + f];
        return;
    }
    int idx = gidx - NATF;
    if (idx >= WPREP_TOTAL) {                   // zero cnt + cursor (adjacent)
        cntz[idx - WPREP_TOTAL] = 0;
        return;
    }
    if (idx >= WPREP_W) {
        int l = idx - WPREP_W;
        robias[l] = (l < 64) ? ro_b1[l] : 0.f;
        return;
    }
    float val;
    if (idx < 540672) {
        const float* src; int K, N, rem;
        if (idx < 49152)       { int l = idx;          int c = l / 16384; rem = l % 16384; K = 128; N = 128; src = msg_w1 + c * 16384; }
        else if (idx < 196608) { int l = idx - 49152;  int c = l / 49152; rem = l % 49152; K = 128; N = 384; src = msg_w2 + c * 49152; }
        else if (idx < 294912) { int l = idx - 196608; int c = l / 32768; rem = l % 32768; K = 128; N = 128;
                                 if (rem < 16384) src = upd_u + c * 16384;
                                 else { src = upd_v + c * 16384; rem -= 16384; } }
        else if (idx < 393216) { int l = idx - 294912; int c = l / 32768; rem = l % 32768; K = 256; N = 128; src = upd_w1 + c * 32768; }
        else                   { int l = idx - 393216; int c = l / 49152; rem = l % 49152; K = 128; N = 384; src = upd_w2 + c * 49152; }
        int n = rem / K, k = rem % K;
        val = src[k * N + n];
    } else {
        int l = idx - 540672;             // ro_w1 pad: [n][k], n>=64 -> 0
        int n = l >> 7, k = l & 127;
        val = (n < 64) ? ro_w1[k * 64 + n] : 0.f;
    }
    ushort_t h = f2bf(val);
    dhi[idx] = h;
    dlo[idx] = f2bf(val - bf2f(h));
}

// ---------------- merged: phi0 MLP (blocks [0,252)) + build records (blocks [252,877)) ----------------
__global__ __launch_bounds__(256) void build_phi0_kernel(
    const float* __restrict__ xyz, const int* __restrict__ nbrs,
    const float* __restrict__ envb, const int* __restrict__ offsets,
    int* __restrict__ cursor, float* __restrict__ rec,
    const float* __restrict__ sbuf,
    const ushort_t* __restrict__ W1h, const ushort_t* __restrict__ W1l,
    const float* __restrict__ b1,
    const ushort_t* __restrict__ W2h, const ushort_t* __restrict__ W2l,
    const float* __restrict__ b2,
    float* __restrict__ C)
{
    if (blockIdx.x >= NPHI_BLK) {
        // ---------- build body ----------
        int e = (blockIdx.x - NPHI_BLK) * 256 + threadIdx.x;
        if (e >= N_EDGES) return;
        float ev = envb[e];
        if (ev <= 0.f) return;
        int i0 = nbrs[2*e+0], i1 = nbrs[2*e+1];
        float dx = xyz[3*i1+0] - xyz[3*i0+0];
        float dy = xyz[3*i1+1] - xyz[3*i0+1];
        float dz = xyz[3*i1+2] - xyz[3*i0+2];
        float d  = sqrtf(dx*dx + dy*dy + dz*dz);
        float inv = 1.f / d;
        int pos = offsets[i0] + atomicAdd(&cursor[i0], 1);
        float* r = rec + (size_t)pos * REC;
        r[0] = __int_as_float(i1);
        r[1] = ev;
        r[2] = dx*inv; r[3] = dy*inv; r[4] = dz*inv;
        float base = PIF*d/CUTOFF;
        float sc = inv * ev;   // fold env into rbf (w_s = (rbf*env)@W + b*env)
        #pragma unroll
        for (int k = 0; k < N_RBF; ++k)
            r[5 + k] = sinf((float)(k+1)*base) * sc;
        return;
    }

    // ---------- phi0 body (identical to verified r3 phi0_kernel) ----------
    __shared__ __align__(16) ushort_t Ah[2][32 * 40], Al[2][32 * 40];
    __shared__ __align__(16) ushort_t Bh[2][128 * 40], Bl[2][128 * 40];
    __shared__ __align__(16) ushort_t Hh[32 * 136], Hl[32 * 136];
    const int tid = threadIdx.x;
    const int wave = tid >> 6, lane = tid & 63;
    const int row_l = lane & 15, quad = lane >> 4;
    const int wn = wave * 32;
    const int m0 = blockIdx.x * 32;
    const int lrA = tid >> 3, ksA = (tid & 7) * 4;
    const int lrB = tid >> 1, ksB = (tid & 1) * 16;

    float4 rx;
    uint4 b_h0, b_h1, b_l0, b_l1;

    auto loadB1 = [&](int k0) {
        const ushort_t* bh = &W1h[(size_t)lrB * 128 + k0 + ksB];
        const ushort_t* bl = &W1l[(size_t)lrB * 128 + k0 + ksB];
        b_h0 = *(const uint4*)bh; b_h1 = *(const uint4*)(bh + 8);
        b_l0 = *(const uint4*)bl; b_l1 = *(const uint4*)(bl + 8);
    };
    auto loadB2 = [&](int it2) {
        int ct = it2 >> 2, k0 = (it2 & 3) * 32;
        const ushort_t* bh = &W2h[(size_t)(ct * 128 + lrB) * 128 + k0 + ksB];
        const ushort_t* bl = &W2l[(size_t)(ct * 128 + lrB) * 128 + k0 + ksB];
        b_h0 = *(const uint4*)bh; b_h1 = *(const uint4*)(bh + 8);
        b_l0 = *(const uint4*)bl; b_l1 = *(const uint4*)(bl + 8);
    };
    auto writeA = [&](int buf) {
        float e[4] = {rx.x, rx.y, rx.z, rx.w};
        ushort_t ph[4], pl[4];
        #pragma unroll
        for (int t = 0; t < 4; ++t) {
            ushort_t h = f2bf(e[t]);
            ph[t] = h; pl[t] = f2bf(e[t] - bf2f(h));
        }
        *(uint2*)&Ah[buf][lrA * 40 + ksA] = *(uint2*)ph;
        *(uint2*)&Al[buf][lrA * 40 + ksA] = *(uint2*)pl;
    };
    auto writeB = [&](int buf) {
        *(uint4*)&Bh[buf][lrB * 40 + ksB]     = b_h0;
        *(uint4*)&Bh[buf][lrB * 40 + ksB + 8] = b_h1;
        *(uint4*)&Bl[buf][lrB * 40 + ksB]     = b_l0;
        *(uint4*)&Bl[buf][lrB * 40 + ksB + 8] = b_l1;
    };

    f32x4 acc[2][2];
    #pragma unroll
    for (int i = 0; i < 2; ++i)
        #pragma unroll
        for (int j = 0; j < 2; ++j)
            #pragma unroll
            for (int r = 0; r < 4; ++r) acc[i][j][r] = 0.f;

    rx = *(const float4*)&sbuf[(size_t)(m0 + lrA) * 128 + ksA];
    loadB1(0);
    writeA(0); writeB(0);
    __syncthreads();
    #pragma unroll
    for (int it = 0; it < 4; ++it) {
        const int k0n = (it + 1) * 32;
        if (it + 1 < 4) {
            rx = *(const float4*)&sbuf[(size_t)(m0 + lrA) * 128 + k0n + ksA];
            loadB1(k0n);
        }
        bf16x8 ahf[2], alf[2], bhf[2], blf[2];
        #pragma unroll
        for (int i = 0; i < 2; ++i) {
            int ar = (i * 16 + row_l) * 40 + quad * 8;
            ahf[i] = *(const bf16x8*)&Ah[it & 1][ar];
            alf[i] = *(const bf16x8*)&Al[it & 1][ar];
        }
        #pragma unroll
        for (int j = 0; j < 2; ++j) {
            int br = (wn + j * 16 + row_l) * 40 + quad * 8;
            bhf[j] = *(const bf16x8*)&Bh[it & 1][br];
            blf[j] = *(const bf16x8*)&Bl[it & 1][br];
        }
        #pragma unroll
        for (int i = 0; i < 2; ++i)
            #pragma unroll
            for (int j = 0; j < 2; ++j) {
                acc[i][j] = __builtin_amdgcn_mfma_f32_16x16x32_bf16(ahf[i], bhf[j], acc[i][j], 0, 0, 0);
                acc[i][j] = __builtin_amdgcn_mfma_f32_16x16x32_bf16(ahf[i], blf[j], acc[i][j], 0, 0, 0);
                acc[i][j] = __builtin_amdgcn_mfma_f32_16x16x32_bf16(alf[i], bhf[j], acc[i][j], 0, 0, 0);
            }
        if (it + 1 < 4) { writeA((it + 1) & 1); writeB((it + 1) & 1); }
        __syncthreads();
    }
    #pragma unroll
    for (int j = 0; j < 2; ++j) {
        int col = wn + j * 16 + row_l;
        float bval = b1[col];
        #pragma unroll
        for (int i = 0; i < 2; ++i)
            #pragma unroll
            for (int r = 0; r < 4; ++r) {
                int row = i * 16 + quad * 4 + r;
                float v = silu_f(acc[i][j][r] + bval);
                ushort_t h = f2bf(v);
                Hh[row * 136 + col] = h;
                Hl[row * 136 + col] = f2bf(v - bf2f(h));
            }
    }

    #pragma unroll
    for (int i = 0; i < 2; ++i)
        #pragma unroll
        for (int j = 0; j < 2; ++j)
            #pragma unroll
            for (int r = 0; r < 4; ++r) acc[i][j][r] = 0.f;
    loadB2(0); writeB(0);
    __syncthreads();
    #pragma unroll
    for (int it = 0; it < 12; ++it) {
        const int k0 = (it & 3) * 32;
        if (it + 1 < 12) loadB2(it + 1);
        bf16x8 ahf[2], alf[2], bhf[2], blf[2];
        #pragma unroll
        for (int i = 0; i < 2; ++i) {
            int ar = (i * 16 + row_l) * 136 + k0 + quad * 8;
            ahf[i] = *(const bf16x8*)&Hh[ar];
            alf[i] = *(const bf16x8*)&Hl[ar];
        }
        #pragma unroll
        for (int j = 0; j < 2; ++j) {
            int br = (wn + j * 16 + row_l) * 40 + quad * 8;
            bhf[j] = *(const bf16x8*)&Bh[it & 1][br];
            blf[j] = *(const bf16x8*)&Bl[it & 1][br];
        }
        #pragma unroll
        for (int i = 0; i < 2; ++i)
            #pragma unroll
            for (int j = 0; j < 2; ++j) {
                acc[i][j] = __builtin_amdgcn_mfma_f32_16x16x32_bf16(ahf[i], bhf[j], acc[i][j], 0, 0, 0);
                acc[i][j] = __builtin_amdgcn_mfma_f32_16x16x32_bf16(ahf[i], blf[j], acc[i][j], 0, 0, 0);
                acc[i][j] = __builtin_amdgcn_mfma_f32_16x16x32_bf16(alf[i], bhf[j], acc[i][j], 0, 0, 0);
            }
        if ((it & 3) == 3) {
            const int ct = it >> 2;
            #pragma unroll
            for (int j = 0; j < 2; ++j) {
                int col = ct * 128 + wn + j * 16 + row_l;
                float bval = b2[col];
                #pragma unroll
                for (int i = 0; i < 2; ++i)
                    #pragma unroll
                    for (int r = 0; r < 4; ++r) {
                        int row = i * 16 + quad * 4 + r;
                        C[(size_t)(m0 + row) * 384 + col] = acc[i][j][r] + bval;
                    }
            }
            #pragma unroll
            for (int i = 0; i < 2; ++i)
                #pragma unroll
                for (int j = 0; j < 2; ++j)
                    #pragma unroll
                    for (int r = 0; r < 4; ++r) acc[i][j][r] = 0.f;
        }
        if (it + 1 < 12) writeB((it + 1) & 1);
        __syncthreads();
    }
}

// ---------------- fused update (+ next phi / readout tail) ----------------
// Phase 0: [uv|vv] = v @ UVt in LDS.  Phase 1: h = silu([s|norm(vv)]@W1+b1).
// Phase 2: a = h@W2+b2; finupd folded into column-tile epilogues; s_new kept in LDS (sS).
// Phase 3 (TAIL=0): phi_{i+1} = silu(sS@XW1+xb1)@XW2+xb2 -> phi_out.
// Phase 3 (TAIL=1): h2 = silu(sS@ROt+robias); atom_e = h2[0:64]·w2ro + b2ro;
//                   per-block mol table -> atomicAdd(out).  (ct0/a_vv skipped: v dead.)
template<int TAIL>
__global__ __launch_bounds__(256) void updphi_kernel(
    float* __restrict__ s_io, float* __restrict__ v_io,
    const ushort_t* __restrict__ UVh, const ushort_t* __restrict__ UVl,
    const ushort_t* __restrict__ W1h, const ushort_t* __restrict__ W1l,
    const float* __restrict__ b1,
    const ushort_t* __restrict__ W2h, const ushort_t* __restrict__ W2l,
    const float* __restrict__ b2,
    const ushort_t* __restrict__ XW1h, const ushort_t* __restrict__ XW1l,
    const float* __restrict__ xb1,
    const ushort_t* __restrict__ XW2h, const ushort_t* __restrict__ XW2l,
    const float* __restrict__ xb2,
    float* __restrict__ phi_out,
    const float* __restrict__ w2ro, const float* __restrict__ b2ro,
    const int* __restrict__ mol, float* __restrict__ outp)
{
    __shared__ float uvv[96][260];                     // [ln*3+d][0:128 uv | 128:256 vv]
    __shared__ __align__(16) ushort_t Bh[2][128 * 40];
    __shared__ __align__(16) ushort_t Bl[2][128 * 40];
    __shared__ __align__(16) unsigned char AH[17408];  // union: A-stage dbuf / H
    __shared__ float molacc[128];                      // TAIL=1 only
    __shared__ float redl[32][4];                      // TAIL=1 only
    const int tid = threadIdx.x;
    const int wave = tid >> 6, lane = tid & 63;
    const int row_l = lane & 15, quad = lane >> 4;
    const int wn = wave * 32;
    const int m0 = blockIdx.x * 32;
    const int lrA = tid >> 3;          // 0..31
    const int ksA = (tid & 7) * 4;     // 0,4,..28
    const int lrB = tid >> 1, ksB = (tid & 1) * 16;

    float* sS = &uvv[0][0];            // 32 x 132 f32 (overlays dead uvv rows in phase 2 tail)
    constexpr int SSTR = 132;

    // ================= phase 0: [uv|vv] = v @ UVt (M=96, N=256, K=128) =================
    {
        ushort_t* A0h = (ushort_t*)AH;                 // [96][40]
        ushort_t* A0l = A0h + 96 * 40;
        ushort_t* B0h = &Bh[0][0];                     // [256][40] spans both buffers
        ushort_t* B0l = &Bl[0][0];
        f32x4 acc0[6][4];
        #pragma unroll
        for (int i = 0; i < 6; ++i)
            #pragma unroll
            for (int j = 0; j < 4; ++j)
                #pragma unroll
                for (int r = 0; r < 4; ++r) acc0[i][j][r] = 0.f;
        for (int k0 = 0; k0 < 128; k0 += 32) {
            #pragma unroll
            for (int g = 0; g < 3; ++g) {
                int row = g * 32 + lrA;
                float4 v = *(const float4*)&v_io[(size_t)(m0 * 3 + row) * 128 + k0 + ksA];
                float e[4] = {v.x, v.y, v.z, v.w};
                ushort_t ph[4], pl[4];
                #pragma unroll
                for (int t = 0; t < 4; ++t) {
                    ushort_t h = f2bf(e[t]);
                    ph[t] = h; pl[t] = f2bf(e[t] - bf2f(h));
                }
                *(uint2*)&A0h[row * 40 + ksA] = *(uint2*)ph;
                *(uint2*)&A0l[row * 40 + ksA] = *(uint2*)pl;
            }
            {
                const ushort_t* bh = &UVh[(size_t)tid * 128 + k0];
                const ushort_t* bl = &UVl[(size_t)tid * 128 + k0];
                *(uint4*)&B0h[tid * 40 + 0]  = *(const uint4*)(bh + 0);
                *(uint4*)&B0h[tid * 40 + 8]  = *(const uint4*)(bh + 8);
                *(uint4*)&B0h[tid * 40 + 16] = *(const uint4*)(bh + 16);
                *(uint4*)&B0h[tid * 40 + 24] = *(const uint4*)(bh + 24);
                *(uint4*)&B0l[tid * 40 + 0]  = *(const uint4*)(bl + 0);
                *(uint4*)&B0l[tid * 40 + 8]  = *(const uint4*)(bl + 8);
                *(uint4*)&B0l[tid * 40 + 16] = *(const uint4*)(bl + 16);
                *(uint4*)&B0l[tid * 40 + 24] = *(const uint4*)(bl + 24);
            }
            __syncthreads();
            bf16x8 a0h[6], a0l[6], b0h[4], b0l[4];
            #pragma unroll
            for (int i = 0; i < 6; ++i) {
                int ar = (i * 16 + row_l) * 40 + quad * 8;
                a0h[i] = *(const bf16x8*)&A0h[ar];
                a0l[i] = *(const bf16x8*)&A0l[ar];
            }
            #pragma unroll
            for (int j = 0; j < 4; ++j) {
                int br = (wave * 64 + j * 16 + row_l) * 40 + quad * 8;
                b0h[j] = *(const bf16x8*)&B0h[br];
                b0l[j] = *(const bf16x8*)&B0l[br];
            }
            #pragma unroll
            for (int i = 0; i < 6; ++i)
                #pragma unroll
                for (int j = 0; j < 4; ++j) {
                    acc0[i][j] = __builtin_amdgcn_mfma_f32_16x16x32_bf16(a0h[i], b0h[j], acc0[i][j], 0, 0, 0);
                    acc0[i][j] = __builtin_amdgcn_mfma_f32_16x16x32_bf16(a0h[i], b0l[j], acc0[i][j], 0, 0, 0);
                    acc0[i][j] = __builtin_amdgcn_mfma_f32_16x16x32_bf16(a0l[i], b0h[j], acc0[i][j], 0, 0, 0);
                }
            __syncthreads();
        }
        #pragma unroll
        for (int i = 0; i < 6; ++i)
            #pragma unroll
            for (int j = 0; j < 4; ++j)
                #pragma unroll
                for (int r = 0; r < 4; ++r)
                    uvv[i * 16 + quad * 4 + r][wave * 64 + j * 16 + row_l] = acc0[i][j][r];
        __syncthreads();
    }

    // ================= phase 1: h = silu([s | norm(vv)] @ W1 + b1) =================
    ushort_t* Ah1 = (ushort_t*)AH;                     // [2][32*40]
    ushort_t* Al1 = Ah1 + 2 * 32 * 40;
    ushort_t* Hh  = (ushort_t*)AH;                     // [32][136]
    ushort_t* Hl  = Hh + 32 * 136;

    float4 rx;
    uint4 b_h0, b_h1, b_l0, b_l1;

    auto loadB1 = [&](int k0) {
        const ushort_t* bh = &W1h[(size_t)lrB * 256 + k0 + ksB];
        const ushort_t* bl = &W1l[(size_t)lrB * 256 + k0 + ksB];
        b_h0 = *(const uint4*)bh; b_h1 = *(const uint4*)(bh + 8);
        b_l0 = *(const uint4*)bl; b_l1 = *(const uint4*)(bl + 8);
    };
    auto writeB = [&](int buf) {
        *(uint4*)&Bh[buf][lrB * 40 + ksB]     = b_h0;
        *(uint4*)&Bh[buf][lrB * 40 + ksB + 8] = b_h1;
        *(uint4*)&Bl[buf][lrB * 40 + ksB]     = b_l0;
        *(uint4*)&Bl[buf][lrB * 40 + ksB + 8] = b_l1;
    };
    auto writeA1 = [&](int buf, int k0) {
        float e[4];
        if (k0 < 128) {
            e[0] = rx.x; e[1] = rx.y; e[2] = rx.z; e[3] = rx.w;
        } else {
            int f = k0 + ksA;          // uvv col 128..255 (vv)
            #pragma unroll
            for (int t = 0; t < 4; ++t) {
                float x = uvv[lrA * 3 + 0][f + t];
                float y = uvv[lrA * 3 + 1][f + t];
                float z = uvv[lrA * 3 + 2][f + t];
                e[t] = sqrtf(x * x + y * y + z * z + 1e-15f);
            }
        }
        ushort_t ph[4], pl[4];
        #pragma unroll
        for (int t = 0; t < 4; ++t) {
            ushort_t h = f2bf(e[t]);
            ph[t] = h; pl[t] = f2bf(e[t] - bf2f(h));
        }
        *(uint2*)&Ah1[buf * 1280 + lrA * 40 + ksA] = *(uint2*)ph;
        *(uint2*)&Al1[buf * 1280 + lrA * 40 + ksA] = *(uint2*)pl;
    };

    f32x4 acc[2][2];
    #pragma unroll
    for (int i = 0; i < 2; ++i)
        #pragma unroll
        for (int j = 0; j < 2; ++j)
            #pragma unroll
            for (int r = 0; r < 4; ++r) acc[i][j][r] = 0.f;

    rx = *(const float4*)&s_io[(size_t)(m0 + lrA) * 128 + ksA];
    loadB1(0);
    writeA1(0, 0); writeB(0);
    __syncthreads();
    #pragma unroll
    for (int it = 0; it < 8; ++it) {
        const int k0n = (it + 1) * 32;
        if (it + 1 < 8) {
            if (k0n < 128) rx = *(const float4*)&s_io[(size_t)(m0 + lrA) * 128 + k0n + ksA];
            loadB1(k0n);
        }
        bf16x8 ahf[2], alf[2], bhf[2], blf[2];
        #pragma unroll
        for (int i = 0; i < 2; ++i) {
            int ar = (it & 1) * 1280 + (i * 16 + row_l) * 40 + quad * 8;
            ahf[i] = *(const bf16x8*)&Ah1[ar];
            alf[i] = *(const bf16x8*)&Al1[ar];
        }
        #pragma unroll
        for (int j = 0; j < 2; ++j) {
            int br = (wn + j * 16 + row_l) * 40 + quad * 8;
            bhf[j] = *(const bf16x8*)&Bh[it & 1][br];
            blf[j] = *(const bf16x8*)&Bl[it & 1][br];
        }
        #pragma unroll
        for (int i = 0; i < 2; ++i)
            #pragma unroll
            for (int j = 0; j < 2; ++j) {
                acc[i][j] = __builtin_amdgcn_mfma_f32_16x16x32_bf16(ahf[i], bhf[j], acc[i][j], 0, 0, 0);
                acc[i][j] = __builtin_amdgcn_mfma_f32_16x16x32_bf16(ahf[i], blf[j], acc[i][j], 0, 0, 0);
                acc[i][j] = __builtin_amdgcn_mfma_f32_16x16x32_bf16(alf[i], bhf[j], acc[i][j], 0, 0, 0);
            }
        if (it + 1 < 8) { writeA1((it + 1) & 1, k0n); writeB((it + 1) & 1); }
        __syncthreads();
    }
    // epilogue 1 -> H (overwrites phase-1 A region; loop-end barrier makes it safe)
    #pragma unroll
    for (int j = 0; j < 2; ++j) {
        int col = wn + j * 16 + row_l;
        float bval = b1[col];
        #pragma unroll
        for (int i = 0; i < 2; ++i)
            #pragma unroll
            for (int r = 0; r < 4; ++r) {
                int row = i * 16 + quad * 4 + r;
                float v = silu_f(acc[i][j][r] + bval);
                ushort_t h = f2bf(v);
                Hh[row * 136 + col] = h;
                Hl[row * 136 + col] = f2bf(v - bf2f(h));
            }
    }

    // ================= phase 2: a = h @ W2 + b2, finupd folded into ct epilogues =================
    constexpr int CT0 = TAIL ? 1 : 0;          // TAIL=1: a_vv unused (v dead) -> skip ct0
    constexpr int NIT2 = (3 - CT0) * 4;
    auto loadB2 = [&](int it2) {
        int ct = CT0 + (it2 >> 2), k0 = (it2 & 3) * 32;
        const ushort_t* bh = &W2h[(size_t)(ct * 128 + lrB) * 128 + k0 + ksB];
        const ushort_t* bl = &W2l[(size_t)(ct * 128 + lrB) * 128 + k0 + ksB];
        b_h0 = *(const uint4*)bh; b_h1 = *(const uint4*)(bh + 8);
        b_l0 = *(const uint4*)bl; b_l1 = *(const uint4*)(bl + 8);
    };

    #pragma unroll
    for (int i = 0; i < 2; ++i)
        #pragma unroll
        for (int j = 0; j < 2; ++j)
            #pragma unroll
            for (int r = 0; r < 4; ++r) acc[i][j][r] = 0.f;
    f32x4 ssum[2][2];

    loadB2(0); writeB(0);
    __syncthreads();
    #pragma unroll
    for (int it = 0; it < NIT2; ++it) {
        const int k0 = (it & 3) * 32;
        if (it + 1 < NIT2) loadB2(it + 1);
        bf16x8 ahf[2], alf[2], bhf[2], blf[2];
        #pragma unroll
        for (int i = 0; i < 2; ++i) {
            int ar = (i * 16 + row_l) * 136 + k0 + quad * 8;
            ahf[i] = *(const bf16x8*)&Hh[ar];
            alf[i] = *(const bf16x8*)&Hl[ar];
        }
        #pragma unroll
        for (int j = 0; j < 2; ++j) {
            int br = (wn + j * 16 + row_l) * 40 + quad * 8;
            bhf[j] = *(const bf16x8*)&Bh[it & 1][br];
            blf[j] = *(const bf16x8*)&Bl[it & 1][br];
        }
        #pragma unroll
        for (int i = 0; i < 2; ++i)
            #pragma unroll
            for (int j = 0; j < 2; ++j) {
                acc[i][j] = __builtin_amdgcn_mfma_f32_16x16x32_bf16(ahf[i], bhf[j], acc[i][j], 0, 0, 0);
                acc[i][j] = __builtin_amdgcn_mfma_f32_16x16x32_bf16(ahf[i], blf[j], acc[i][j], 0, 0, 0);
                acc[i][j] = __builtin_amdgcn_mfma_f32_16x16x32_bf16(alf[i], bhf[j], acc[i][j], 0, 0, 0);
            }
        if ((it & 3) == 3) {                     // column-tile epilogue + finupd slice
            const int ct = CT0 + (it >> 2);
            #pragma unroll
            for (int j = 0; j < 2; ++j) {
                int f = wn + j * 16 + row_l;
                float bval = b2[ct * 128 + f];
                #pragma unroll
                for (int i = 0; i < 2; ++i)
                    #pragma unroll
                    for (int r = 0; r < 4; ++r) {
                        int ln = i * 16 + quad * 4 + r;
                        float a = acc[i][j][r] + bval;
                        if (ct == 0) {                      // a_vv: v += uv * a
                            size_t vb = (size_t)(m0 + ln) * 3 * F + f;
                            v_io[vb]         += uvv[ln * 3 + 0][f] * a;
                            v_io[vb + F]     += uvv[ln * 3 + 1][f] * a;
                            v_io[vb + 2 * F] += uvv[ln * 3 + 2][f] * a;
                        } else if (ct == 1) {               // a_sv: ssum = <uv,vv> * a
                            float dot = uvv[ln * 3 + 0][f] * uvv[ln * 3 + 0][128 + f]
                                      + uvv[ln * 3 + 1][f] * uvv[ln * 3 + 1][128 + f]
                                      + uvv[ln * 3 + 2][f] * uvv[ln * 3 + 2][128 + f];
                            ssum[i][j][r] = dot * a;
                        } else {                            // a_ss: s_new = s + ssum + a
                            float sv = s_io[(size_t)(m0 + ln) * F + f] + ssum[i][j][r] + a;
                            if constexpr (TAIL == 0) s_io[(size_t)(m0 + ln) * F + f] = sv;
                            sS[ln * SSTR + f] = sv;         // sS overlays uvv rows (dead by now)
                        }
                    }
            }
            #pragma unroll
            for (int i = 0; i < 2; ++i)
                #pragma unroll
                for (int j = 0; j < 2; ++j)
                    #pragma unroll
                    for (int r = 0; r < 4; ++r) acc[i][j][r] = 0.f;
        }
        if (it + 1 < NIT2) writeB((it + 1) & 1);
        __syncthreads();
    }

    // ================= phase 3: next-phi MLP (TAIL=0) or readout (TAIL=1), A = sS =================
    if constexpr (TAIL == 1) { if (tid < 128) molacc[tid] = 0.f; }
    ushort_t* Ah3 = (ushort_t*)AH;
    ushort_t* Al3 = Ah3 + 2 * 1280;

    auto loadB31 = [&](int k0) {
        const ushort_t* bh = &XW1h[(size_t)lrB * 128 + k0 + ksB];
        const ushort_t* bl = &XW1l[(size_t)lrB * 128 + k0 + ksB];
        b_h0 = *(const uint4*)bh; b_h1 = *(const uint4*)(bh + 8);
        b_l0 = *(const uint4*)bl; b_l1 = *(const uint4*)(bl + 8);
    };
    auto writeA3 = [&](int buf, int k0) {
        float e[4];
        #pragma unroll
        for (int t = 0; t < 4; ++t) e[t] = sS[lrA * SSTR + k0 + ksA + t];
        ushort_t ph[4], pl[4];
        #pragma unroll
        for (int t = 0; t < 4; ++t) {
            ushort_t h = f2bf(e[t]);
            ph[t] = h; pl[t] = f2bf(e[t] - bf2f(h));
        }
        *(uint2*)&Ah3[buf * 1280 + lrA * 40 + ksA] = *(uint2*)ph;
        *(uint2*)&Al3[buf * 1280 + lrA * 40 + ksA] = *(uint2*)pl;
    };

    #pragma unroll
    for (int i = 0; i < 2; ++i)
        #pragma unroll
        for (int j = 0; j < 2; ++j)
            #pragma unroll
            for (int r = 0; r < 4; ++r) acc[i][j][r] = 0.f;

    loadB31(0);
    writeA3(0, 0); writeB(0);
    __syncthreads();
    #pragma unroll
    for (int it = 0; it < 4; ++it) {
        const int k0n = (it + 1) * 32;
        if (it + 1 < 4) loadB31(k0n);
        bf16x8 ahf[2], alf[2], bhf[2], blf[2];
        #pragma unroll
        for (int i = 0; i < 2; ++i) {
            int ar = (it & 1) * 1280 + (i * 16 + row_l) * 40 + quad * 8;
            ahf[i] = *(const bf16x8*)&Ah3[ar];
            alf[i] = *(const bf16x8*)&Al3[ar];
        }
        #pragma unroll
        for (int j = 0; j < 2; ++j) {
            int br = (wn + j * 16 + row_l) * 40 + quad * 8;
            bhf[j] = *(const bf16x8*)&Bh[it & 1][br];
            blf[j] = *(const bf16x8*)&Bl[it & 1][br];
        }
        #pragma unroll
        for (int i = 0; i < 2; ++i)
            #pragma unroll
            for (int j = 0; j < 2; ++j) {
                acc[i][j] = __builtin_amdgcn_mfma_f32_16x16x32_bf16(ahf[i], bhf[j], acc[i][j], 0, 0, 0);
                acc[i][j] = __builtin_amdgcn_mfma_f32_16x16x32_bf16(ahf[i], blf[j], acc[i][j], 0, 0, 0);
                acc[i][j] = __builtin_amdgcn_mfma_f32_16x16x32_bf16(alf[i], bhf[j], acc[i][j], 0, 0, 0);
            }
        if (it + 1 < 4) { writeA3((it + 1) & 1, k0n); writeB((it + 1) & 1); }
        __syncthreads();
    }

    if constexpr (TAIL == 0) {
        // -> H, then stage 2 with XW2 -> phi_out
        #pragma unroll
        for (int j = 0; j < 2; ++j) {
            int col = wn + j * 16 + row_l;
            float bval = xb1[col];
            #pragma unroll
            for (int i = 0; i < 2; ++i)
                #pragma unroll
                for (int r = 0; r < 4; ++r) {
                    int row = i * 16 + quad * 4 + r;
                    float v = silu_f(acc[i][j][r] + bval);
                    ushort_t h = f2bf(v);
                    Hh[row * 136 + col] = h;
                    Hl[row * 136 + col] = f2bf(v - bf2f(h));
                }
        }
        auto loadB32 = [&](int it2) {
            int ct = it2 >> 2, k0 = (it2 & 3) * 32;
            const ushort_t* bh = &XW2h[(size_t)(ct * 128 + lrB) * 128 + k0 + ksB];
            const ushort_t* bl = &XW2l[(size_t)(ct * 128 + lrB) * 128 + k0 + ksB];
            b_h0 = *(const uint4*)bh; b_h1 = *(const uint4*)(bh + 8);
            b_l0 = *(const uint4*)bl; b_l1 = *(const uint4*)(bl + 8);
        };
        #pragma unroll
        for (int i = 0; i < 2; ++i)
            #pragma unroll
            for (int j = 0; j < 2; ++j)
                #pragma unroll
                for (int r = 0; r < 4; ++r) acc[i][j][r] = 0.f;
        loadB32(0); writeB(0);
        __syncthreads();
        #pragma unroll
        for (int it = 0; it < 12; ++it) {
            const int k0 = (it & 3) * 32;
            if (it + 1 < 12) loadB32(it + 1);
            bf16x8 ahf[2], alf[2], bhf[2], blf[2];
            #pragma unroll
            for (int i = 0; i < 2; ++i) {
                int ar = (i * 16 + row_l) * 136 + k0 + quad * 8;
                ahf[i] = *(const bf16x8*)&Hh[ar];
                alf[i] = *(const bf16x8*)&Hl[ar];
            }
            #pragma unroll
            for (int j = 0; j < 2; ++j) {
                int br = (wn + j * 16 + row_l) * 40 + quad * 8;
                bhf[j] = *(const bf16x8*)&Bh[it & 1][br];
                blf[j] = *(const bf16x8*)&Bl[it & 1][br];
            }
            #pragma unroll
            for (int i = 0; i < 2; ++i)
                #pragma unroll
                for (int j = 0; j < 2; ++j) {
                    acc[i][j] = __builtin_amdgcn_mfma_f32_16x16x32_bf16(ahf[i], bhf[j], acc[i][j], 0, 0, 0);
                    acc[i][j] = __builtin_amdgcn_mfma_f32_16x16x32_bf16(ahf[i], blf[j], acc[i][j], 0, 0, 0);
                    acc[i][j] = __builtin_amdgcn_mfma_f32_16x16x32_bf16(alf[i], bhf[j], acc[i][j], 0, 0, 0);
                }
            if ((it & 3) == 3) {
                const int ct = it >> 2;
                #pragma unroll
                for (int j = 0; j < 2; ++j) {
                    int col = ct * 128 + wn + j * 16 + row_l;
                    float bval = xb2[col];
                    #pragma unroll
                    for (int i = 0; i < 2; ++i)
                        #pragma unroll
                        for (int r = 0; r < 4; ++r) {
                            int row = i * 16 + quad * 4 + r;
                            phi_out[(size_t)(m0 + row) * 384 + col] = acc[i][j][r] + bval;
                        }
                }
                #pragma unroll
                for (int i = 0; i < 2; ++i)
                    #pragma unroll
                    for (int j = 0; j < 2; ++j)
                        #pragma unroll
                        for (int r = 0; r < 4; ++r) acc[i][j][r] = 0.f;
            }
            if (it + 1 < 12) writeB((it + 1) & 1);
            __syncthreads();
        }
    } else {
        // readout: atom_e = sum_{col<64} silu(acc+robias)·w2 ; block mol table -> out
        float part[2][4];
        #pragma unroll
        for (int i = 0; i < 2; ++i)
            #pragma unroll
            for (int r = 0; r < 4; ++r) part[i][r] = 0.f;
        #pragma unroll
        for (int j = 0; j < 2; ++j) {
            int col = wn + j * 16 + row_l;
            float bv = xb1[col];                       // robias (zero-padded)
            float wv = (col < 64) ? w2ro[col] : 0.f;
            #pragma unroll
            for (int i = 0; i < 2; ++i)
                #pragma unroll
                for (int r = 0; r < 4; ++r)
                    part[i][r] += silu_f(acc[i][j][r] + bv) * wv;
        }
        #pragma unroll
        for (int o = 1; o < 16; o <<= 1)
            #pragma unroll
            for (int i = 0; i < 2; ++i)
                #pragma unroll
                for (int r = 0; r < 4; ++r)
                    part[i][r] += __shfl_xor(part[i][r], o);
        if (row_l == 0)
            #pragma unroll
            for (int i = 0; i < 2; ++i)
                #pragma unroll
                for (int r = 0; r < 4; ++r)
                    redl[i * 16 + quad * 4 + r][wave] = part[i][r];
        __syncthreads();
        if (tid < 32) {
            int n = m0 + tid;
            if (n < N_ATOMS) {
                float e = redl[tid][0] + redl[tid][1] + redl[tid][2] + redl[tid][3] + b2ro[0];
                atomicAdd(&molacc[mol[n]], e);
            }
        }
        __syncthreads();
        if (tid < 100 && molacc[tid] != 0.f) atomicAdd(&outp[tid], molacc[tid]);
    }
}

// ---------------- atom-centric message gather (atomic-free, packed records) ----------------
template<int ZVIN>
__global__ __launch_bounds__(128) void msg_gather(
    const float* __restrict__ phi, const float* __restrict__ rec,
    const float* __restrict__ rbf_w, const float* __restrict__ rbf_b,
    const float* __restrict__ v_in, float* __restrict__ s,
    float* __restrict__ v_out, const int* __restrict__ offsets,
    const int* __restrict__ cnt)
{
    const int n = blockIdx.x, tid = threadIdx.x;
    float W0[N_RBF], W1[N_RBF], W2[N_RBF];
    #pragma unroll
    for (int k = 0; k < N_RBF; ++k) {
        W0[k] = rbf_w[k*3*F + tid];
        W1[k] = rbf_w[k*3*F + F + tid];
        W2[k] = rbf_w[k*3*F + 2*F + tid];
    }
    const float b0 = rbf_b[tid], b1 = rbf_b[F + tid], b2 = rbf_b[2*F + tid];
    float ds = 0.f, dvx = 0.f, dvy = 0.f, dvz = 0.f;
    const int off = offsets[n], c = cnt[n];
    const float* r = rec + (size_t)off * REC;
    #pragma unroll 2
    for (int t = 0; t < c; ++t, r += REC) {
        int j = __float_as_int(r[0]);
        float ev = r[1];
        float ux = r[2], uy = r[3], uz = r[4];
        float w0 = b0 * ev, w1 = b1 * ev, w2 = b2 * ev;
        #pragma unroll
        for (int k = 0; k < N_RBF; ++k) {
            float rk = r[5 + k];
            w0 += rk * W0[k]; w1 += rk * W1[k]; w2 += rk * W2[k];
        }
        const float* prow = phi + (size_t)j * 3 * F;
        float s0 = prow[tid] * w0;
        float s1 = prow[F + tid] * w1;
        float s2 = prow[2*F + tid] * w2;
        ds  += s1;
        if constexpr (ZVIN) {
            dvx += s2*ux; dvy += s2*uy; dvz += s2*uz;
        } else {
            const float* vrow = v_in + (size_t)j * 3 * F;
            dvx += s2*ux + s0 * vrow[tid];
            dvy += s2*uy + s0 * vrow[F + tid];
            dvz += s2*uz + s0 * vrow[2*F + tid];
        }
    }
    s[(size_t)n * F + tid] += ds;
    size_t vb = (size_t)n * 3 * F + tid;
    if constexpr (ZVIN) {
        v_out[vb]       = dvx;
        v_out[vb + F]   = dvy;
        v_out[vb + 2*F] = dvz;
    } else {
        v_out[vb]       = v_in[vb]       + dvx;
        v_out[vb + F]   = v_in[vb + F]   + dvy;
        v_out[vb + 2*F] = v_in[vb + 2*F] + dvz;
    }
}

extern "C" void kernel_launch(void* const* d_in, const int* in_sizes, int n_in,
                              void* d_out, int out_size, void* d_ws, size_t ws_size,
                              hipStream_t stream)
{
    const float* xyz    = (const float*)d_in[0];
    const float* emb    = (const float*)d_in[1];
    const float* msg_w1 = (const float*)d_in[2];
    const float* msg_b1 = (const float*)d_in[3];
    const float* msg_w2 = (const float*)d_in[4];
    const float* msg_b2 = (const float*)d_in[5];
    const float* rbf_w  = (const float*)d_in[6];
    const float* rbf_b  = (const float*)d_in[7];
    const float* upd_u  = (const float*)d_in[8];
    const float* upd_v  = (const float*)d_in[9];
    const float* upd_w1 = (const float*)d_in[10];
    const float* upd_b1 = (const float*)d_in[11];
    const float* upd_w2 = (const float*)d_in[12];
    const float* upd_b2 = (const float*)d_in[13];
    const float* ro_w1  = (const float*)d_in[14];
    const float* ro_b1  = (const float*)d_in[15];
    const float* ro_w2  = (const float*)d_in[16];
    const float* ro_b2  = (const float*)d_in[17];
    const int*   z      = (const int*)d_in[18];
    const int*   nbrs   = (const int*)d_in[19];
    const int*   molidx = (const int*)d_in[20];
    float* out = (float*)d_out;

    float* ws = (float*)d_ws;
    size_t off = 0;
    auto alloc = [&](size_t n) { float* p = ws + off; off += n; return p; };
    float* s_buf   = alloc(NFC);
    float* v1_buf  = alloc(3 * NFC);       // [n][3][f]
    float* v2_buf  = alloc(3 * NFC);
    float* phi_buf = alloc(3 * NFC);
    float* envb    = alloc(N_EDGES);
    float* edgerec = alloc((size_t)N_EDGES * REC);
    ushort_t* wbf_hi = (ushort_t*)alloc(WPREP_W / 2 + 64);
    ushort_t* wbf_lo = (ushort_t*)alloc(WPREP_W / 2 + 64);
    float* robias   = alloc(128);
    int* cnt        = (int*)alloc(N_ATOMS);
    int* cursor     = (int*)alloc(N_ATOMS);   // adjacent to cnt (zeroed together)
    int* offsets    = (int*)alloc(N_ATOMS);

    // bf16 weight sub-offsets (elements, see prep_kernel)
    const size_t oW1 = 0, oW2 = 49152, oUV = 196608, oU1 = 294912, oU2 = 393216, oRO = 540672;

    prep_kernel<<<dim3(PREP_TOTAL / 256), dim3(256), 0, stream>>>(
        emb, z, s_buf,
        msg_w1, msg_w2, upd_u, upd_v, upd_w1, upd_w2, ro_w1, ro_b1,
        wbf_hi, wbf_lo, robias, cnt);
    count_kernel<<<dim3((N_EDGES + 255) / 256), dim3(256), 0, stream>>>(
        xyz, nbrs, envb, cnt);
    scan_kernel<<<dim3(1), dim3(1024), 0, stream>>>(cnt, offsets, out);
    // merged: phi_0 MLP (blocks [0,252)) + build live-edge records (blocks [252,877))
    build_phi0_kernel<<<dim3(NPHI_BLK + NBUILD_BLK), dim3(256), 0, stream>>>(
        xyz, nbrs, envb, offsets, cursor, edgerec,
        s_buf,
        wbf_hi + oW1, wbf_lo + oW1, msg_b1,
        wbf_hi + oW2, wbf_lo + oW2, msg_b2,
        phi_buf);

    float* vin = v1_buf;
    float* vout = v2_buf;
    for (int i = 0; i < 3; ++i) {
        if (i == 0)
            msg_gather<1><<<dim3(N_ATOMS), dim3(128), 0, stream>>>(
                phi_buf, edgerec, rbf_w + (size_t)i*N_RBF*3*F, rbf_b + (size_t)i*3*F,
                vin, s_buf, vout, offsets, cnt);
        else
            msg_gather<0><<<dim3(N_ATOMS), dim3(128), 0, stream>>>(
                phi_buf, edgerec, rbf_w + (size_t)i*N_RBF*3*F, rbf_b + (size_t)i*3*F,
                vin, s_buf, vout, offsets, cnt);
        if (i < 2) {
            // upd(i) + phi(i+1) fused
            updphi_kernel<0><<<dim3(NP/32), dim3(256), 0, stream>>>(
                s_buf, vout,
                wbf_hi + oUV + (size_t)i*32768, wbf_lo + oUV + (size_t)i*32768,
                wbf_hi + oU1 + (size_t)i*32768, wbf_lo + oU1 + (size_t)i*32768,
                upd_b1 + (size_t)i*F,
                wbf_hi + oU2 + (size_t)i*49152, wbf_lo + oU2 + (size_t)i*49152,
                upd_b2 + (size_t)i*3*F,
                wbf_hi + oW1 + (size_t)(i+1)*16384, wbf_lo + oW1 + (size_t)(i+1)*16384,
                msg_b1 + (size_t)(i+1)*F,
                wbf_hi + oW2 + (size_t)(i+1)*49152, wbf_lo + oW2 + (size_t)(i+1)*49152,
                msg_b2 + (size_t)(i+1)*3*F,
                phi_buf,
                nullptr, nullptr, nullptr, nullptr);
        } else {
            // upd(2) + readout + mol reduce fused
            updphi_kernel<1><<<dim3(NP/32), dim3(256), 0, stream>>>(
                s_buf, vout,
                wbf_hi + oUV + (size_t)i*32768, wbf_lo + oUV + (size_t)i*32768,
                wbf_hi + oU1 + (size_t)i*32768, wbf_lo + oU1 + (size_t)i*32768,
                upd_b1 + (size_t)i*F,
                wbf_hi + oU2 + (size_t)i*49152, wbf_lo + oU2 + (size_t)i*49152,
                upd_b2 + (size_t)i*3*F,
                wbf_hi + oRO, wbf_lo + oRO, robias,
                nullptr, nullptr, nullptr,
                nullptr,
                ro_w2, ro_b2, molidx, out);
        }
        float* tmp = vin; vin = vout; vout = tmp;
    }
}

// Round 13
// 298.228 us; speedup vs baseline: 1.3734x; 1.0673x over previous
//
#include <hip/hip_runtime.h>

static constexpr int F = 128;
static constexpr int N_RBF = 20;
static constexpr int N_ATOMS = 8000;
static constexpr int NP = 8064;          // padded to 128
static constexpr int N_EDGES = 160000;
static constexpr int N_MOLS = 100;
static constexpr float CUTOFF = 5.0f;
static constexpr size_t NFC = (size_t)NP * F;
static constexpr int REC = 28;           // j, ev, ux,uy,uz, rbf[20], pad[3]
static constexpr int NPHI_BLK = NP / 32;                 // 252
static constexpr int NBUILD_BLK = (N_EDGES + 255) / 256; // 625
#define PIF 3.14159265358979323846f

typedef __attribute__((ext_vector_type(8))) short bf16x8;
typedef __attribute__((ext_vector_type(4))) float f32x4;
typedef unsigned short ushort_t;
typedef unsigned int uint_t;

__device__ __forceinline__ float silu_f(float x) { return x / (1.f + __expf(-x)); }

__device__ __forceinline__ ushort_t f2bf(float x) {   // round-to-nearest-even
    union { float f; uint_t u; } v; v.f = x;
    uint_t r = v.u + 0x7fffu + ((v.u >> 16) & 1u);
    return (ushort_t)(r >> 16);
}
__device__ __forceinline__ float bf2f(ushort_t h) {
    union { uint_t u; float f; } v; v.u = ((uint_t)h) << 16; return v.f;
}

// Session lessons:
//  - r4: cooperative launch silently fails under graph capture -> zeros.
//  - r5: fusing edge-gather into the MFMA kernel: 3x slower (latency, no TLP).
//  - r6: phi/v/s inter-layer activations MUST stay f32 (bf16 phi -> 49% output error).
//  - r7: 2-deep B prefetch regressed; r8 pad regressed; r9 direct-B regressed;
//    r10 16-atom tiles regressed. r12 (= r3 + build/phi0 merge) = 318.3us best.
//  - r12 profile: updphi 45us at 1 wave/SIMD (Occ 8.7%), 80% bubbles.
//  - THIS ROUND: updphi -> 512 threads / 8 waves on the SAME 32-atom tile &
//    staged pipeline (per-wave cols halved; 2 waves/SIMD fill latency bubbles).
//    Identical per-element math order -> bit-identical numerics.

// ---------------- pass 1: distance + envelope + live-edge histogram ----------------
__global__ __launch_bounds__(256) void count_kernel(
    const float* __restrict__ xyz, const int* __restrict__ nbrs,
    float* __restrict__ envb, int* __restrict__ cnt)
{
    int e = blockIdx.x * 256 + threadIdx.x;
    if (e >= N_EDGES) return;
    int i0 = nbrs[2*e+0], i1 = nbrs[2*e+1];
    float dx = xyz[3*i1+0] - xyz[3*i0+0];
    float dy = xyz[3*i1+1] - xyz[3*i0+1];
    float dz = xyz[3*i1+2] - xyz[3*i0+2];
    float d  = sqrtf(dx*dx + dy*dy + dz*dz);
    float ev = (d <= CUTOFF) ? 0.5f*(cosf(PIF*d/CUTOFF) + 1.f) : 0.f;
    envb[e] = ev;
    if (ev > 0.f) atomicAdd(&cnt[i0], 1);
}

// ---------------- exclusive scan of 8000 counters (single block) + zero out ----------------
__global__ __launch_bounds__(1024) void scan_kernel(
    const int* __restrict__ cnt, int* __restrict__ offsets, float* __restrict__ out)
{
    __shared__ int sums[1024];
    int tid = threadIdx.x;
    if (tid < N_MOLS) out[tid] = 0.f;
    int base = tid * 8;
    int local[8]; int s = 0;
    #pragma unroll
    for (int i = 0; i < 8; ++i) {
        int idx = base + i;
        local[i] = (idx < N_ATOMS) ? cnt[idx] : 0;
        s += local[i];
    }
    sums[tid] = s;
    __syncthreads();
    for (int d = 1; d < 1024; d <<= 1) {
        int v = (tid >= d) ? sums[tid - d] : 0;
        __syncthreads();
        sums[tid] += v;
        __syncthreads();
    }
    int ex = (tid == 0) ? 0 : sums[tid - 1];
    #pragma unroll
    for (int i = 0; i < 8; ++i) {
        int idx = base + i;
        if (idx < N_ATOMS) { offsets[idx] = ex; ex += local[i]; }
    }
}

// ---------------- fused prep: embed + weight transpose/split + zero cnt/cursor ----------------
static constexpr int WPREP_W = 557056;
static constexpr int WPREP_TOTAL = 557184;
static constexpr int NATF = N_ATOMS * F;
static constexpr int PREP_TOTAL = NATF + WPREP_TOTAL + 2 * N_ATOMS;
__global__ __launch_bounds__(256) void prep_kernel(
    const float* __restrict__ emb, const int* __restrict__ z, float* __restrict__ s,
    const float* __restrict__ msg_w1, const float* __restrict__ msg_w2,
    const float* __restrict__ upd_u,  const float* __restrict__ upd_v,
    const float* __restrict__ upd_w1, const float* __restrict__ upd_w2,
    const float* __restrict__ ro_w1,  const float* __restrict__ ro_b1,
    ushort_t* __restrict__ dhi, ushort_t* __restrict__ dlo,
    float* __restrict__ robias, int* __restrict__ cntz)
{
    int gidx = blockIdx.x * 256 + threadIdx.x;
    if (gidx < NATF) {                          // s = emb_table[z]
        int n = gidx >> 7, f = gidx & 127;
        s[gidx] = emb[z[n]*F + f];
        return;
    }
    int idx = gidx - NATF;
    if (idx >= WPREP_TOTAL) {                   // zero cnt + cursor (adjacent)
        cntz[idx - WPREP_TOTAL] = 0;
        return;
    }
    if (idx >= WPREP_W) {
        int l = idx - WPREP_W;
        robias[l] = (l < 64) ? ro_b1[l] : 0.f;
        return;
    }
    float val;
    if (idx < 540672) {
        const float* src; int K, N, rem;
        if (idx < 49152)       { int l = idx;          int c = l / 16384; rem = l % 16384; K = 128; N = 128; src = msg_w1 + c * 16384; }
        else if (idx < 196608) { int l = idx - 49152;  int c = l / 49152; rem = l % 49152; K = 128; N = 384; src = msg_w2 + c * 49152; }
        else if (idx < 294912) { int l = idx - 196608; int c = l / 32768; rem = l % 32768; K = 128; N = 128;
                                 if (rem < 16384) src = upd_u + c * 16384;
                                 else { src = upd_v + c * 16384; rem -= 16384; } }
        else if (idx < 393216) { int l = idx - 294912; int c = l / 32768; rem = l % 32768; K = 256; N = 128; src = upd_w1 + c * 32768; }
        else                   { int l = idx - 393216; int c = l / 49152; rem = l % 49152; K = 128; N = 384; src = upd_w2 + c * 49152; }
        int n = rem / K, k = rem % K;
        val = src[k * N + n];
    } else {
        int l = idx - 540672;             // ro_w1 pad: [n][k], n>=64 -> 0
        int n = l >> 7, k = l & 127;
        val = (n < 64) ? ro_w1[k * 64 + n] : 0.f;
    }
    ushort_t h = f2bf(val);
    dhi[idx] = h;
    dlo[idx] = f2bf(val - bf2f(h));
}

// ---------------- merged: phi0 MLP (blocks [0,252)) + build records (blocks [252,877)) ----------------
__global__ __launch_bounds__(256) void build_phi0_kernel(
    const float* __restrict__ xyz, const int* __restrict__ nbrs,
    const float* __restrict__ envb, const int* __restrict__ offsets,
    int* __restrict__ cursor, float* __restrict__ rec,
    const float* __restrict__ sbuf,
    const ushort_t* __restrict__ W1h, const ushort_t* __restrict__ W1l,
    const float* __restrict__ b1,
    const ushort_t* __restrict__ W2h, const ushort_t* __restrict__ W2l,
    const float* __restrict__ b2,
    float* __restrict__ C)
{
    if (blockIdx.x >= NPHI_BLK) {
        // ---------- build body ----------
        int e = (blockIdx.x - NPHI_BLK) * 256 + threadIdx.x;
        if (e >= N_EDGES) return;
        float ev = envb[e];
        if (ev <= 0.f) return;
        int i0 = nbrs[2*e+0], i1 = nbrs[2*e+1];
        float dx = xyz[3*i1+0] - xyz[3*i0+0];
        float dy = xyz[3*i1+1] - xyz[3*i0+1];
        float dz = xyz[3*i1+2] - xyz[3*i0+2];
        float d  = sqrtf(dx*dx + dy*dy + dz*dz);
        float inv = 1.f / d;
        int pos = offsets[i0] + atomicAdd(&cursor[i0], 1);
        float* r = rec + (size_t)pos * REC;
        r[0] = __int_as_float(i1);
        r[1] = ev;
        r[2] = dx*inv; r[3] = dy*inv; r[4] = dz*inv;
        float base = PIF*d/CUTOFF;
        float sc = inv * ev;   // fold env into rbf (w_s = (rbf*env)@W + b*env)
        #pragma unroll
        for (int k = 0; k < N_RBF; ++k)
            r[5 + k] = sinf((float)(k+1)*base) * sc;
        return;
    }

    // ---------- phi0 body (identical to verified r3 phi0_kernel) ----------
    __shared__ __align__(16) ushort_t Ah[2][32 * 40], Al[2][32 * 40];
    __shared__ __align__(16) ushort_t Bh[2][128 * 40], Bl[2][128 * 40];
    __shared__ __align__(16) ushort_t Hh[32 * 136], Hl[32 * 136];
    const int tid = threadIdx.x;
    const int wave = tid >> 6, lane = tid & 63;
    const int row_l = lane & 15, quad = lane >> 4;
    const int wn = wave * 32;
    const int m0 = blockIdx.x * 32;
    const int lrA = tid >> 3, ksA = (tid & 7) * 4;
    const int lrB = tid >> 1, ksB = (tid & 1) * 16;

    float4 rx;
    uint4 b_h0, b_h1, b_l0, b_l1;

    auto loadB1 = [&](int k0) {
        const ushort_t* bh = &W1h[(size_t)lrB * 128 + k0 + ksB];
        const ushort_t* bl = &W1l[(size_t)lrB * 128 + k0 + ksB];
        b_h0 = *(const uint4*)bh; b_h1 = *(const uint4*)(bh + 8);
        b_l0 = *(const uint4*)bl; b_l1 = *(const uint4*)(bl + 8);
    };
    auto loadB2 = [&](int it2) {
        int ct = it2 >> 2, k0 = (it2 & 3) * 32;
        const ushort_t* bh = &W2h[(size_t)(ct * 128 + lrB) * 128 + k0 + ksB];
        const ushort_t* bl = &W2l[(size_t)(ct * 128 + lrB) * 128 + k0 + ksB];
        b_h0 = *(const uint4*)bh; b_h1 = *(const uint4*)(bh + 8);
        b_l0 = *(const uint4*)bl; b_l1 = *(const uint4*)(bl + 8);
    };
    auto writeA = [&](int buf) {
        float e[4] = {rx.x, rx.y, rx.z, rx.w};
        ushort_t ph[4], pl[4];
        #pragma unroll
        for (int t = 0; t < 4; ++t) {
            ushort_t h = f2bf(e[t]);
            ph[t] = h; pl[t] = f2bf(e[t] - bf2f(h));
        }
        *(uint2*)&Ah[buf][lrA * 40 + ksA] = *(uint2*)ph;
        *(uint2*)&Al[buf][lrA * 40 + ksA] = *(uint2*)pl;
    };
    auto writeB = [&](int buf) {
        *(uint4*)&Bh[buf][lrB * 40 + ksB]     = b_h0;
        *(uint4*)&Bh[buf][lrB * 40 + ksB + 8] = b_h1;
        *(uint4*)&Bl[buf][lrB * 40 + ksB]     = b_l0;
        *(uint4*)&Bl[buf][lrB * 40 + ksB + 8] = b_l1;
    };

    f32x4 acc[2][2];
    #pragma unroll
    for (int i = 0; i < 2; ++i)
        #pragma unroll
        for (int j = 0; j < 2; ++j)
            #pragma unroll
            for (int r = 0; r < 4; ++r) acc[i][j][r] = 0.f;

    rx = *(const float4*)&sbuf[(size_t)(m0 + lrA) * 128 + ksA];
    loadB1(0);
    writeA(0); writeB(0);
    __syncthreads();
    #pragma unroll
    for (int it = 0; it < 4; ++it) {
        const int k0n = (it + 1) * 32;
        if (it + 1 < 4) {
            rx = *(const float4*)&sbuf[(size_t)(m0 + lrA) * 128 + k0n + ksA];
            loadB1(k0n);
        }
        bf16x8 ahf[2], alf[2], bhf[2], blf[2];
        #pragma unroll
        for (int i = 0; i < 2; ++i) {
            int ar = (i * 16 + row_l) * 40 + quad * 8;
            ahf[i] = *(const bf16x8*)&Ah[it & 1][ar];
            alf[i] = *(const bf16x8*)&Al[it & 1][ar];
        }
        #pragma unroll
        for (int j = 0; j < 2; ++j) {
            int br = (wn + j * 16 + row_l) * 40 + quad * 8;
            bhf[j] = *(const bf16x8*)&Bh[it & 1][br];
            blf[j] = *(const bf16x8*)&Bl[it & 1][br];
        }
        #pragma unroll
        for (int i = 0; i < 2; ++i)
            #pragma unroll
            for (int j = 0; j < 2; ++j) {
                acc[i][j] = __builtin_amdgcn_mfma_f32_16x16x32_bf16(ahf[i], bhf[j], acc[i][j], 0, 0, 0);
                acc[i][j] = __builtin_amdgcn_mfma_f32_16x16x32_bf16(ahf[i], blf[j], acc[i][j], 0, 0, 0);
                acc[i][j] = __builtin_amdgcn_mfma_f32_16x16x32_bf16(alf[i], bhf[j], acc[i][j], 0, 0, 0);
            }
        if (it + 1 < 4) { writeA((it + 1) & 1); writeB((it + 1) & 1); }
        __syncthreads();
    }
    #pragma unroll
    for (int j = 0; j < 2; ++j) {
        int col = wn + j * 16 + row_l;
        float bval = b1[col];
        #pragma unroll
        for (int i = 0; i < 2; ++i)
            #pragma unroll
            for (int r = 0; r < 4; ++r) {
                int row = i * 16 + quad * 4 + r;
                float v = silu_f(acc[i][j][r] + bval);
                ushort_t h = f2bf(v);
                Hh[row * 136 + col] = h;
                Hl[row * 136 + col] = f2bf(v - bf2f(h));
            }
    }

    #pragma unroll
    for (int i = 0; i < 2; ++i)
        #pragma unroll
        for (int j = 0; j < 2; ++j)
            #pragma unroll
            for (int r = 0; r < 4; ++r) acc[i][j][r] = 0.f;
    loadB2(0); writeB(0);
    __syncthreads();
    #pragma unroll
    for (int it = 0; it < 12; ++it) {
        const int k0 = (it & 3) * 32;
        if (it + 1 < 12) loadB2(it + 1);
        bf16x8 ahf[2], alf[2], bhf[2], blf[2];
        #pragma unroll
        for (int i = 0; i < 2; ++i) {
            int ar = (i * 16 + row_l) * 136 + k0 + quad * 8;
            ahf[i] = *(const bf16x8*)&Hh[ar];
            alf[i] = *(const bf16x8*)&Hl[ar];
        }
        #pragma unroll
        for (int j = 0; j < 2; ++j) {
            int br = (wn + j * 16 + row_l) * 40 + quad * 8;
            bhf[j] = *(const bf16x8*)&Bh[it & 1][br];
            blf[j] = *(const bf16x8*)&Bl[it & 1][br];
        }
        #pragma unroll
        for (int i = 0; i < 2; ++i)
            #pragma unroll
            for (int j = 0; j < 2; ++j) {
                acc[i][j] = __builtin_amdgcn_mfma_f32_16x16x32_bf16(ahf[i], bhf[j], acc[i][j], 0, 0, 0);
                acc[i][j] = __builtin_amdgcn_mfma_f32_16x16x32_bf16(ahf[i], blf[j], acc[i][j], 0, 0, 0);
                acc[i][j] = __builtin_amdgcn_mfma_f32_16x16x32_bf16(alf[i], bhf[j], acc[i][j], 0, 0, 0);
            }
        if ((it & 3) == 3) {
            const int ct = it >> 2;
            #pragma unroll
            for (int j = 0; j < 2; ++j) {
                int col = ct * 128 + wn + j * 16 + row_l;
                float bval = b2[col];
                #pragma unroll
                for (int i = 0; i < 2; ++i)
                    #pragma unroll
                    for (int r = 0; r < 4; ++r) {
                        int row = i * 16 + quad * 4 + r;
                        C[(size_t)(m0 + row) * 384 + col] = acc[i][j][r] + bval;
                    }
            }
            #pragma unroll
            for (int i = 0; i < 2; ++i)
                #pragma unroll
                for (int j = 0; j < 2; ++j)
                    #pragma unroll
                    for (int r = 0; r < 4; ++r) acc[i][j][r] = 0.f;
        }
        if (it + 1 < 12) writeB((it + 1) & 1);
        __syncthreads();
    }
}

// ---------------- fused update (+ next phi / readout tail), 512 threads / 8 waves ----------------
// Same 32-atom tile and staged pipeline as the verified 256-thread version; each wave
// owns 16 output cols (32 in phase 0) so 2 waves/SIMD co-reside and hide latency.
// Per-output-element math order identical -> bit-identical results.
template<int TAIL>
__global__ __launch_bounds__(512) void updphi_kernel(
    float* __restrict__ s_io, float* __restrict__ v_io,
    const ushort_t* __restrict__ UVh, const ushort_t* __restrict__ UVl,
    const ushort_t* __restrict__ W1h, const ushort_t* __restrict__ W1l,
    const float* __restrict__ b1,
    const ushort_t* __restrict__ W2h, const ushort_t* __restrict__ W2l,
    const float* __restrict__ b2,
    const ushort_t* __restrict__ XW1h, const ushort_t* __restrict__ XW1l,
    const float* __restrict__ xb1,
    const ushort_t* __restrict__ XW2h, const ushort_t* __restrict__ XW2l,
    const float* __restrict__ xb2,
    float* __restrict__ phi_out,
    const float* __restrict__ w2ro, const float* __restrict__ b2ro,
    const int* __restrict__ mol, float* __restrict__ outp)
{
    __shared__ float uvv[96][260];                     // [ln*3+d][0:128 uv | 128:256 vv]
    __shared__ __align__(16) ushort_t Bh[2][128 * 40];
    __shared__ __align__(16) ushort_t Bl[2][128 * 40];
    __shared__ __align__(16) unsigned char AH[17408];  // union: A-stage dbuf / H
    __shared__ float molacc[128];                      // TAIL=1 only
    __shared__ float redl[32][8];                      // TAIL=1 only
    const int tid = threadIdx.x;
    const int wave = tid >> 6, lane = tid & 63;        // wave 0..7
    const int row_l = lane & 15, quad = lane >> 4;
    const int wn16 = wave * 16;                        // phase 1/2/3 col base
    const int wn32 = wave * 32;                        // phase 0 col base
    const int m0 = blockIdx.x * 32;
    const int lrA = tid >> 3;          // 0..63 (A-stage helpers use tid<256 -> 0..31)
    const int ksA = (tid & 7) * 4;     // 0,4,..28
    const int lrB4 = tid >> 2, ksB4 = (tid & 3) * 8;   // B-stage (128 rows x 32k, 1 uint4/thr)

    float* sS = &uvv[0][0];            // 32 x 132 f32 (overlays dead uvv rows in phase 2 tail)
    constexpr int SSTR = 132;

    // ================= phase 0: [uv|vv] = v @ UVt (M=96, N=256, K=128) =================
    {
        ushort_t* A0h = (ushort_t*)AH;                 // [96][40]
        ushort_t* A0l = A0h + 96 * 40;
        ushort_t* B0h = &Bh[0][0];                     // [256][40] spans both buffers
        ushort_t* B0l = &Bl[0][0];
        f32x4 acc0[6][2];
        #pragma unroll
        for (int i = 0; i < 6; ++i)
            #pragma unroll
            for (int j = 0; j < 2; ++j)
                #pragma unroll
                for (int r = 0; r < 4; ++r) acc0[i][j][r] = 0.f;
        auto stageA0 = [&](int row, int k0) {
            float4 v = *(const float4*)&v_io[(size_t)(m0 * 3 + row) * 128 + k0 + ksA];
            float e[4] = {v.x, v.y, v.z, v.w};
            ushort_t ph[4], pl[4];
            #pragma unroll
            for (int t = 0; t < 4; ++t) {
                ushort_t h = f2bf(e[t]);
                ph[t] = h; pl[t] = f2bf(e[t] - bf2f(h));
            }
            *(uint2*)&A0h[row * 40 + ksA] = *(uint2*)ph;
            *(uint2*)&A0l[row * 40 + ksA] = *(uint2*)pl;
        };
        for (int k0 = 0; k0 < 128; k0 += 32) {
            stageA0(lrA, k0);                          // rows 0..63
            if (tid < 256) stageA0(64 + lrA, k0);      // rows 64..95
            {
                int row = tid >> 1, hb = (tid & 1) * 16;
                const ushort_t* bh = &UVh[(size_t)row * 128 + k0 + hb];
                const ushort_t* bl = &UVl[(size_t)row * 128 + k0 + hb];
                *(uint4*)&B0h[row * 40 + hb]     = *(const uint4*)bh;
                *(uint4*)&B0h[row * 40 + hb + 8] = *(const uint4*)(bh + 8);
                *(uint4*)&B0l[row * 40 + hb]     = *(const uint4*)bl;
                *(uint4*)&B0l[row * 40 + hb + 8] = *(const uint4*)(bl + 8);
            }
            __syncthreads();
            bf16x8 a0h[6], a0l[6], b0h[2], b0l[2];
            #pragma unroll
            for (int i = 0; i < 6; ++i) {
                int ar = (i * 16 + row_l) * 40 + quad * 8;
                a0h[i] = *(const bf16x8*)&A0h[ar];
                a0l[i] = *(const bf16x8*)&A0l[ar];
            }
            #pragma unroll
            for (int j = 0; j < 2; ++j) {
                int br = (wn32 + j * 16 + row_l) * 40 + quad * 8;
                b0h[j] = *(const bf16x8*)&B0h[br];
                b0l[j] = *(const bf16x8*)&B0l[br];
            }
            #pragma unroll
            for (int i = 0; i < 6; ++i)
                #pragma unroll
                for (int j = 0; j < 2; ++j) {
                    acc0[i][j] = __builtin_amdgcn_mfma_f32_16x16x32_bf16(a0h[i], b0h[j], acc0[i][j], 0, 0, 0);
                    acc0[i][j] = __builtin_amdgcn_mfma_f32_16x16x32_bf16(a0h[i], b0l[j], acc0[i][j], 0, 0, 0);
                    acc0[i][j] = __builtin_amdgcn_mfma_f32_16x16x32_bf16(a0l[i], b0h[j], acc0[i][j], 0, 0, 0);
                }
            __syncthreads();
        }
        #pragma unroll
        for (int i = 0; i < 6; ++i)
            #pragma unroll
            for (int j = 0; j < 2; ++j)
                #pragma unroll
                for (int r = 0; r < 4; ++r)
                    uvv[i * 16 + quad * 4 + r][wn32 + j * 16 + row_l] = acc0[i][j][r];
        __syncthreads();
    }

    // ================= phase 1: h = silu([s | norm(vv)] @ W1 + b1) =================
    ushort_t* Ah1 = (ushort_t*)AH;                     // [2][32*40]
    ushort_t* Al1 = Ah1 + 2 * 32 * 40;
    ushort_t* Hh  = (ushort_t*)AH;                     // [32][136]
    ushort_t* Hl  = Hh + 32 * 136;

    float4 rx;
    uint4 b_h0, b_l0;

    auto loadB1 = [&](int k0) {
        b_h0 = *(const uint4*)&W1h[(size_t)lrB4 * 256 + k0 + ksB4];
        b_l0 = *(const uint4*)&W1l[(size_t)lrB4 * 256 + k0 + ksB4];
    };
    auto writeB = [&](int buf) {
        *(uint4*)&Bh[buf][lrB4 * 40 + ksB4] = b_h0;
        *(uint4*)&Bl[buf][lrB4 * 40 + ksB4] = b_l0;
    };
    auto writeA1 = [&](int buf, int k0) {              // tid < 256 only
        float e[4];
        if (k0 < 128) {
            e[0] = rx.x; e[1] = rx.y; e[2] = rx.z; e[3] = rx.w;
        } else {
            int f = k0 + ksA;          // uvv col 128..255 (vv)
            #pragma unroll
            for (int t = 0; t < 4; ++t) {
                float x = uvv[lrA * 3 + 0][f + t];
                float y = uvv[lrA * 3 + 1][f + t];
                float z = uvv[lrA * 3 + 2][f + t];
                e[t] = sqrtf(x * x + y * y + z * z + 1e-15f);
            }
        }
        ushort_t ph[4], pl[4];
        #pragma unroll
        for (int t = 0; t < 4; ++t) {
            ushort_t h = f2bf(e[t]);
            ph[t] = h; pl[t] = f2bf(e[t] - bf2f(h));
        }
        *(uint2*)&Ah1[buf * 1280 + lrA * 40 + ksA] = *(uint2*)ph;
        *(uint2*)&Al1[buf * 1280 + lrA * 40 + ksA] = *(uint2*)pl;
    };

    f32x4 acc[2];
    #pragma unroll
    for (int i = 0; i < 2; ++i)
        #pragma unroll
        for (int r = 0; r < 4; ++r) acc[i][r] = 0.f;

    if (tid < 256) rx = *(const float4*)&s_io[(size_t)(m0 + lrA) * 128 + ksA];
    loadB1(0);
    if (tid < 256) writeA1(0, 0);
    writeB(0);
    __syncthreads();
    #pragma unroll
    for (int it = 0; it < 8; ++it) {
        const int k0n = (it + 1) * 32;
        if (it + 1 < 8) {
            if (tid < 256 && k0n < 128) rx = *(const float4*)&s_io[(size_t)(m0 + lrA) * 128 + k0n + ksA];
            loadB1(k0n);
        }
        bf16x8 ahf[2], alf[2], bhf, blf;
        #pragma unroll
        for (int i = 0; i < 2; ++i) {
            int ar = (it & 1) * 1280 + (i * 16 + row_l) * 40 + quad * 8;
            ahf[i] = *(const bf16x8*)&Ah1[ar];
            alf[i] = *(const bf16x8*)&Al1[ar];
        }
        {
            int br = (wn16 + row_l) * 40 + quad * 8;
            bhf = *(const bf16x8*)&Bh[it & 1][br];
            blf = *(const bf16x8*)&Bl[it & 1][br];
        }
        #pragma unroll
        for (int i = 0; i < 2; ++i) {
            acc[i] = __builtin_amdgcn_mfma_f32_16x16x32_bf16(ahf[i], bhf, acc[i], 0, 0, 0);
            acc[i] = __builtin_amdgcn_mfma_f32_16x16x32_bf16(ahf[i], blf, acc[i], 0, 0, 0);
            acc[i] = __builtin_amdgcn_mfma_f32_16x16x32_bf16(alf[i], bhf, acc[i], 0, 0, 0);
        }
        if (it + 1 < 8) { if (tid < 256) writeA1((it + 1) & 1, k0n); writeB((it + 1) & 1); }
        __syncthreads();
    }
    // epilogue 1 -> H
    {
        int col = wn16 + row_l;
        float bval = b1[col];
        #pragma unroll
        for (int i = 0; i < 2; ++i)
            #pragma unroll
            for (int r = 0; r < 4; ++r) {
                int row = i * 16 + quad * 4 + r;
                float v = silu_f(acc[i][r] + bval);
                ushort_t h = f2bf(v);
                Hh[row * 136 + col] = h;
                Hl[row * 136 + col] = f2bf(v - bf2f(h));
            }
    }

    // ================= phase 2: a = h @ W2 + b2, finupd folded into ct epilogues =================
    constexpr int CT0 = TAIL ? 1 : 0;          // TAIL=1: a_vv unused (v dead) -> skip ct0
    constexpr int NIT2 = (3 - CT0) * 4;
    auto loadB2 = [&](int it2) {
        int ct = CT0 + (it2 >> 2), k0 = (it2 & 3) * 32;
        b_h0 = *(const uint4*)&W2h[(size_t)(ct * 128 + lrB4) * 128 + k0 + ksB4];
        b_l0 = *(const uint4*)&W2l[(size_t)(ct * 128 + lrB4) * 128 + k0 + ksB4];
    };

    #pragma unroll
    for (int i = 0; i < 2; ++i)
        #pragma unroll
        for (int r = 0; r < 4; ++r) acc[i][r] = 0.f;
    f32x4 ssum[2];

    loadB2(0); writeB(0);
    __syncthreads();
    #pragma unroll
    for (int it = 0; it < NIT2; ++it) {
        const int k0 = (it & 3) * 32;
        if (it + 1 < NIT2) loadB2(it + 1);
        bf16x8 ahf[2], alf[2], bhf, blf;
        #pragma unroll
        for (int i = 0; i < 2; ++i) {
            int ar = (i * 16 + row_l) * 136 + k0 + quad * 8;
            ahf[i] = *(const bf16x8*)&Hh[ar];
            alf[i] = *(const bf16x8*)&Hl[ar];
        }
        {
            int br = (wn16 + row_l) * 40 + quad * 8;
            bhf = *(const bf16x8*)&Bh[it & 1][br];
            blf = *(const bf16x8*)&Bl[it & 1][br];
        }
        #pragma unroll
        for (int i = 0; i < 2; ++i) {
            acc[i] = __builtin_amdgcn_mfma_f32_16x16x32_bf16(ahf[i], bhf, acc[i], 0, 0, 0);
            acc[i] = __builtin_amdgcn_mfma_f32_16x16x32_bf16(ahf[i], blf, acc[i], 0, 0, 0);
            acc[i] = __builtin_amdgcn_mfma_f32_16x16x32_bf16(alf[i], bhf, acc[i], 0, 0, 0);
        }
        if ((it & 3) == 3) {                     // column-tile epilogue + finupd slice
            const int ct = CT0 + (it >> 2);
            int f = wn16 + row_l;
            float bval = b2[ct * 128 + f];
            #pragma unroll
            for (int i = 0; i < 2; ++i)
                #pragma unroll
                for (int r = 0; r < 4; ++r) {
                    int ln = i * 16 + quad * 4 + r;
                    float a = acc[i][r] + bval;
                    if (ct == 0) {                      // a_vv: v += uv * a
                        size_t vb = (size_t)(m0 + ln) * 3 * F + f;
                        v_io[vb]         += uvv[ln * 3 + 0][f] * a;
                        v_io[vb + F]     += uvv[ln * 3 + 1][f] * a;
                        v_io[vb + 2 * F] += uvv[ln * 3 + 2][f] * a;
                    } else if (ct == 1) {               // a_sv: ssum = <uv,vv> * a
                        float dot = uvv[ln * 3 + 0][f] * uvv[ln * 3 + 0][128 + f]
                                  + uvv[ln * 3 + 1][f] * uvv[ln * 3 + 1][128 + f]
                                  + uvv[ln * 3 + 2][f] * uvv[ln * 3 + 2][128 + f];
                        ssum[i][r] = dot * a;
                    } else {                            // a_ss: s_new = s + ssum + a
                        float sv = s_io[(size_t)(m0 + ln) * F + f] + ssum[i][r] + a;
                        if constexpr (TAIL == 0) s_io[(size_t)(m0 + ln) * F + f] = sv;
                        sS[ln * SSTR + f] = sv;         // sS overlays uvv rows (dead by now)
                    }
                }
            #pragma unroll
            for (int i = 0; i < 2; ++i)
                #pragma unroll
                for (int r = 0; r < 4; ++r) acc[i][r] = 0.f;
        }
        if (it + 1 < NIT2) writeB((it + 1) & 1);
        __syncthreads();
    }

    // ================= phase 3: next-phi MLP (TAIL=0) or readout (TAIL=1), A = sS =================
    if constexpr (TAIL == 1) { if (tid < 128) molacc[tid] = 0.f; }
    ushort_t* Ah3 = (ushort_t*)AH;
    ushort_t* Al3 = Ah3 + 2 * 1280;

    auto loadB31 = [&](int k0) {
        b_h0 = *(const uint4*)&XW1h[(size_t)lrB4 * 128 + k0 + ksB4];
        b_l0 = *(const uint4*)&XW1l[(size_t)lrB4 * 128 + k0 + ksB4];
    };
    auto writeA3 = [&](int buf, int k0) {              // tid < 256 only
        float e[4];
        #pragma unroll
        for (int t = 0; t < 4; ++t) e[t] = sS[lrA * SSTR + k0 + ksA + t];
        ushort_t ph[4], pl[4];
        #pragma unroll
        for (int t = 0; t < 4; ++t) {
            ushort_t h = f2bf(e[t]);
            ph[t] = h; pl[t] = f2bf(e[t] - bf2f(h));
        }
        *(uint2*)&Ah3[buf * 1280 + lrA * 40 + ksA] = *(uint2*)ph;
        *(uint2*)&Al3[buf * 1280 + lrA * 40 + ksA] = *(uint2*)pl;
    };

    #pragma unroll
    for (int i = 0; i < 2; ++i)
        #pragma unroll
        for (int r = 0; r < 4; ++r) acc[i][r] = 0.f;

    loadB31(0);
    if (tid < 256) writeA3(0, 0);
    writeB(0);
    __syncthreads();
    #pragma unroll
    for (int it = 0; it < 4; ++it) {
        const int k0n = (it + 1) * 32;
        if (it + 1 < 4) loadB31(k0n);
        bf16x8 ahf[2], alf[2], bhf, blf;
        #pragma unroll
        for (int i = 0; i < 2; ++i) {
            int ar = (it & 1) * 1280 + (i * 16 + row_l) * 40 + quad * 8;
            ahf[i] = *(const bf16x8*)&Ah3[ar];
            alf[i] = *(const bf16x8*)&Al3[ar];
        }
        {
            int br = (wn16 + row_l) * 40 + quad * 8;
            bhf = *(const bf16x8*)&Bh[it & 1][br];
            blf = *(const bf16x8*)&Bl[it & 1][br];
        }
        #pragma unroll
        for (int i = 0; i < 2; ++i) {
            acc[i] = __builtin_amdgcn_mfma_f32_16x16x32_bf16(ahf[i], bhf, acc[i], 0, 0, 0);
            acc[i] = __builtin_amdgcn_mfma_f32_16x16x32_bf16(ahf[i], blf, acc[i], 0, 0, 0);
            acc[i] = __builtin_amdgcn_mfma_f32_16x16x32_bf16(alf[i], bhf, acc[i], 0, 0, 0);
        }
        if (it + 1 < 4) { if (tid < 256) writeA3((it + 1) & 1, k0n); writeB((it + 1) & 1); }
        __syncthreads();
    }

    if constexpr (TAIL == 0) {
        // -> H, then stage 2 with XW2 -> phi_out
        {
            int col = wn16 + row_l;
            float bval = xb1[col];
            #pragma unroll
            for (int i = 0; i < 2; ++i)
                #pragma unroll
                for (int r = 0; r < 4; ++r) {
                    int row = i * 16 + quad * 4 + r;
                    float v = silu_f(acc[i][r] + bval);
                    ushort_t h = f2bf(v);
                    Hh[row * 136 + col] = h;
                    Hl[row * 136 + col] = f2bf(v - bf2f(h));
                }
        }
        auto loadB32 = [&](int it2) {
            int ct = it2 >> 2, k0 = (it2 & 3) * 32;
            b_h0 = *(const uint4*)&XW2h[(size_t)(ct * 128 + lrB4) * 128 + k0 + ksB4];
            b_l0 = *(const uint4*)&XW2l[(size_t)(ct * 128 + lrB4) * 128 + k0 + ksB4];
        };
        #pragma unroll
        for (int i = 0; i < 2; ++i)
            #pragma unroll
            for (int r = 0; r < 4; ++r) acc[i][r] = 0.f;
        loadB32(0); writeB(0);
        __syncthreads();
        #pragma unroll
        for (int it = 0; it < 12; ++it) {
            const int k0 = (it & 3) * 32;
            if (it + 1 < 12) loadB32(it + 1);
            bf16x8 ahf[2], alf[2], bhf, blf;
            #pragma unroll
            for (int i = 0; i < 2; ++i) {
                int ar = (i * 16 + row_l) * 136 + k0 + quad * 8;
                ahf[i] = *(const bf16x8*)&Hh[ar];
                alf[i] = *(const bf16x8*)&Hl[ar];
            }
            {
                int br = (wn16 + row_l) * 40 + quad * 8;
                bhf = *(const bf16x8*)&Bh[it & 1][br];
                blf = *(const bf16x8*)&Bl[it & 1][br];
            }
            #pragma unroll
            for (int i = 0; i < 2; ++i) {
                acc[i] = __builtin_amdgcn_mfma_f32_16x16x32_bf16(ahf[i], bhf, acc[i], 0, 0, 0);
                acc[i] = __builtin_amdgcn_mfma_f32_16x16x32_bf16(ahf[i], blf, acc[i], 0, 0, 0);
                acc[i] = __builtin_amdgcn_mfma_f32_16x16x32_bf16(alf[i], bhf, acc[i], 0, 0, 0);
            }
            if ((it & 3) == 3) {
                const int ct = it >> 2;
                int col = ct * 128 + wn16 + row_l;
                float bval = xb2[col];
                #pragma unroll
                for (int i = 0; i < 2; ++i)
                    #pragma unroll
                    for (int r = 0; r < 4; ++r) {
                        int row = i * 16 + quad * 4 + r;
                        phi_out[(size_t)(m0 + row) * 384 + col] = acc[i][r] + bval;
                    }
                #pragma unroll
                for (int i = 0; i < 2; ++i)
                    #pragma unroll
                    for (int r = 0; r < 4; ++r) acc[i][r] = 0.f;
            }
            if (it + 1 < 12) writeB((it + 1) & 1);
            __syncthreads();
        }
    } else {
        // readout: atom_e = sum_{col<64} silu(acc+robias)·w2 ; block mol table -> out
        float part[2][4];
        #pragma unroll
        for (int i = 0; i < 2; ++i)
            #pragma unroll
            for (int r = 0; r < 4; ++r) part[i][r] = 0.f;
        {
            int col = wn16 + row_l;
            float bv = xb1[col];                       // robias (zero-padded)
            float wv = (col < 64) ? w2ro[col] : 0.f;
            #pragma unroll
            for (int i = 0; i < 2; ++i)
                #pragma unroll
                for (int r = 0; r < 4; ++r)
                    part[i][r] += silu_f(acc[i][r] + bv) * wv;
        }
        #pragma unroll
        for (int o = 1; o < 16; o <<= 1)
            #pragma unroll
            for (int i = 0; i < 2; ++i)
                #pragma unroll
                for (int r = 0; r < 4; ++r)
                    part[i][r] += __shfl_xor(part[i][r], o);
        if (row_l == 0)
            #pragma unroll
            for (int i = 0; i < 2; ++i)
                #pragma unroll
                for (int r = 0; r < 4; ++r)
                    redl[i * 16 + quad * 4 + r][wave] = part[i][r];
        __syncthreads();
        if (tid < 32) {
            int n = m0 + tid;
            if (n < N_ATOMS) {
                float e = redl[tid][0] + redl[tid][1] + redl[tid][2] + redl[tid][3]
                        + redl[tid][4] + redl[tid][5] + redl[tid][6] + redl[tid][7] + b2ro[0];
                atomicAdd(&molacc[mol[n]], e);
            }
        }
        __syncthreads();
        if (tid < 100 && molacc[tid] != 0.f) atomicAdd(&outp[tid], molacc[tid]);
    }
}

// ---------------- atom-centric message gather (atomic-free, packed records) ----------------
template<int ZVIN>
__global__ __launch_bounds__(128) void msg_gather(
    const float* __restrict__ phi, const float* __restrict__ rec,
    const float* __restrict__ rbf_w, const float* __restrict__ rbf_b,
    const float* __restrict__ v_in, float* __restrict__ s,
    float* __restrict__ v_out, const int* __restrict__ offsets,
    const int* __restrict__ cnt)
{
    const int n = blockIdx.x, tid = threadIdx.x;
    float W0[N_RBF], W1[N_RBF], W2[N_RBF];
    #pragma unroll
    for (int k = 0; k < N_RBF; ++k) {
        W0[k] = rbf_w[k*3*F + tid];
        W1[k] = rbf_w[k*3*F + F + tid];
        W2[k] = rbf_w[k*3*F + 2*F + tid];
    }
    const float b0 = rbf_b[tid], b1 = rbf_b[F + tid], b2 = rbf_b[2*F + tid];
    float ds = 0.f, dvx = 0.f, dvy = 0.f, dvz = 0.f;
    const int off = offsets[n], c = cnt[n];
    const float* r = rec + (size_t)off * REC;
    #pragma unroll 2
    for (int t = 0; t < c; ++t, r += REC) {
        int j = __float_as_int(r[0]);
        float ev = r[1];
        float ux = r[2], uy = r[3], uz = r[4];
        float w0 = b0 * ev, w1 = b1 * ev, w2 = b2 * ev;
        #pragma unroll
        for (int k = 0; k < N_RBF; ++k) {
            float rk = r[5 + k];
            w0 += rk * W0[k]; w1 += rk * W1[k]; w2 += rk * W2[k];
        }
        const float* prow = phi + (size_t)j * 3 * F;
        float s0 = prow[tid] * w0;
        float s1 = prow[F + tid] * w1;
        float s2 = prow[2*F + tid] * w2;
        ds  += s1;
        if constexpr (ZVIN) {
            dvx += s2*ux; dvy += s2*uy; dvz += s2*uz;
        } else {
            const float* vrow = v_in + (size_t)j * 3 * F;
            dvx += s2*ux + s0 * vrow[tid];
            dvy += s2*uy + s0 * vrow[F + tid];
            dvz += s2*uz + s0 * vrow[2*F + tid];
        }
    }
    s[(size_t)n * F + tid] += ds;
    size_t vb = (size_t)n * 3 * F + tid;
    if constexpr (ZVIN) {
        v_out[vb]       = dvx;
        v_out[vb + F]   = dvy;
        v_out[vb + 2*F] = dvz;
    } else {
        v_out[vb]       = v_in[vb]       + dvx;
        v_out[vb + F]   = v_in[vb + F]   + dvy;
        v_out[vb + 2*F] = v_in[vb + 2*F] + dvz;
    }
}

extern "C" void kernel_launch(void* const* d_in, const int* in_sizes, int n_in,
                              void* d_out, int out_size, void* d_ws, size_t ws_size,
                              hipStream_t stream)
{
    const float* xyz    = (const float*)d_in[0];
    const float* emb    = (const float*)d_in[1];
    const float* msg_w1 = (const float*)d_in[2];
    const float* msg_b1 = (const float*)d_in[3];
    const float* msg_w2 = (const float*)d_in[4];
    const float* msg_b2 = (const float*)d_in[5];
    const float* rbf_w  = (const float*)d_in[6];
    const float* rbf_b  = (const float*)d_in[7];
    const float* upd_u  = (const float*)d_in[8];
    const float* upd_v  = (const float*)d_in[9];
    const float* upd_w1 = (const float*)d_in[10];
    const float* upd_b1 = (const float*)d_in[11];
    const float* upd_w2 = (const float*)d_in[12];
    const float* upd_b2 = (const float*)d_in[13];
    const float* ro_w1  = (const float*)d_in[14];
    const float* ro_b1  = (const float*)d_in[15];
    const float* ro_w2  = (const float*)d_in[16];
    const float* ro_b2  = (const float*)d_in[17];
    const int*   z      = (const int*)d_in[18];
    const int*   nbrs   = (const int*)d_in[19];
    const int*   molidx = (const int*)d_in[20];
    float* out = (float*)d_out;

    float* ws = (float*)d_ws;
    size_t off = 0;
    auto alloc = [&](size_t n) { float* p = ws + off; off += n; return p; };
    float* s_buf   = alloc(NFC);
    float* v1_buf  = alloc(3 * NFC);       // [n][3][f]
    float* v2_buf  = alloc(3 * NFC);
    float* phi_buf = alloc(3 * NFC);
    float* envb    = alloc(N_EDGES);
    float* edgerec = alloc((size_t)N_EDGES * REC);
    ushort_t* wbf_hi = (ushort_t*)alloc(WPREP_W / 2 + 64);
    ushort_t* wbf_lo = (ushort_t*)alloc(WPREP_W / 2 + 64);
    float* robias   = alloc(128);
    int* cnt        = (int*)alloc(N_ATOMS);
    int* cursor     = (int*)alloc(N_ATOMS);   // adjacent to cnt (zeroed together)
    int* offsets    = (int*)alloc(N_ATOMS);

    // bf16 weight sub-offsets (elements, see prep_kernel)
    const size_t oW1 = 0, oW2 = 49152, oUV = 196608, oU1 = 294912, oU2 = 393216, oRO = 540672;

    prep_kernel<<<dim3(PREP_TOTAL / 256), dim3(256), 0, stream>>>(
        emb, z, s_buf,
        msg_w1, msg_w2, upd_u, upd_v, upd_w1, upd_w2, ro_w1, ro_b1,
        wbf_hi, wbf_lo, robias, cnt);
    count_kernel<<<dim3((N_EDGES + 255) / 256), dim3(256), 0, stream>>>(
        xyz, nbrs, envb, cnt);
    scan_kernel<<<dim3(1), dim3(1024), 0, stream>>>(cnt, offsets, out);
    // merged: phi_0 MLP (blocks [0,252)) + build live-edge records (blocks [252,877))
    build_phi0_kernel<<<dim3(NPHI_BLK + NBUILD_BLK), dim3(256), 0, stream>>>(
        xyz, nbrs, envb, offsets, cursor, edgerec,
        s_buf,
        wbf_hi + oW1, wbf_lo + oW1, msg_b1,
        wbf_hi + oW2, wbf_lo + oW2, msg_b2,
        phi_buf);

    float* vin = v1_buf;
    float* vout = v2_buf;
    for (int i = 0; i < 3; ++i) {
        if (i == 0)
            msg_gather<1><<<dim3(N_ATOMS), dim3(128), 0, stream>>>(
                phi_buf, edgerec, rbf_w + (size_t)i*N_RBF*3*F, rbf_b + (size_t)i*3*F,
                vin, s_buf, vout, offsets, cnt);
        else
            msg_gather<0><<<dim3(N_ATOMS), dim3(128), 0, stream>>>(
                phi_buf, edgerec, rbf_w + (size_t)i*N_RBF*3*F, rbf_b + (size_t)i*3*F,
                vin, s_buf, vout, offsets, cnt);
        if (i < 2) {
            // upd(i) + phi(i+1) fused (512 threads / 8 waves)
            updphi_kernel<0><<<dim3(NP/32), dim3(512), 0, stream>>>(
                s_buf, vout,
                wbf_hi + oUV + (size_t)i*32768, wbf_lo + oUV + (size_t)i*32768,
                wbf_hi + oU1 + (size_t)i*32768, wbf_lo + oU1 + (size_t)i*32768,
                upd_b1 + (size_t)i*F,
                wbf_hi + oU2 + (size_t)i*49152, wbf_lo + oU2 + (size_t)i*49152,
                upd_b2 + (size_t)i*3*F,
                wbf_hi + oW1 + (size_t)(i+1)*16384, wbf_lo + oW1 + (size_t)(i+1)*16384,
                msg_b1 + (size_t)(i+1)*F,
                wbf_hi + oW2 + (size_t)(i+1)*49152, wbf_lo + oW2 + (size_t)(i+1)*49152,
                msg_b2 + (size_t)(i+1)*3*F,
                phi_buf,
                nullptr, nullptr, nullptr, nullptr);
        } else {
            // upd(2) + readout + mol reduce fused
            updphi_kernel<1><<<dim3(NP/32), dim3(512), 0, stream>>>(
                s_buf, vout,
                wbf_hi + oUV + (size_t)i*32768, wbf_lo + oUV + (size_t)i*32768,
                wbf_hi + oU1 + (size_t)i*32768, wbf_lo + oU1 + (size_t)i*32768,
                upd_b1 + (size_t)i*F,
                wbf_hi + oU2 + (size_t)i*49152, wbf_lo + oU2 + (size_t)i*49152,
                upd_b2 + (size_t)i*3*F,
                wbf_hi + oRO, wbf_lo + oRO, robias,
                nullptr, nullptr, nullptr,
                nullptr,
                ro_w2, ro_b2, molidx, out);
        }
        float* tmp = vin; vin = vout; vout = tmp;
    }
}